// Round 1
// baseline (53436.133 us; speedup 1.0000x reference)
//
#include <hip/hip_runtime.h>
#include <hip/hip_bf16.h>
#include <math.h>

// Problem constants
#define BB 4
#define TT 1024
#define VV 50257
#define CC 768
#define HH 12
#define DD 64
#define LL 12
#define FFH 3072
#define MROWS (BB*TT)   // 4096

// ---------------- embedding: h = tok_emb[x] + pos_emb[x] (quirk: pos indexed by token id)
__global__ void embed_kernel(const int* __restrict__ x, const float* __restrict__ tok,
                             const float* __restrict__ pos, float* __restrict__ h) {
    int idx = blockIdx.x * 256 + threadIdx.x;
    if (idx >= MROWS * CC) return;
    int row = idx / CC, c = idx - row * CC;
    int id = x[row];
    h[idx] = tok[(size_t)id * CC + c] + pos[(size_t)id * CC + c];
}

// ---------------- generic row-major GEMM: C = A[M,K] @ B[K,N] + bias, optional relu
// 128x128 tile, 256 threads, 8x8 per thread
__global__ __launch_bounds__(256) void gemm_rm(const float* __restrict__ A,
                                               const float* __restrict__ B,
                                               const float* __restrict__ bias,
                                               float* __restrict__ C,
                                               int M, int N, int K, int relu) {
    __shared__ float As[16][132];
    __shared__ float Bs[16][132];
    int tid = threadIdx.x;
    int tx = tid & 15, ty = tid >> 4;
    int bn = blockIdx.x * 128, bm = blockIdx.y * 128;
    float acc[8][8] = {};
    for (int k0 = 0; k0 < K; k0 += 16) {
        #pragma unroll
        for (int i = tid; i < 2048; i += 256) {
            int m = i >> 4, kk = i & 15;
            As[kk][m] = A[(size_t)(bm + m) * K + k0 + kk];
        }
        #pragma unroll
        for (int i = tid; i < 2048; i += 256) {
            int kk = i >> 7, n = i & 127;
            int gn = bn + n;
            Bs[kk][n] = (gn < N) ? B[(size_t)(k0 + kk) * N + gn] : 0.f;
        }
        __syncthreads();
        #pragma unroll
        for (int kk = 0; kk < 16; kk++) {
            float a[8], bv[8];
            #pragma unroll
            for (int i = 0; i < 8; i++) a[i] = As[kk][ty + 16 * i];
            #pragma unroll
            for (int j = 0; j < 8; j++) bv[j] = Bs[kk][tx + 16 * j];
            #pragma unroll
            for (int i = 0; i < 8; i++)
                #pragma unroll
                for (int j = 0; j < 8; j++) acc[i][j] += a[i] * bv[j];
        }
        __syncthreads();
    }
    #pragma unroll
    for (int i = 0; i < 8; i++) {
        int m = bm + ty + 16 * i;
        #pragma unroll
        for (int j = 0; j < 8; j++) {
            int n = bn + tx + 16 * j;
            if (n < N) {
                float vv = acc[i][j] + (bias ? bias[n] : 0.f);
                if (relu) vv = fmaxf(vv, 0.f);
                C[(size_t)m * N + n] = vv;
            }
        }
    }
}

// ---------------- QKV projection: out[b,h,t,d] = sum_c h[b,t,c] * W[h,c,d]
// A = h [4096,768]; logical B[k][n] = W[((n>>6)*C + k)*64 + (n&63)], n = head*64+d
// blockIdx.z picks (Wk->kout, Wq->qout, Wv->vout)
__global__ __launch_bounds__(256) void gemm_qkv(const float* __restrict__ A,
                                                const float* __restrict__ W0,
                                                const float* __restrict__ W1,
                                                const float* __restrict__ W2,
                                                float* __restrict__ o0,
                                                float* __restrict__ o1,
                                                float* __restrict__ o2) {
    const float* W = (blockIdx.z == 0) ? W0 : (blockIdx.z == 1) ? W1 : W2;
    float* O = (blockIdx.z == 0) ? o0 : (blockIdx.z == 1) ? o1 : o2;
    __shared__ float As[16][132];
    __shared__ float Bs[16][132];
    int tid = threadIdx.x;
    int tx = tid & 15, ty = tid >> 4;
    int bn = blockIdx.x * 128, bm = blockIdx.y * 128;
    float acc[8][8] = {};
    for (int k0 = 0; k0 < CC; k0 += 16) {
        #pragma unroll
        for (int i = tid; i < 2048; i += 256) {
            int m = i >> 4, kk = i & 15;
            As[kk][m] = A[(size_t)(bm + m) * CC + k0 + kk];
        }
        #pragma unroll
        for (int i = tid; i < 2048; i += 256) {
            int kk = i >> 7, n = i & 127;
            int gn = bn + n;
            Bs[kk][n] = W[((size_t)(gn >> 6) * CC + (k0 + kk)) * 64 + (gn & 63)];
        }
        __syncthreads();
        #pragma unroll
        for (int kk = 0; kk < 16; kk++) {
            float a[8], bv[8];
            #pragma unroll
            for (int i = 0; i < 8; i++) a[i] = As[kk][ty + 16 * i];
            #pragma unroll
            for (int j = 0; j < 8; j++) bv[j] = Bs[kk][tx + 16 * j];
            #pragma unroll
            for (int i = 0; i < 8; i++)
                #pragma unroll
                for (int j = 0; j < 8; j++) acc[i][j] += a[i] * bv[j];
        }
        __syncthreads();
    }
    #pragma unroll
    for (int i = 0; i < 8; i++) {
        int m = bm + ty + 16 * i;
        int b = m >> 10, t = m & 1023;
        #pragma unroll
        for (int j = 0; j < 8; j++) {
            int n = bn + tx + 16 * j;
            int head = n >> 6, d = n & 63;
            O[(((size_t)(b * HH + head)) * TT + t) * DD + d] = acc[i][j];
        }
    }
}

// ---------------- fused attention row: o[t] = softmax_s<=t(scale * k[t].q[s]) @ v
// (quirk: k is the "query"). Output in concat layout [B,T,H*D].
__global__ __launch_bounds__(256) void attn_kernel(const float* __restrict__ q,
                                                   const float* __restrict__ k,
                                                   const float* __restrict__ v,
                                                   float* __restrict__ oc) {
    int t = blockIdx.x, hh = blockIdx.y, b = blockIdx.z;
    int tid = threadIdx.x;
    __shared__ float kv[64];
    __shared__ float sc[TT];
    __shared__ float red[256];
    __shared__ float pacc[4][64];
    const size_t base = ((size_t)(b * HH + hh)) * TT * DD;
    if (tid < 64) kv[tid] = k[base + (size_t)t * DD + tid];
    __syncthreads();
    float lmax = -1e30f;
    for (int s = tid; s <= t; s += 256) {
        const float* qs = q + base + (size_t)s * DD;
        float dot = 0.f;
        #pragma unroll
        for (int d = 0; d < 64; d++) dot += kv[d] * qs[d];
        dot *= 0.125f;  // D^-0.5
        sc[s] = dot;
        lmax = fmaxf(lmax, dot);
    }
    red[tid] = lmax; __syncthreads();
    for (int off = 128; off > 0; off >>= 1) {
        if (tid < off) red[tid] = fmaxf(red[tid], red[tid + off]);
        __syncthreads();
    }
    float mx = red[0]; __syncthreads();
    float lsum = 0.f;
    for (int s = tid; s <= t; s += 256) {
        float e = __expf(sc[s] - mx);
        sc[s] = e;
        lsum += e;
    }
    red[tid] = lsum; __syncthreads();
    for (int off = 128; off > 0; off >>= 1) {
        if (tid < off) red[tid] += red[tid + off];
        __syncthreads();
    }
    float inv = 1.f / red[0];
    int d = tid & 63, part = tid >> 6;
    float acc = 0.f;
    for (int s = part; s <= t; s += 4) acc += sc[s] * v[base + (size_t)s * DD + d];
    pacc[part][d] = acc;
    __syncthreads();
    if (tid < 64) {
        float o = (pacc[0][tid] + pacc[1][tid] + pacc[2][tid] + pacc[3][tid]) * inv;
        oc[((size_t)(b * TT + t)) * CC + hh * DD + tid] = o;
    }
}

// ---------------- h = LayerNorm(h + t) * g + b  (population var, post-norm)
__global__ __launch_bounds__(256) void resid_ln(float* __restrict__ h,
                                                const float* __restrict__ t,
                                                const float* __restrict__ g,
                                                const float* __restrict__ bta) {
    int row = blockIdx.x;
    int tid = threadIdx.x;
    __shared__ float red[256];
    float x[3];
    float s = 0.f;
    #pragma unroll
    for (int i = 0; i < 3; i++) {
        int c = tid + i * 256;
        x[i] = h[(size_t)row * CC + c] + t[(size_t)row * CC + c];
        s += x[i];
    }
    red[tid] = s; __syncthreads();
    for (int off = 128; off > 0; off >>= 1) {
        if (tid < off) red[tid] += red[tid + off];
        __syncthreads();
    }
    float mean = red[0] * (1.f / CC); __syncthreads();
    float s2 = 0.f;
    #pragma unroll
    for (int i = 0; i < 3; i++) { float dd = x[i] - mean; s2 += dd * dd; }
    red[tid] = s2; __syncthreads();
    for (int off = 128; off > 0; off >>= 1) {
        if (tid < off) red[tid] += red[tid + off];
        __syncthreads();
    }
    float inv = rsqrtf(red[0] * (1.f / CC) + 1e-5f);
    #pragma unroll
    for (int i = 0; i < 3; i++) {
        int c = tid + i * 256;
        h[(size_t)row * CC + c] = (x[i] - mean) * inv * g[c] + bta[c];
    }
}

// ---------------- per-row NLL: rl[m] = lse(logits[m]) - logits[m][y[m]]
__global__ __launch_bounds__(256) void row_nll(const float* __restrict__ logits,
                                               const int* __restrict__ y,
                                               float* __restrict__ rl) {
    int m = blockIdx.x, tid = threadIdx.x;
    const float* row = logits + (size_t)m * VV;
    __shared__ float red[256];
    float lmax = -1e30f;
    for (int j = tid; j < VV; j += 256) lmax = fmaxf(lmax, row[j]);
    red[tid] = lmax; __syncthreads();
    for (int off = 128; off > 0; off >>= 1) {
        if (tid < off) red[tid] = fmaxf(red[tid], red[tid + off]);
        __syncthreads();
    }
    float mx = red[0]; __syncthreads();
    float ls = 0.f;
    for (int j = tid; j < VV; j += 256) ls += __expf(row[j] - mx);
    red[tid] = ls; __syncthreads();
    for (int off = 128; off > 0; off >>= 1) {
        if (tid < off) red[tid] += red[tid + off];
        __syncthreads();
    }
    if (tid == 0) rl[m] = logf(red[0]) + mx - row[y[m]];
}

// ---------------- deterministic final reduce: loss = mean(rl)
__global__ __launch_bounds__(256) void loss_reduce(const float* __restrict__ rl,
                                                   float* __restrict__ out) {
    int tid = threadIdx.x;
    __shared__ float red[256];
    float s = 0.f;
    for (int i = tid; i < MROWS; i += 256) s += rl[i];
    red[tid] = s; __syncthreads();
    for (int off = 128; off > 0; off >>= 1) {
        if (tid < off) red[tid] += red[tid + off];
        __syncthreads();
    }
    if (tid == 0) out[0] = red[0] * (1.f / MROWS);
}

extern "C" void kernel_launch(void* const* d_in, const int* in_sizes, int n_in,
                              void* d_out, int out_size, void* d_ws, size_t ws_size,
                              hipStream_t stream) {
    const int*   x     = (const int*)d_in[0];
    const int*   y     = (const int*)d_in[1];
    const float* tok   = (const float*)d_in[2];
    const float* pos   = (const float*)d_in[3];
    const float* Wk    = (const float*)d_in[4];
    const float* Wq    = (const float*)d_in[5];
    const float* Wv    = (const float*)d_in[6];
    const float* Wproj = (const float*)d_in[7];
    const float* bproj = (const float*)d_in[8];
    const float* ln1g  = (const float*)d_in[9];
    const float* ln1b  = (const float*)d_in[10];
    const float* W1    = (const float*)d_in[11];
    const float* b1    = (const float*)d_in[12];
    const float* W2    = (const float*)d_in[13];
    const float* b2    = (const float*)d_in[14];
    const float* ln2g  = (const float*)d_in[15];
    const float* ln2b  = (const float*)d_in[16];
    const float* Wlm   = (const float*)d_in[17];
    const float* blm   = (const float*)d_in[18];

    float* logits = (float*)d_out;
    float* lossp  = (float*)d_out + ((size_t)out_size - 1);

    const size_t S_HC = (size_t)MROWS * CC;
    float* ws  = (float*)d_ws;
    float* h   = ws;
    float* qb  = h  + S_HC;
    float* kb  = qb + S_HC;
    float* vb  = kb + S_HC;
    float* ocb = vb + S_HC;
    float* ff1 = ocb + S_HC;
    float* rl  = ff1 + (size_t)MROWS * FFH;

    dim3 blk(256);
    // embedding
    embed_kernel<<<dim3((MROWS * CC + 255) / 256), blk, 0, stream>>>(x, tok, pos, h);

    for (int l = 0; l < LL; l++) {
        const float* Wk_l = Wk + (size_t)l * HH * CC * DD;
        const float* Wq_l = Wq + (size_t)l * HH * CC * DD;
        const float* Wv_l = Wv + (size_t)l * HH * CC * DD;
        const float* Wp_l = Wproj + (size_t)l * CC * CC;
        const float* bp_l = bproj + (size_t)l * CC;
        const float* W1_l = W1 + (size_t)l * CC * FFH;
        const float* b1_l = b1 + (size_t)l * FFH;
        const float* W2_l = W2 + (size_t)l * FFH * CC;
        const float* b2_l = b2 + (size_t)l * CC;

        // QKV projections
        gemm_qkv<<<dim3(CC / 128, MROWS / 128, 3), blk, 0, stream>>>(
            h, Wk_l, Wq_l, Wv_l, kb, qb, vb);
        // fused attention (k plays query role), output concat layout
        attn_kernel<<<dim3(TT, HH, BB), blk, 0, stream>>>(qb, kb, vb, ocb);
        // output projection -> qb (free now)
        gemm_rm<<<dim3(CC / 128, MROWS / 128), blk, 0, stream>>>(
            ocb, Wp_l, bp_l, qb, MROWS, CC, CC, 0);
        // h = LN(h + attn)
        resid_ln<<<dim3(MROWS), blk, 0, stream>>>(h, qb, ln1g + (size_t)l * CC, ln1b + (size_t)l * CC);
        // FFN
        gemm_rm<<<dim3(FFH / 128, MROWS / 128), blk, 0, stream>>>(
            h, W1_l, b1_l, ff1, MROWS, FFH, CC, 1);
        gemm_rm<<<dim3(CC / 128, MROWS / 128), blk, 0, stream>>>(
            ff1, W2_l, b2_l, qb, MROWS, CC, FFH, 0);
        // h = LN(h + ff)
        resid_ln<<<dim3(MROWS), blk, 0, stream>>>(h, qb, ln2g + (size_t)l * CC, ln2b + (size_t)l * CC);
    }

    // LM head -> logits (N=50257, guarded)
    gemm_rm<<<dim3((VV + 127) / 128, MROWS / 128), blk, 0, stream>>>(
        h, Wlm, blm, logits, MROWS, VV, CC, 0);
    // loss
    row_nll<<<dim3(MROWS), blk, 0, stream>>>(logits, y, rl);
    loss_reduce<<<dim3(1), blk, 0, stream>>>(rl, lossp);
}

// Round 2
// 19823.050 us; speedup vs baseline: 2.6957x; 2.6957x over previous
//
#include <hip/hip_runtime.h>
#include <hip/hip_bf16.h>
#include <math.h>

#define BB 4
#define TT 1024
#define VV 50257
#define VPAD 50304
#define CC 768
#define HH 12
#define DD 64
#define LL 12
#define FFH 3072
#define MROWS (BB*TT)   // 4096

typedef __bf16 bf16x8 __attribute__((ext_vector_type(8)));
typedef float  f32x4  __attribute__((ext_vector_type(4)));
typedef unsigned int u32;
#define AS1 __attribute__((address_space(1)))
#define AS3 __attribute__((address_space(3)))

static __device__ __forceinline__ void gload_lds16(const void* g, void* l) {
    __builtin_amdgcn_global_load_lds((const AS1 u32*)g, (AS3 u32*)l, 16, 0, 0);
}

// ---------------- embedding: h = tok_emb[x] + pos_emb[x]; also bf16 copy
__global__ void embed_kernel(const int* __restrict__ x, const float* __restrict__ tok,
                             const float* __restrict__ pos, float* __restrict__ h,
                             __hip_bfloat16* __restrict__ hb) {
    int idx = blockIdx.x * 256 + threadIdx.x;
    if (idx >= MROWS * CC) return;
    int row = idx / CC, c = idx - row * CC;
    int id = x[row];
    float v = tok[(size_t)id * CC + c] + pos[(size_t)id * CC + c];
    h[idx] = v;
    hb[idx] = __float2bfloat16(v);
}

// ---------------- convert + transpose: out[b][n][k] = (n<Nin ? in[b][k][n] : 0), bf16
__global__ __launch_bounds__(256) void cvtT_mat(const float* __restrict__ in,
                                                __hip_bfloat16* __restrict__ out,
                                                int K, int Nin,
                                                size_t ibs, size_t obs) {
    __shared__ float t[32][33];
    const float* ip = in + blockIdx.z * ibs;
    __hip_bfloat16* op = out + blockIdx.z * obs;
    int n0 = blockIdx.x * 32, k0 = blockIdx.y * 32;
    int tx = threadIdx.x & 31, ty = threadIdx.x >> 5;   // 32x8
    #pragma unroll
    for (int i = 0; i < 4; i++) {
        int k = k0 + ty + i * 8, n = n0 + tx;
        t[ty + i * 8][tx] = (n < Nin) ? ip[(size_t)k * Nin + n] : 0.f;
    }
    __syncthreads();
    #pragma unroll
    for (int i = 0; i < 4; i++) {
        int n = n0 + ty + i * 8, k = k0 + tx;
        op[(size_t)n * K + k] = __float2bfloat16(t[tx][ty + i * 8]);
    }
}

// ---------------- QKV weights (L,H,C,D) -> per-layer [768][768] bf16 with row n=h*64+d, col c
__global__ __launch_bounds__(256) void cvtT_qkv(const float* __restrict__ Wk,
                                                const float* __restrict__ Wq,
                                                const float* __restrict__ Wv,
                                                __hip_bfloat16* __restrict__ kT,
                                                __hip_bfloat16* __restrict__ qT,
                                                __hip_bfloat16* __restrict__ vT) {
    // grid: (24, 2, 3*144)
    int z = blockIdx.z;
    int tensor = z / 144, lh = z % 144;
    int l = lh / HH, hh = lh % HH;
    const float* in = (tensor == 0 ? Wk : tensor == 1 ? Wq : Wv) + (size_t)lh * CC * DD;
    __hip_bfloat16* out = (tensor == 0 ? kT : tensor == 1 ? qT : vT)
                          + ((size_t)l * CC + hh * DD) * CC;
    __shared__ float t[32][33];
    int c0 = blockIdx.x * 32, d0 = blockIdx.y * 32;
    int tx = threadIdx.x & 31, ty = threadIdx.x >> 5;
    #pragma unroll
    for (int i = 0; i < 4; i++)
        t[ty + i * 8][tx] = in[(size_t)(c0 + ty + i * 8) * DD + d0 + tx];
    __syncthreads();
    #pragma unroll
    for (int i = 0; i < 4; i++)
        out[(size_t)(d0 + ty + i * 8) * CC + c0 + tx] = __float2bfloat16(t[tx][ty + i * 8]);
}

// ---------------- MFMA GEMM: C = A[M,K]bf16 @ Bt[Npad,K]bf16^T (+bias, relu)
// 128x128 tile, BK=64, 4 waves (2x2), 4x4 frags of 16x16x32 per wave.
__global__ __launch_bounds__(256) void gemm_mfma(const __hip_bfloat16* __restrict__ A,
                                                 const __hip_bfloat16* __restrict__ Bt,
                                                 const float* __restrict__ bias,
                                                 float* __restrict__ Cf,
                                                 __hip_bfloat16* __restrict__ Cb,
                                                 int M, int N, int K, int relu) {
    __shared__ __hip_bfloat16 As[128][64];
    __shared__ __hip_bfloat16 Bs[128][64];
    int tid = threadIdx.x;
    int l = tid & 63, w = tid >> 6;
    int wr = w >> 1, wc = w & 1;
    int bm = blockIdx.y * 128, bn = blockIdx.x * 128;

    f32x4 acc[4][4] = {};

    for (int k0 = 0; k0 < K; k0 += 64) {
        __syncthreads();
        #pragma unroll
        for (int it = 0; it < 4; it++) {
            int chunk = w * 4 + it;
            int e = chunk * 512 + l * 8;       // bf16 element index in 128x64 tile
            int m = e >> 6, kk = e & 63;
            gload_lds16(A + (size_t)(bm + m) * K + k0 + kk,
                        (char*)&As[0][0] + chunk * 1024);
            gload_lds16(Bt + (size_t)(bn + m) * K + k0 + kk,
                        (char*)&Bs[0][0] + chunk * 1024);
        }
        __syncthreads();
        #pragma unroll
        for (int ks = 0; ks < 2; ks++) {
            bf16x8 af[4], bfr[4];
            #pragma unroll
            for (int i = 0; i < 4; i++)
                af[i] = *(const bf16x8*)&As[wr * 64 + i * 16 + (l & 15)][ks * 32 + (l >> 4) * 8];
            #pragma unroll
            for (int j = 0; j < 4; j++)
                bfr[j] = *(const bf16x8*)&Bs[wc * 64 + j * 16 + (l & 15)][ks * 32 + (l >> 4) * 8];
            #pragma unroll
            for (int i = 0; i < 4; i++)
                #pragma unroll
                for (int j = 0; j < 4; j++)
                    acc[i][j] = __builtin_amdgcn_mfma_f32_16x16x32_bf16(af[i], bfr[j], acc[i][j], 0, 0, 0);
        }
    }
    #pragma unroll
    for (int i = 0; i < 4; i++) {
        int row = bm + wr * 64 + i * 16 + (l >> 4) * 4;
        #pragma unroll
        for (int j = 0; j < 4; j++) {
            int col = bn + wc * 64 + j * 16 + (l & 15);
            if (col < N) {
                float bv = bias ? bias[col] : 0.f;
                #pragma unroll
                for (int r = 0; r < 4; r++) {
                    float v = acc[i][j][r] + bv;
                    if (relu) v = fmaxf(v, 0.f);
                    if (Cf) Cf[(size_t)(row + r) * N + col] = v;
                    if (Cb) Cb[(size_t)(row + r) * N + col] = __float2bfloat16(v);
                }
            }
        }
    }
}

// ---------------- QKV MFMA GEMM: A=hb [4096,768], Bt per z, out f32 [B,H,T,D]
__global__ __launch_bounds__(256) void gemm_qkv_mfma(const __hip_bfloat16* __restrict__ A,
                                                     const __hip_bfloat16* __restrict__ kT,
                                                     const __hip_bfloat16* __restrict__ qT,
                                                     const __hip_bfloat16* __restrict__ vT,
                                                     float* __restrict__ ko,
                                                     float* __restrict__ qo,
                                                     float* __restrict__ vo) {
    const __hip_bfloat16* Bt = (blockIdx.z == 0) ? kT : (blockIdx.z == 1) ? qT : vT;
    float* O = (blockIdx.z == 0) ? ko : (blockIdx.z == 1) ? qo : vo;
    __shared__ __hip_bfloat16 As[128][64];
    __shared__ __hip_bfloat16 Bs[128][64];
    int tid = threadIdx.x;
    int l = tid & 63, w = tid >> 6;
    int wr = w >> 1, wc = w & 1;
    int bm = blockIdx.y * 128, bn = blockIdx.x * 128;

    f32x4 acc[4][4] = {};

    for (int k0 = 0; k0 < CC; k0 += 64) {
        __syncthreads();
        #pragma unroll
        for (int it = 0; it < 4; it++) {
            int chunk = w * 4 + it;
            int e = chunk * 512 + l * 8;
            int m = e >> 6, kk = e & 63;
            gload_lds16(A + (size_t)(bm + m) * CC + k0 + kk,
                        (char*)&As[0][0] + chunk * 1024);
            gload_lds16(Bt + (size_t)(bn + m) * CC + k0 + kk,
                        (char*)&Bs[0][0] + chunk * 1024);
        }
        __syncthreads();
        #pragma unroll
        for (int ks = 0; ks < 2; ks++) {
            bf16x8 af[4], bfr[4];
            #pragma unroll
            for (int i = 0; i < 4; i++)
                af[i] = *(const bf16x8*)&As[wr * 64 + i * 16 + (l & 15)][ks * 32 + (l >> 4) * 8];
            #pragma unroll
            for (int j = 0; j < 4; j++)
                bfr[j] = *(const bf16x8*)&Bs[wc * 64 + j * 16 + (l & 15)][ks * 32 + (l >> 4) * 8];
            #pragma unroll
            for (int i = 0; i < 4; i++)
                #pragma unroll
                for (int j = 0; j < 4; j++)
                    acc[i][j] = __builtin_amdgcn_mfma_f32_16x16x32_bf16(af[i], bfr[j], acc[i][j], 0, 0, 0);
        }
    }
    #pragma unroll
    for (int i = 0; i < 4; i++) {
        int row = bm + wr * 64 + i * 16 + (l >> 4) * 4;
        #pragma unroll
        for (int j = 0; j < 4; j++) {
            int col = bn + wc * 64 + j * 16 + (l & 15);
            int head = col >> 6, d = col & 63;
            #pragma unroll
            for (int r = 0; r < 4; r++) {
                int m = row + r;
                int b = m >> 10, t = m & 1023;
                O[(((size_t)(b * HH + head)) * TT + t) * DD + d] = acc[i][j][r];
            }
        }
    }
}

// ---------------- fused attention row (quirk: k is the query); out bf16 concat layout
__global__ __launch_bounds__(256) void attn_kernel(const float* __restrict__ q,
                                                   const float* __restrict__ k,
                                                   const float* __restrict__ v,
                                                   __hip_bfloat16* __restrict__ oc) {
    int t = blockIdx.x, hh = blockIdx.y, b = blockIdx.z;
    int tid = threadIdx.x;
    __shared__ float kv[64];
    __shared__ float sc[TT];
    __shared__ float red[256];
    __shared__ float pacc[4][64];
    const size_t base = ((size_t)(b * HH + hh)) * TT * DD;
    if (tid < 64) kv[tid] = k[base + (size_t)t * DD + tid];
    __syncthreads();
    float lmax = -1e30f;
    for (int s = tid; s <= t; s += 256) {
        const float* qs = q + base + (size_t)s * DD;
        float dot = 0.f;
        #pragma unroll
        for (int d = 0; d < 64; d++) dot += kv[d] * qs[d];
        dot *= 0.125f;
        sc[s] = dot;
        lmax = fmaxf(lmax, dot);
    }
    red[tid] = lmax; __syncthreads();
    for (int off = 128; off > 0; off >>= 1) {
        if (tid < off) red[tid] = fmaxf(red[tid], red[tid + off]);
        __syncthreads();
    }
    float mx = red[0]; __syncthreads();
    float lsum = 0.f;
    for (int s = tid; s <= t; s += 256) {
        float e = __expf(sc[s] - mx);
        sc[s] = e;
        lsum += e;
    }
    red[tid] = lsum; __syncthreads();
    for (int off = 128; off > 0; off >>= 1) {
        if (tid < off) red[tid] += red[tid + off];
        __syncthreads();
    }
    float inv = 1.f / red[0];
    int d = tid & 63, part = tid >> 6;
    float acc = 0.f;
    for (int s = part; s <= t; s += 4) acc += sc[s] * v[base + (size_t)s * DD + d];
    pacc[part][d] = acc;
    __syncthreads();
    if (tid < 64) {
        float o = (pacc[0][tid] + pacc[1][tid] + pacc[2][tid] + pacc[3][tid]) * inv;
        oc[((size_t)(b * TT + t)) * CC + hh * DD + tid] = __float2bfloat16(o);
    }
}

// ---------------- h = LN(h + t); writes f32 h and bf16 hb
__global__ __launch_bounds__(256) void resid_ln(float* __restrict__ h,
                                                const float* __restrict__ t,
                                                const float* __restrict__ g,
                                                const float* __restrict__ bta,
                                                __hip_bfloat16* __restrict__ hb) {
    int row = blockIdx.x;
    int tid = threadIdx.x;
    __shared__ float red[256];
    float x[3];
    float s = 0.f;
    #pragma unroll
    for (int i = 0; i < 3; i++) {
        int c = tid + i * 256;
        x[i] = h[(size_t)row * CC + c] + t[(size_t)row * CC + c];
        s += x[i];
    }
    red[tid] = s; __syncthreads();
    for (int off = 128; off > 0; off >>= 1) {
        if (tid < off) red[tid] += red[tid + off];
        __syncthreads();
    }
    float mean = red[0] * (1.f / CC); __syncthreads();
    float s2 = 0.f;
    #pragma unroll
    for (int i = 0; i < 3; i++) { float dd = x[i] - mean; s2 += dd * dd; }
    red[tid] = s2; __syncthreads();
    for (int off = 128; off > 0; off >>= 1) {
        if (tid < off) red[tid] += red[tid + off];
        __syncthreads();
    }
    float inv = rsqrtf(red[0] * (1.f / CC) + 1e-5f);
    #pragma unroll
    for (int i = 0; i < 3; i++) {
        int c = tid + i * 256;
        float o = (x[i] - mean) * inv * g[c] + bta[c];
        h[(size_t)row * CC + c] = o;
        hb[(size_t)row * CC + c] = __float2bfloat16(o);
    }
}

// ---------------- per-row NLL
__global__ __launch_bounds__(256) void row_nll(const float* __restrict__ logits,
                                               const int* __restrict__ y,
                                               float* __restrict__ rl) {
    int m = blockIdx.x, tid = threadIdx.x;
    const float* row = logits + (size_t)m * VV;
    __shared__ float red[256];
    float lmax = -1e30f;
    for (int j = tid; j < VV; j += 256) lmax = fmaxf(lmax, row[j]);
    red[tid] = lmax; __syncthreads();
    for (int off = 128; off > 0; off >>= 1) {
        if (tid < off) red[tid] = fmaxf(red[tid], red[tid + off]);
        __syncthreads();
    }
    float mx = red[0]; __syncthreads();
    float ls = 0.f;
    for (int j = tid; j < VV; j += 256) ls += __expf(row[j] - mx);
    red[tid] = ls; __syncthreads();
    for (int off = 128; off > 0; off >>= 1) {
        if (tid < off) red[tid] += red[tid + off];
        __syncthreads();
    }
    if (tid == 0) rl[m] = logf(red[0]) + mx - row[y[m]];
}

__global__ __launch_bounds__(256) void loss_reduce(const float* __restrict__ rl,
                                                   float* __restrict__ out) {
    int tid = threadIdx.x;
    __shared__ float red[256];
    float s = 0.f;
    for (int i = tid; i < MROWS; i += 256) s += rl[i];
    red[tid] = s; __syncthreads();
    for (int off = 128; off > 0; off >>= 1) {
        if (tid < off) red[tid] += red[tid + off];
        __syncthreads();
    }
    if (tid == 0) out[0] = red[0] * (1.f / MROWS);
}

extern "C" void kernel_launch(void* const* d_in, const int* in_sizes, int n_in,
                              void* d_out, int out_size, void* d_ws, size_t ws_size,
                              hipStream_t stream) {
    const int*   x     = (const int*)d_in[0];
    const int*   y     = (const int*)d_in[1];
    const float* tok   = (const float*)d_in[2];
    const float* pos   = (const float*)d_in[3];
    const float* Wk    = (const float*)d_in[4];
    const float* Wq    = (const float*)d_in[5];
    const float* Wv    = (const float*)d_in[6];
    const float* Wproj = (const float*)d_in[7];
    const float* bproj = (const float*)d_in[8];
    const float* ln1g  = (const float*)d_in[9];
    const float* ln1b  = (const float*)d_in[10];
    const float* W1    = (const float*)d_in[11];
    const float* b1    = (const float*)d_in[12];
    const float* W2    = (const float*)d_in[13];
    const float* b2    = (const float*)d_in[14];
    const float* ln2g  = (const float*)d_in[15];
    const float* ln2b  = (const float*)d_in[16];
    const float* Wlm   = (const float*)d_in[17];
    const float* blm   = (const float*)d_in[18];

    float* logits = (float*)d_out;
    float* lossp  = (float*)d_out + ((size_t)out_size - 1);

    char* p = (char*)d_ws;
    auto alloc = [&](size_t bytes) { char* r = p; p += (bytes + 255) & ~255ULL; return r; };
    const size_t S_HC = (size_t)MROWS * CC;

    float* h   = (float*)alloc(S_HC * 4);
    float* kb  = (float*)alloc(S_HC * 4);
    float* qb  = (float*)alloc(S_HC * 4);
    float* vb  = (float*)alloc(S_HC * 4);
    float* rl  = (float*)alloc(MROWS * 4);
    __hip_bfloat16* hb   = (__hip_bfloat16*)alloc(S_HC * 2);
    __hip_bfloat16* ocb  = (__hip_bfloat16*)alloc(S_HC * 2);
    __hip_bfloat16* ff1b = (__hip_bfloat16*)alloc((size_t)MROWS * FFH * 2);
    __hip_bfloat16* kT   = (__hip_bfloat16*)alloc((size_t)LL * CC * CC * 2);
    __hip_bfloat16* qT   = (__hip_bfloat16*)alloc((size_t)LL * CC * CC * 2);
    __hip_bfloat16* vT   = (__hip_bfloat16*)alloc((size_t)LL * CC * CC * 2);
    __hip_bfloat16* pT   = (__hip_bfloat16*)alloc((size_t)LL * CC * CC * 2);
    __hip_bfloat16* w1T  = (__hip_bfloat16*)alloc((size_t)LL * CC * FFH * 2);
    __hip_bfloat16* w2T  = (__hip_bfloat16*)alloc((size_t)LL * FFH * CC * 2);
    __hip_bfloat16* lmT  = (__hip_bfloat16*)alloc((size_t)VPAD * CC * 2);

    dim3 blk(256);

    // ---- weight conversion (every launch; deterministic)
    cvtT_qkv<<<dim3(24, 2, 3 * 144), blk, 0, stream>>>(Wk, Wq, Wv, kT, qT, vT);
    cvtT_mat<<<dim3(24, 24, LL), blk, 0, stream>>>(Wproj, pT, CC, CC,
                                                   (size_t)CC * CC, (size_t)CC * CC);
    cvtT_mat<<<dim3(96, 24, LL), blk, 0, stream>>>(W1, w1T, CC, FFH,
                                                   (size_t)CC * FFH, (size_t)FFH * CC);
    cvtT_mat<<<dim3(24, 96, LL), blk, 0, stream>>>(W2, w2T, FFH, CC,
                                                   (size_t)FFH * CC, (size_t)CC * FFH);
    cvtT_mat<<<dim3(VPAD / 32, 24, 1), blk, 0, stream>>>(Wlm, lmT, CC, VV, 0, 0);

    // ---- embedding
    embed_kernel<<<dim3((MROWS * CC + 255) / 256), blk, 0, stream>>>(x, tok, pos, h, hb);

    for (int l = 0; l < LL; l++) {
        const __hip_bfloat16* kT_l = kT + (size_t)l * CC * CC;
        const __hip_bfloat16* qT_l = qT + (size_t)l * CC * CC;
        const __hip_bfloat16* vT_l = vT + (size_t)l * CC * CC;
        const __hip_bfloat16* pT_l = pT + (size_t)l * CC * CC;
        const __hip_bfloat16* w1T_l = w1T + (size_t)l * CC * FFH;
        const __hip_bfloat16* w2T_l = w2T + (size_t)l * FFH * CC;

        // QKV projections (MFMA)
        gemm_qkv_mfma<<<dim3(CC / 128, MROWS / 128, 3), blk, 0, stream>>>(
            hb, kT_l, qT_l, vT_l, kb, qb, vb);
        // attention (k plays query role), bf16 concat output
        attn_kernel<<<dim3(TT, HH, BB), blk, 0, stream>>>(qb, kb, vb, ocb);
        // output projection -> kb (f32, attn residual)
        gemm_mfma<<<dim3(CC / 128, MROWS / 128), blk, 0, stream>>>(
            ocb, pT_l, bproj + (size_t)l * CC, kb, (__hip_bfloat16*)nullptr,
            MROWS, CC, CC, 0);
        resid_ln<<<dim3(MROWS), blk, 0, stream>>>(h, kb, ln1g + (size_t)l * CC,
                                                  ln1b + (size_t)l * CC, hb);
        // FFN1: relu, bf16-only output
        gemm_mfma<<<dim3(FFH / 128, MROWS / 128), blk, 0, stream>>>(
            hb, w1T_l, b1 + (size_t)l * FFH, (float*)nullptr, ff1b,
            MROWS, FFH, CC, 1);
        // FFN2 -> kb (f32)
        gemm_mfma<<<dim3(CC / 128, MROWS / 128), blk, 0, stream>>>(
            ff1b, w2T_l, b2 + (size_t)l * CC, kb, (__hip_bfloat16*)nullptr,
            MROWS, CC, FFH, 0);
        resid_ln<<<dim3(MROWS), blk, 0, stream>>>(h, kb, ln2g + (size_t)l * CC,
                                                  ln2b + (size_t)l * CC, hb);
    }

    // LM head -> logits
    gemm_mfma<<<dim3(VPAD / 128, MROWS / 128), blk, 0, stream>>>(
        hb, lmT, blm, logits, (__hip_bfloat16*)nullptr, MROWS, VV, CC, 0);
    // loss
    row_nll<<<dim3(MROWS), blk, 0, stream>>>(logits, y, rl);
    loss_reduce<<<dim3(1), blk, 0, stream>>>(rl, lossp);
}

// Round 3
// 5040.676 us; speedup vs baseline: 10.6010x; 3.9326x over previous
//
#include <hip/hip_runtime.h>
#include <hip/hip_bf16.h>
#include <math.h>

#define BB 4
#define TT 1024
#define VV 50257
#define VPAD 50304
#define CC 768
#define HH 12
#define DD 64
#define LL 12
#define FFH 3072
#define MROWS (BB*TT)   // 4096
#define QBLK 128
#define KVBLK 64

typedef __bf16 bf16x8 __attribute__((ext_vector_type(8)));
typedef float  f32x4  __attribute__((ext_vector_type(4)));
typedef unsigned int u32;
#define AS1 __attribute__((address_space(1)))
#define AS3 __attribute__((address_space(3)))

static __device__ __forceinline__ void gload_lds16(const void* g, void* l) {
    __builtin_amdgcn_global_load_lds((const AS1 u32*)g, (AS3 u32*)l, 16, 0, 0);
}

// ---------------- embedding: h = tok_emb[x] + pos_emb[x]; also bf16 copy
__global__ void embed_kernel(const int* __restrict__ x, const float* __restrict__ tok,
                             const float* __restrict__ pos, float* __restrict__ h,
                             __hip_bfloat16* __restrict__ hb) {
    int idx = blockIdx.x * 256 + threadIdx.x;
    if (idx >= MROWS * CC) return;
    int row = idx / CC, c = idx - row * CC;
    int id = x[row];
    float v = tok[(size_t)id * CC + c] + pos[(size_t)id * CC + c];
    h[idx] = v;
    hb[idx] = __float2bfloat16(v);
}

// ---------------- convert + transpose: out[b][n][k] = (n<Nin ? in[b][k][n] : 0), bf16
__global__ __launch_bounds__(256) void cvtT_mat(const float* __restrict__ in,
                                                __hip_bfloat16* __restrict__ out,
                                                int K, int Nin,
                                                size_t ibs, size_t obs) {
    __shared__ float t[32][33];
    const float* ip = in + blockIdx.z * ibs;
    __hip_bfloat16* op = out + blockIdx.z * obs;
    int n0 = blockIdx.x * 32, k0 = blockIdx.y * 32;
    int tx = threadIdx.x & 31, ty = threadIdx.x >> 5;   // 32x8
    #pragma unroll
    for (int i = 0; i < 4; i++) {
        int k = k0 + ty + i * 8, n = n0 + tx;
        t[ty + i * 8][tx] = (n < Nin) ? ip[(size_t)k * Nin + n] : 0.f;
    }
    __syncthreads();
    #pragma unroll
    for (int i = 0; i < 4; i++) {
        int n = n0 + ty + i * 8, k = k0 + tx;
        op[(size_t)n * K + k] = __float2bfloat16(t[tx][ty + i * 8]);
    }
}

// ---------------- QKV weights (L,H,C,D) -> per-layer [768][768] bf16, row n=h*64+d, col c
__global__ __launch_bounds__(256) void cvtT_qkv(const float* __restrict__ Wk,
                                                const float* __restrict__ Wq,
                                                const float* __restrict__ Wv,
                                                __hip_bfloat16* __restrict__ kT,
                                                __hip_bfloat16* __restrict__ qT,
                                                __hip_bfloat16* __restrict__ vT) {
    int z = blockIdx.z;
    int tensor = z / 144, lh = z % 144;
    int l = lh / HH, hh = lh % HH;
    const float* in = (tensor == 0 ? Wk : tensor == 1 ? Wq : Wv) + (size_t)lh * CC * DD;
    __hip_bfloat16* out = (tensor == 0 ? kT : tensor == 1 ? qT : vT)
                          + ((size_t)l * CC + hh * DD) * CC;
    __shared__ float t[32][33];
    int c0 = blockIdx.x * 32, d0 = blockIdx.y * 32;
    int tx = threadIdx.x & 31, ty = threadIdx.x >> 5;
    #pragma unroll
    for (int i = 0; i < 4; i++)
        t[ty + i * 8][tx] = in[(size_t)(c0 + ty + i * 8) * DD + d0 + tx];
    __syncthreads();
    #pragma unroll
    for (int i = 0; i < 4; i++)
        out[(size_t)(d0 + ty + i * 8) * CC + c0 + tx] = __float2bfloat16(t[tx][ty + i * 8]);
}

// ---------------- MFMA GEMM: C = A[M,K]bf16 @ Bt[Npad,K]bf16^T (+bias, relu)
__global__ __launch_bounds__(256) void gemm_mfma(const __hip_bfloat16* __restrict__ A,
                                                 const __hip_bfloat16* __restrict__ Bt,
                                                 const float* __restrict__ bias,
                                                 float* __restrict__ Cf,
                                                 __hip_bfloat16* __restrict__ Cb,
                                                 int M, int N, int K, int relu) {
    __shared__ __hip_bfloat16 As[128][64];
    __shared__ __hip_bfloat16 Bs[128][64];
    int tid = threadIdx.x;
    int l = tid & 63, w = tid >> 6;
    int wr = w >> 1, wc = w & 1;
    int bm = blockIdx.y * 128, bn = blockIdx.x * 128;

    f32x4 acc[4][4] = {};

    for (int k0 = 0; k0 < K; k0 += 64) {
        __syncthreads();
        #pragma unroll
        for (int it = 0; it < 4; it++) {
            int chunk = w * 4 + it;
            int e = chunk * 512 + l * 8;
            int m = e >> 6, kk = e & 63;
            gload_lds16(A + (size_t)(bm + m) * K + k0 + kk,
                        (char*)&As[0][0] + chunk * 1024);
            gload_lds16(Bt + (size_t)(bn + m) * K + k0 + kk,
                        (char*)&Bs[0][0] + chunk * 1024);
        }
        __syncthreads();
        #pragma unroll
        for (int ks = 0; ks < 2; ks++) {
            bf16x8 af[4], bfr[4];
            #pragma unroll
            for (int i = 0; i < 4; i++)
                af[i] = *(const bf16x8*)&As[wr * 64 + i * 16 + (l & 15)][ks * 32 + (l >> 4) * 8];
            #pragma unroll
            for (int j = 0; j < 4; j++)
                bfr[j] = *(const bf16x8*)&Bs[wc * 64 + j * 16 + (l & 15)][ks * 32 + (l >> 4) * 8];
            #pragma unroll
            for (int i = 0; i < 4; i++)
                #pragma unroll
                for (int j = 0; j < 4; j++)
                    acc[i][j] = __builtin_amdgcn_mfma_f32_16x16x32_bf16(af[i], bfr[j], acc[i][j], 0, 0, 0);
        }
    }
    #pragma unroll
    for (int i = 0; i < 4; i++) {
        int row = bm + wr * 64 + i * 16 + (l >> 4) * 4;
        #pragma unroll
        for (int j = 0; j < 4; j++) {
            int col = bn + wc * 64 + j * 16 + (l & 15);
            if (col < N) {
                float bv = bias ? bias[col] : 0.f;
                #pragma unroll
                for (int r = 0; r < 4; r++) {
                    float v = acc[i][j][r] + bv;
                    if (relu) v = fmaxf(v, 0.f);
                    if (Cf) Cf[(size_t)(row + r) * N + col] = v;
                    if (Cb) Cb[(size_t)(row + r) * N + col] = __float2bfloat16(v);
                }
            }
        }
    }
}

// ---------------- QKV MFMA GEMM: A=hb [4096,768]; k,q -> bf16 [B,H,T,D]; v -> bf16 [B,H,D,T]
__global__ __launch_bounds__(256) void gemm_qkv_mfma(const __hip_bfloat16* __restrict__ A,
                                                     const __hip_bfloat16* __restrict__ kT,
                                                     const __hip_bfloat16* __restrict__ qT,
                                                     const __hip_bfloat16* __restrict__ vT,
                                                     __hip_bfloat16* __restrict__ ko,
                                                     __hip_bfloat16* __restrict__ qo,
                                                     __hip_bfloat16* __restrict__ vto) {
    const __hip_bfloat16* Bt = (blockIdx.z == 0) ? kT : (blockIdx.z == 1) ? qT : vT;
    __shared__ __hip_bfloat16 As[128][64];
    __shared__ __hip_bfloat16 Bs[128][64];
    int tid = threadIdx.x;
    int l = tid & 63, w = tid >> 6;
    int wr = w >> 1, wc = w & 1;
    int bm = blockIdx.y * 128, bn = blockIdx.x * 128;

    f32x4 acc[4][4] = {};

    for (int k0 = 0; k0 < CC; k0 += 64) {
        __syncthreads();
        #pragma unroll
        for (int it = 0; it < 4; it++) {
            int chunk = w * 4 + it;
            int e = chunk * 512 + l * 8;
            int m = e >> 6, kk = e & 63;
            gload_lds16(A + (size_t)(bm + m) * CC + k0 + kk,
                        (char*)&As[0][0] + chunk * 1024);
            gload_lds16(Bt + (size_t)(bn + m) * CC + k0 + kk,
                        (char*)&Bs[0][0] + chunk * 1024);
        }
        __syncthreads();
        #pragma unroll
        for (int ks = 0; ks < 2; ks++) {
            bf16x8 af[4], bfr[4];
            #pragma unroll
            for (int i = 0; i < 4; i++)
                af[i] = *(const bf16x8*)&As[wr * 64 + i * 16 + (l & 15)][ks * 32 + (l >> 4) * 8];
            #pragma unroll
            for (int j = 0; j < 4; j++)
                bfr[j] = *(const bf16x8*)&Bs[wc * 64 + j * 16 + (l & 15)][ks * 32 + (l >> 4) * 8];
            #pragma unroll
            for (int i = 0; i < 4; i++)
                #pragma unroll
                for (int j = 0; j < 4; j++)
                    acc[i][j] = __builtin_amdgcn_mfma_f32_16x16x32_bf16(af[i], bfr[j], acc[i][j], 0, 0, 0);
        }
    }
    int zz = blockIdx.z;
    #pragma unroll
    for (int i = 0; i < 4; i++) {
        int row = bm + wr * 64 + i * 16 + (l >> 4) * 4;
        #pragma unroll
        for (int j = 0; j < 4; j++) {
            int col = bn + wc * 64 + j * 16 + (l & 15);
            int head = col >> 6, d = col & 63;
            #pragma unroll
            for (int r = 0; r < 4; r++) {
                int m = row + r;
                int b = m >> 10, t = m & 1023;
                __hip_bfloat16 val = __float2bfloat16(acc[i][j][r]);
                if (zz == 0)      ko[(((size_t)(b * HH + head)) * TT + t) * DD + d] = val;
                else if (zz == 1) qo[(((size_t)(b * HH + head)) * TT + t) * DD + d] = val;
                else              vto[(((size_t)(b * HH + head)) * DD + d) * TT + t] = val;
            }
        }
    }
}

// ---------------- MFMA flash attention (quirk: k plays query role)
// kq = k [B,H,T,D], qk = q [B,H,T,D], vt = V^T [B,H,D,T]; out bf16 concat [B,T,C]
// block: (qtile, h, b); 4 waves x 32 rows; KV tiles of 64 with online softmax.
__global__ __launch_bounds__(256) void attn_mfma(const __hip_bfloat16* __restrict__ kq,
                                                 const __hip_bfloat16* __restrict__ qk,
                                                 const __hip_bfloat16* __restrict__ vt,
                                                 __hip_bfloat16* __restrict__ oc) {
    __shared__ __hip_bfloat16 Qs[KVBLK * 64];    // "keys" tile, XOR-swizzled rows of 128B
    __shared__ __hip_bfloat16 Vs[64 * KVBLK];    // V^T tile, XOR-swizzled
    __shared__ __hip_bfloat16 Ps[QBLK * KVBLK];  // P tile, XOR-swizzled
    int tid = threadIdx.x;
    int l = tid & 63, w = tid >> 6;
    int t0 = blockIdx.x * QBLK;
    size_t bh = (size_t)(blockIdx.z * HH + blockIdx.y);
    const __hip_bfloat16* kqp = kq + bh * TT * DD;
    const __hip_bfloat16* qkp = qk + bh * TT * DD;
    const __hip_bfloat16* vtp = vt + bh * DD * TT;

    // A-frags: k-rows for this wave (rows t0 + w*32 + i*16 + (l&15))
    bf16x8 af[2][2];
    #pragma unroll
    for (int i = 0; i < 2; i++)
        #pragma unroll
        for (int ks = 0; ks < 2; ks++)
            af[i][ks] = *(const bf16x8*)&kqp[(size_t)(t0 + w * 32 + i * 16 + (l & 15)) * DD
                                             + ks * 32 + (l >> 4) * 8];

    f32x4 acc_o[2][4] = {};
    float mrow[2][4], lrow[2][4];
    #pragma unroll
    for (int i = 0; i < 2; i++)
        #pragma unroll
        for (int r = 0; r < 4; r++) { mrow[i][r] = -1e30f; lrow[i][r] = 0.f; }

    for (int s0 = 0; s0 < t0 + QBLK; s0 += KVBLK) {
        __syncthreads();
        // stage keys + V^T tiles (8KB each): linear LDS dest, pre-swizzled global source
        #pragma unroll
        for (int it = 0; it < 2; it++) {
            int chunk = w * 2 + it;                 // 8 chunks of 1KB
            int o = chunk * 1024 + l * 16;          // physical LDS byte offset
            int row = o >> 7;                       // 128B rows
            int cb = (o & 127) ^ ((row & 7) << 4);  // swizzled source column byte
            gload_lds16(qkp + (size_t)(s0 + row) * DD + (cb >> 1),
                        (char*)Qs + chunk * 1024);
            gload_lds16(vtp + (size_t)row * TT + s0 + (cb >> 1),
                        (char*)Vs + chunk * 1024);
        }
        __syncthreads();

        // S = k @ q^T for this tile
        f32x4 sa[2][4] = {};
        #pragma unroll
        for (int ks = 0; ks < 2; ks++) {
            bf16x8 bfr[4];
            #pragma unroll
            for (int j = 0; j < 4; j++) {
                int row = j * 16 + (l & 15);
                int cb = (ks * 64 + (l >> 4) * 16) ^ ((row & 7) << 4);
                bfr[j] = *(const bf16x8*)((const char*)Qs + row * 128 + cb);
            }
            #pragma unroll
            for (int i = 0; i < 2; i++)
                #pragma unroll
                for (int j = 0; j < 4; j++)
                    sa[i][j] = __builtin_amdgcn_mfma_f32_16x16x32_bf16(af[i][ks], bfr[j], sa[i][j], 0, 0, 0);
        }

        // online softmax (rows held as col=lane&15 groups; reduce over 16 lanes)
        #pragma unroll
        for (int i = 0; i < 2; i++) {
            #pragma unroll
            for (int r = 0; r < 4; r++) {
                int t = t0 + w * 32 + i * 16 + (l >> 4) * 4 + r;
                float pv[4];
                float rmax = -1e30f;
                #pragma unroll
                for (int j = 0; j < 4; j++) {
                    int s = s0 + j * 16 + (l & 15);
                    float v = sa[i][j][r] * 0.125f;
                    v = (s <= t) ? v : -1e30f;
                    pv[j] = v;
                    rmax = fmaxf(rmax, v);
                }
                #pragma unroll
                for (int msk = 1; msk < 16; msk <<= 1)
                    rmax = fmaxf(rmax, __shfl_xor(rmax, msk));
                float mo = mrow[i][r];
                float mn = fmaxf(mo, rmax);
                float fac = __expf(mo - mn);
                float ls = 0.f;
                int prow = w * 32 + i * 16 + (l >> 4) * 4 + r;
                #pragma unroll
                for (int j = 0; j < 4; j++) {
                    float e = __expf(pv[j] - mn);
                    ls += e;
                    int cb = (j * 32 + (l & 15) * 2) ^ ((prow & 7) << 4);
                    *(__hip_bfloat16*)((char*)Ps + prow * 128 + cb) = __float2bfloat16(e);
                }
                #pragma unroll
                for (int msk = 1; msk < 16; msk <<= 1)
                    ls += __shfl_xor(ls, msk);
                mrow[i][r] = mn;
                lrow[i][r] = lrow[i][r] * fac + ls;
                #pragma unroll
                for (int jd = 0; jd < 4; jd++)
                    acc_o[i][jd][r] *= fac;
            }
        }
        __syncthreads();   // P writes drained (also covers same-wave RAW)

        // O += P @ V^T^T : A = P rows (t), B = Vt rows (d), k = s
        #pragma unroll
        for (int ks = 0; ks < 2; ks++) {
            bf16x8 pa[2], vf[4];
            #pragma unroll
            for (int i = 0; i < 2; i++) {
                int row = w * 32 + i * 16 + (l & 15);
                int cb = (ks * 64 + (l >> 4) * 16) ^ ((row & 7) << 4);
                pa[i] = *(const bf16x8*)((const char*)Ps + row * 128 + cb);
            }
            #pragma unroll
            for (int jd = 0; jd < 4; jd++) {
                int row = jd * 16 + (l & 15);
                int cb = (ks * 64 + (l >> 4) * 16) ^ ((row & 7) << 4);
                vf[jd] = *(const bf16x8*)((const char*)Vs + row * 128 + cb);
            }
            #pragma unroll
            for (int i = 0; i < 2; i++)
                #pragma unroll
                for (int jd = 0; jd < 4; jd++)
                    acc_o[i][jd] = __builtin_amdgcn_mfma_f32_16x16x32_bf16(pa[i], vf[jd], acc_o[i][jd], 0, 0, 0);
        }
    }

    // epilogue: divide by softmax denom, write concat layout
    int b = blockIdx.z, hh = blockIdx.y;
    #pragma unroll
    for (int i = 0; i < 2; i++) {
        #pragma unroll
        for (int r = 0; r < 4; r++) {
            float inv = 1.f / lrow[i][r];
            int t = t0 + w * 32 + i * 16 + (l >> 4) * 4 + r;
            #pragma unroll
            for (int jd = 0; jd < 4; jd++) {
                int d = jd * 16 + (l & 15);
                oc[((size_t)(b * TT + t)) * CC + hh * DD + d] =
                    __float2bfloat16(acc_o[i][jd][r] * inv);
            }
        }
    }
}

// ---------------- h = LN(h + t); writes f32 h and bf16 hb
__global__ __launch_bounds__(256) void resid_ln(float* __restrict__ h,
                                                const float* __restrict__ t,
                                                const float* __restrict__ g,
                                                const float* __restrict__ bta,
                                                __hip_bfloat16* __restrict__ hb) {
    int row = blockIdx.x;
    int tid = threadIdx.x;
    __shared__ float red[256];
    float x[3];
    float s = 0.f;
    #pragma unroll
    for (int i = 0; i < 3; i++) {
        int c = tid + i * 256;
        x[i] = h[(size_t)row * CC + c] + t[(size_t)row * CC + c];
        s += x[i];
    }
    red[tid] = s; __syncthreads();
    for (int off = 128; off > 0; off >>= 1) {
        if (tid < off) red[tid] += red[tid + off];
        __syncthreads();
    }
    float mean = red[0] * (1.f / CC); __syncthreads();
    float s2 = 0.f;
    #pragma unroll
    for (int i = 0; i < 3; i++) { float dd = x[i] - mean; s2 += dd * dd; }
    red[tid] = s2; __syncthreads();
    for (int off = 128; off > 0; off >>= 1) {
        if (tid < off) red[tid] += red[tid + off];
        __syncthreads();
    }
    float inv = rsqrtf(red[0] * (1.f / CC) + 1e-5f);
    #pragma unroll
    for (int i = 0; i < 3; i++) {
        int c = tid + i * 256;
        float o = (x[i] - mean) * inv * g[c] + bta[c];
        h[(size_t)row * CC + c] = o;
        hb[(size_t)row * CC + c] = __float2bfloat16(o);
    }
}

// ---------------- per-row NLL
__global__ __launch_bounds__(256) void row_nll(const float* __restrict__ logits,
                                               const int* __restrict__ y,
                                               float* __restrict__ rl) {
    int m = blockIdx.x, tid = threadIdx.x;
    const float* row = logits + (size_t)m * VV;
    __shared__ float red[256];
    float lmax = -1e30f;
    for (int j = tid; j < VV; j += 256) lmax = fmaxf(lmax, row[j]);
    red[tid] = lmax; __syncthreads();
    for (int off = 128; off > 0; off >>= 1) {
        if (tid < off) red[tid] = fmaxf(red[tid], red[tid + off]);
        __syncthreads();
    }
    float mx = red[0]; __syncthreads();
    float ls = 0.f;
    for (int j = tid; j < VV; j += 256) ls += __expf(row[j] - mx);
    red[tid] = ls; __syncthreads();
    for (int off = 128; off > 0; off >>= 1) {
        if (tid < off) red[tid] += red[tid + off];
        __syncthreads();
    }
    if (tid == 0) rl[m] = logf(red[0]) + mx - row[y[m]];
}

__global__ __launch_bounds__(256) void loss_reduce(const float* __restrict__ rl,
                                                   float* __restrict__ out) {
    int tid = threadIdx.x;
    __shared__ float red[256];
    float s = 0.f;
    for (int i = tid; i < MROWS; i += 256) s += rl[i];
    red[tid] = s; __syncthreads();
    for (int off = 128; off > 0; off >>= 1) {
        if (tid < off) red[tid] += red[tid + off];
        __syncthreads();
    }
    if (tid == 0) out[0] = red[0] * (1.f / MROWS);
}

extern "C" void kernel_launch(void* const* d_in, const int* in_sizes, int n_in,
                              void* d_out, int out_size, void* d_ws, size_t ws_size,
                              hipStream_t stream) {
    const int*   x     = (const int*)d_in[0];
    const int*   y     = (const int*)d_in[1];
    const float* tok   = (const float*)d_in[2];
    const float* pos   = (const float*)d_in[3];
    const float* Wk    = (const float*)d_in[4];
    const float* Wq    = (const float*)d_in[5];
    const float* Wv    = (const float*)d_in[6];
    const float* Wproj = (const float*)d_in[7];
    const float* bproj = (const float*)d_in[8];
    const float* ln1g  = (const float*)d_in[9];
    const float* ln1b  = (const float*)d_in[10];
    const float* W1    = (const float*)d_in[11];
    const float* b1    = (const float*)d_in[12];
    const float* W2    = (const float*)d_in[13];
    const float* b2    = (const float*)d_in[14];
    const float* ln2g  = (const float*)d_in[15];
    const float* ln2b  = (const float*)d_in[16];
    const float* Wlm   = (const float*)d_in[17];
    const float* blm   = (const float*)d_in[18];

    float* logits = (float*)d_out;
    float* lossp  = (float*)d_out + ((size_t)out_size - 1);

    char* p = (char*)d_ws;
    auto alloc = [&](size_t bytes) { char* r = p; p += (bytes + 255) & ~255ULL; return r; };
    const size_t S_HC = (size_t)MROWS * CC;

    float* h    = (float*)alloc(S_HC * 4);
    float* tmpf = (float*)alloc(S_HC * 4);
    float* rl   = (float*)alloc(MROWS * 4);
    __hip_bfloat16* kbb  = (__hip_bfloat16*)alloc(S_HC * 2);   // k  [B,H,T,D]
    __hip_bfloat16* qbb  = (__hip_bfloat16*)alloc(S_HC * 2);   // q  [B,H,T,D]
    __hip_bfloat16* vtb  = (__hip_bfloat16*)alloc(S_HC * 2);   // V^T[B,H,D,T]
    __hip_bfloat16* hb   = (__hip_bfloat16*)alloc(S_HC * 2);
    __hip_bfloat16* ocb  = (__hip_bfloat16*)alloc(S_HC * 2);
    __hip_bfloat16* ff1b = (__hip_bfloat16*)alloc((size_t)MROWS * FFH * 2);
    __hip_bfloat16* kT   = (__hip_bfloat16*)alloc((size_t)LL * CC * CC * 2);
    __hip_bfloat16* qT   = (__hip_bfloat16*)alloc((size_t)LL * CC * CC * 2);
    __hip_bfloat16* vT   = (__hip_bfloat16*)alloc((size_t)LL * CC * CC * 2);
    __hip_bfloat16* pT   = (__hip_bfloat16*)alloc((size_t)LL * CC * CC * 2);
    __hip_bfloat16* w1T  = (__hip_bfloat16*)alloc((size_t)LL * CC * FFH * 2);
    __hip_bfloat16* w2T  = (__hip_bfloat16*)alloc((size_t)LL * FFH * CC * 2);
    __hip_bfloat16* lmT  = (__hip_bfloat16*)alloc((size_t)VPAD * CC * 2);

    dim3 blk(256);

    // ---- weight conversion (every launch; deterministic)
    cvtT_qkv<<<dim3(24, 2, 3 * 144), blk, 0, stream>>>(Wk, Wq, Wv, kT, qT, vT);
    cvtT_mat<<<dim3(24, 24, LL), blk, 0, stream>>>(Wproj, pT, CC, CC,
                                                   (size_t)CC * CC, (size_t)CC * CC);
    cvtT_mat<<<dim3(96, 24, LL), blk, 0, stream>>>(W1, w1T, CC, FFH,
                                                   (size_t)CC * FFH, (size_t)FFH * CC);
    cvtT_mat<<<dim3(24, 96, LL), blk, 0, stream>>>(W2, w2T, FFH, CC,
                                                   (size_t)FFH * CC, (size_t)CC * FFH);
    cvtT_mat<<<dim3(VPAD / 32, 24, 1), blk, 0, stream>>>(Wlm, lmT, CC, VV, 0, 0);

    // ---- embedding
    embed_kernel<<<dim3((MROWS * CC + 255) / 256), blk, 0, stream>>>(x, tok, pos, h, hb);

    for (int l = 0; l < LL; l++) {
        const __hip_bfloat16* kT_l = kT + (size_t)l * CC * CC;
        const __hip_bfloat16* qT_l = qT + (size_t)l * CC * CC;
        const __hip_bfloat16* vT_l = vT + (size_t)l * CC * CC;
        const __hip_bfloat16* pT_l = pT + (size_t)l * CC * CC;
        const __hip_bfloat16* w1T_l = w1T + (size_t)l * CC * FFH;
        const __hip_bfloat16* w2T_l = w2T + (size_t)l * FFH * CC;

        gemm_qkv_mfma<<<dim3(CC / 128, MROWS / 128, 3), blk, 0, stream>>>(
            hb, kT_l, qT_l, vT_l, kbb, qbb, vtb);
        attn_mfma<<<dim3(TT / QBLK, HH, BB), blk, 0, stream>>>(kbb, qbb, vtb, ocb);
        gemm_mfma<<<dim3(CC / 128, MROWS / 128), blk, 0, stream>>>(
            ocb, pT_l, bproj + (size_t)l * CC, tmpf, (__hip_bfloat16*)nullptr,
            MROWS, CC, CC, 0);
        resid_ln<<<dim3(MROWS), blk, 0, stream>>>(h, tmpf, ln1g + (size_t)l * CC,
                                                  ln1b + (size_t)l * CC, hb);
        gemm_mfma<<<dim3(FFH / 128, MROWS / 128), blk, 0, stream>>>(
            hb, w1T_l, b1 + (size_t)l * FFH, (float*)nullptr, ff1b,
            MROWS, FFH, CC, 1);
        gemm_mfma<<<dim3(CC / 128, MROWS / 128), blk, 0, stream>>>(
            ff1b, w2T_l, b2 + (size_t)l * CC, tmpf, (__hip_bfloat16*)nullptr,
            MROWS, CC, FFH, 0);
        resid_ln<<<dim3(MROWS), blk, 0, stream>>>(h, tmpf, ln2g + (size_t)l * CC,
                                                  ln2b + (size_t)l * CC, hb);
    }

    // LM head -> logits
    gemm_mfma<<<dim3(VPAD / 128, MROWS / 128), blk, 0, stream>>>(
        hb, lmT, blm, logits, (__hip_bfloat16*)nullptr, MROWS, VV, CC, 0);
    // loss
    row_nll<<<dim3(MROWS), blk, 0, stream>>>(logits, y, rl);
    loss_reduce<<<dim3(1), blk, 0, stream>>>(rl, lossp);
}

// Round 4
// 4861.882 us; speedup vs baseline: 10.9908x; 1.0368x over previous
//
#include <hip/hip_runtime.h>
#include <hip/hip_bf16.h>
#include <math.h>

#define BB 4
#define TT 1024
#define VV 50257
#define VPAD 50304
#define CC 768
#define HH 12
#define DD 64
#define LL 12
#define FFH 3072
#define MROWS (BB*TT)   // 4096
#define QBLK 128
#define KVBLK 64
#define NPART (2 * (VPAD / 128))   // 786 partials per row (2 wc-halves per 128-col block)

typedef __bf16 bf16x8 __attribute__((ext_vector_type(8)));
typedef float  f32x4  __attribute__((ext_vector_type(4)));
typedef unsigned int u32;
#define AS1 __attribute__((address_space(1)))
#define AS3 __attribute__((address_space(3)))

static __device__ __forceinline__ void gload_lds16(const void* g, void* l) {
    __builtin_amdgcn_global_load_lds((const AS1 u32*)g, (AS3 u32*)l, 16, 0, 0);
}

// ---------------- embedding: h = tok_emb[x] + pos_emb[x]; also bf16 copy
__global__ void embed_kernel(const int* __restrict__ x, const float* __restrict__ tok,
                             const float* __restrict__ pos, float* __restrict__ h,
                             __hip_bfloat16* __restrict__ hb) {
    int idx = blockIdx.x * 256 + threadIdx.x;
    if (idx >= MROWS * CC) return;
    int row = idx / CC, c = idx - row * CC;
    int id = x[row];
    float v = tok[(size_t)id * CC + c] + pos[(size_t)id * CC + c];
    h[idx] = v;
    hb[idx] = __float2bfloat16(v);
}

// ---------------- convert + transpose: out[b][n][k] = (n<Nin ? in[b][k][n] : 0), bf16
__global__ __launch_bounds__(256) void cvtT_mat(const float* __restrict__ in,
                                                __hip_bfloat16* __restrict__ out,
                                                int K, int Nin,
                                                size_t ibs, size_t obs) {
    __shared__ float t[32][33];
    const float* ip = in + blockIdx.z * ibs;
    __hip_bfloat16* op = out + blockIdx.z * obs;
    int n0 = blockIdx.x * 32, k0 = blockIdx.y * 32;
    int tx = threadIdx.x & 31, ty = threadIdx.x >> 5;   // 32x8
    #pragma unroll
    for (int i = 0; i < 4; i++) {
        int k = k0 + ty + i * 8, n = n0 + tx;
        t[ty + i * 8][tx] = (n < Nin) ? ip[(size_t)k * Nin + n] : 0.f;
    }
    __syncthreads();
    #pragma unroll
    for (int i = 0; i < 4; i++) {
        int n = n0 + ty + i * 8, k = k0 + tx;
        op[(size_t)n * K + k] = __float2bfloat16(t[tx][ty + i * 8]);
    }
}

// ---------------- QKV weights (L,H,C,D) -> per-layer [768][768] bf16, row n=h*64+d, col c
__global__ __launch_bounds__(256) void cvtT_qkv(const float* __restrict__ Wk,
                                                const float* __restrict__ Wq,
                                                const float* __restrict__ Wv,
                                                __hip_bfloat16* __restrict__ kT,
                                                __hip_bfloat16* __restrict__ qT,
                                                __hip_bfloat16* __restrict__ vT) {
    int z = blockIdx.z;
    int tensor = z / 144, lh = z % 144;
    int l = lh / HH, hh = lh % HH;
    const float* in = (tensor == 0 ? Wk : tensor == 1 ? Wq : Wv) + (size_t)lh * CC * DD;
    __hip_bfloat16* out = (tensor == 0 ? kT : tensor == 1 ? qT : vT)
                          + ((size_t)l * CC + hh * DD) * CC;
    __shared__ float t[32][33];
    int c0 = blockIdx.x * 32, d0 = blockIdx.y * 32;
    int tx = threadIdx.x & 31, ty = threadIdx.x >> 5;
    #pragma unroll
    for (int i = 0; i < 4; i++)
        t[ty + i * 8][tx] = in[(size_t)(c0 + ty + i * 8) * DD + d0 + tx];
    __syncthreads();
    #pragma unroll
    for (int i = 0; i < 4; i++)
        out[(size_t)(d0 + ty + i * 8) * CC + c0 + tx] = __float2bfloat16(t[tx][ty + i * 8]);
}

// ---------------- MFMA GEMM: C = A[M,K]bf16 @ Bt[Npad,K]bf16^T (+bias, relu)
__global__ __launch_bounds__(256) void gemm_mfma(const __hip_bfloat16* __restrict__ A,
                                                 const __hip_bfloat16* __restrict__ Bt,
                                                 const float* __restrict__ bias,
                                                 float* __restrict__ Cf,
                                                 __hip_bfloat16* __restrict__ Cb,
                                                 int M, int N, int K, int relu) {
    __shared__ __hip_bfloat16 As[128][64];
    __shared__ __hip_bfloat16 Bs[128][64];
    int tid = threadIdx.x;
    int l = tid & 63, w = tid >> 6;
    int wr = w >> 1, wc = w & 1;
    int bm = blockIdx.y * 128, bn = blockIdx.x * 128;

    f32x4 acc[4][4] = {};

    for (int k0 = 0; k0 < K; k0 += 64) {
        __syncthreads();
        #pragma unroll
        for (int it = 0; it < 4; it++) {
            int chunk = w * 4 + it;
            int e = chunk * 512 + l * 8;
            int m = e >> 6, kk = e & 63;
            gload_lds16(A + (size_t)(bm + m) * K + k0 + kk,
                        (char*)&As[0][0] + chunk * 1024);
            gload_lds16(Bt + (size_t)(bn + m) * K + k0 + kk,
                        (char*)&Bs[0][0] + chunk * 1024);
        }
        __syncthreads();
        #pragma unroll
        for (int ks = 0; ks < 2; ks++) {
            bf16x8 af[4], bfr[4];
            #pragma unroll
            for (int i = 0; i < 4; i++)
                af[i] = *(const bf16x8*)&As[wr * 64 + i * 16 + (l & 15)][ks * 32 + (l >> 4) * 8];
            #pragma unroll
            for (int j = 0; j < 4; j++)
                bfr[j] = *(const bf16x8*)&Bs[wc * 64 + j * 16 + (l & 15)][ks * 32 + (l >> 4) * 8];
            #pragma unroll
            for (int i = 0; i < 4; i++)
                #pragma unroll
                for (int j = 0; j < 4; j++)
                    acc[i][j] = __builtin_amdgcn_mfma_f32_16x16x32_bf16(af[i], bfr[j], acc[i][j], 0, 0, 0);
        }
    }
    #pragma unroll
    for (int i = 0; i < 4; i++) {
        int row = bm + wr * 64 + i * 16 + (l >> 4) * 4;
        #pragma unroll
        for (int j = 0; j < 4; j++) {
            int col = bn + wc * 64 + j * 16 + (l & 15);
            if (col < N) {
                float bv = bias ? bias[col] : 0.f;
                #pragma unroll
                for (int r = 0; r < 4; r++) {
                    float v = acc[i][j][r] + bv;
                    if (relu) v = fmaxf(v, 0.f);
                    if (Cf) Cf[(size_t)(row + r) * N + col] = v;
                    if (Cb) Cb[(size_t)(row + r) * N + col] = __float2bfloat16(v);
                }
            }
        }
    }
}

// ---------------- LM head: row-fastest grid for B-panel L2 reuse + fused LSE partials.
// grid: (M/128, VPAD/128). Writes logits (col<VV) and per-(row, 64-col-half) (max, sumexp).
__global__ __launch_bounds__(256) void lm_head_mfma(const __hip_bfloat16* __restrict__ A,
                                                    const __hip_bfloat16* __restrict__ Bt,
                                                    const float* __restrict__ bias,
                                                    float* __restrict__ Cf,
                                                    float* __restrict__ pm,
                                                    float* __restrict__ ps) {
    __shared__ __hip_bfloat16 As[128][64];
    __shared__ __hip_bfloat16 Bs[128][64];
    int tid = threadIdx.x;
    int l = tid & 63, w = tid >> 6;
    int wr = w >> 1, wc = w & 1;
    int bm = blockIdx.x * 128, bn = blockIdx.y * 128;   // row-fastest

    f32x4 acc[4][4] = {};

    for (int k0 = 0; k0 < CC; k0 += 64) {
        __syncthreads();
        #pragma unroll
        for (int it = 0; it < 4; it++) {
            int chunk = w * 4 + it;
            int e = chunk * 512 + l * 8;
            int m = e >> 6, kk = e & 63;
            gload_lds16(A + (size_t)(bm + m) * CC + k0 + kk,
                        (char*)&As[0][0] + chunk * 1024);
            gload_lds16(Bt + (size_t)(bn + m) * CC + k0 + kk,
                        (char*)&Bs[0][0] + chunk * 1024);
        }
        __syncthreads();
        #pragma unroll
        for (int ks = 0; ks < 2; ks++) {
            bf16x8 af[4], bfr[4];
            #pragma unroll
            for (int i = 0; i < 4; i++)
                af[i] = *(const bf16x8*)&As[wr * 64 + i * 16 + (l & 15)][ks * 32 + (l >> 4) * 8];
            #pragma unroll
            for (int j = 0; j < 4; j++)
                bfr[j] = *(const bf16x8*)&Bs[wc * 64 + j * 16 + (l & 15)][ks * 32 + (l >> 4) * 8];
            #pragma unroll
            for (int i = 0; i < 4; i++)
                #pragma unroll
                for (int j = 0; j < 4; j++)
                    acc[i][j] = __builtin_amdgcn_mfma_f32_16x16x32_bf16(af[i], bfr[j], acc[i][j], 0, 0, 0);
        }
    }
    int pidx = blockIdx.y * 2 + wc;
    #pragma unroll
    for (int i = 0; i < 4; i++) {
        int row = bm + wr * 64 + i * 16 + (l >> 4) * 4;
        #pragma unroll
        for (int r = 0; r < 4; r++) {
            float pv[4];
            float rmax = -1e30f;
            #pragma unroll
            for (int j = 0; j < 4; j++) {
                int col = bn + wc * 64 + j * 16 + (l & 15);
                float v = -1e30f;
                if (col < VV) {
                    v = acc[i][j][r] + bias[col];
                    Cf[(size_t)(row + r) * VV + col] = v;
                }
                pv[j] = v;
                rmax = fmaxf(rmax, v);
            }
            // reduce across the 16 lanes holding this row's cols
            #pragma unroll
            for (int msk = 1; msk < 16; msk <<= 1)
                rmax = fmaxf(rmax, __shfl_xor(rmax, msk));
            float s = 0.f;
            #pragma unroll
            for (int j = 0; j < 4; j++) s += __expf(pv[j] - rmax);
            #pragma unroll
            for (int msk = 1; msk < 16; msk <<= 1)
                s += __shfl_xor(s, msk);
            if ((l & 15) == 0) {
                pm[(size_t)(row + r) * NPART + pidx] = rmax;
                ps[(size_t)(row + r) * NPART + pidx] = s;
            }
        }
    }
}

// ---------------- combine LSE partials -> per-row NLL
__global__ __launch_bounds__(256) void nll_combine(const float* __restrict__ pm,
                                                   const float* __restrict__ ps,
                                                   const float* __restrict__ logits,
                                                   const int* __restrict__ y,
                                                   float* __restrict__ rl) {
    int m = blockIdx.x, tid = threadIdx.x;
    __shared__ float rm[256], rs[256];
    float mt = -1e30f, st = 0.f;
    for (int i = tid; i < NPART; i += 256) {
        float mi = pm[(size_t)m * NPART + i];
        float si = ps[(size_t)m * NPART + i];
        float mn = fmaxf(mt, mi);
        st = st * __expf(mt - mn) + si * __expf(mi - mn);
        mt = mn;
    }
    rm[tid] = mt; rs[tid] = st; __syncthreads();
    for (int off = 128; off > 0; off >>= 1) {
        if (tid < off) {
            float ma = rm[tid], mb = rm[tid + off];
            float mn = fmaxf(ma, mb);
            rs[tid] = rs[tid] * __expf(ma - mn) + rs[tid + off] * __expf(mb - mn);
            rm[tid] = mn;
        }
        __syncthreads();
    }
    if (tid == 0)
        rl[m] = logf(rs[0]) + rm[0] - logits[(size_t)m * VV + y[m]];
}

// ---------------- QKV MFMA GEMM: A=hb [4096,768]; k,q -> bf16 [B,H,T,D]; v -> bf16 [B,H,D,T]
__global__ __launch_bounds__(256) void gemm_qkv_mfma(const __hip_bfloat16* __restrict__ A,
                                                     const __hip_bfloat16* __restrict__ kT,
                                                     const __hip_bfloat16* __restrict__ qT,
                                                     const __hip_bfloat16* __restrict__ vT,
                                                     __hip_bfloat16* __restrict__ ko,
                                                     __hip_bfloat16* __restrict__ qo,
                                                     __hip_bfloat16* __restrict__ vto) {
    const __hip_bfloat16* Bt = (blockIdx.z == 0) ? kT : (blockIdx.z == 1) ? qT : vT;
    __shared__ __hip_bfloat16 As[128][64];
    __shared__ __hip_bfloat16 Bs[128][64];
    int tid = threadIdx.x;
    int l = tid & 63, w = tid >> 6;
    int wr = w >> 1, wc = w & 1;
    int bm = blockIdx.y * 128, bn = blockIdx.x * 128;

    f32x4 acc[4][4] = {};

    for (int k0 = 0; k0 < CC; k0 += 64) {
        __syncthreads();
        #pragma unroll
        for (int it = 0; it < 4; it++) {
            int chunk = w * 4 + it;
            int e = chunk * 512 + l * 8;
            int m = e >> 6, kk = e & 63;
            gload_lds16(A + (size_t)(bm + m) * CC + k0 + kk,
                        (char*)&As[0][0] + chunk * 1024);
            gload_lds16(Bt + (size_t)(bn + m) * CC + k0 + kk,
                        (char*)&Bs[0][0] + chunk * 1024);
        }
        __syncthreads();
        #pragma unroll
        for (int ks = 0; ks < 2; ks++) {
            bf16x8 af[4], bfr[4];
            #pragma unroll
            for (int i = 0; i < 4; i++)
                af[i] = *(const bf16x8*)&As[wr * 64 + i * 16 + (l & 15)][ks * 32 + (l >> 4) * 8];
            #pragma unroll
            for (int j = 0; j < 4; j++)
                bfr[j] = *(const bf16x8*)&Bs[wc * 64 + j * 16 + (l & 15)][ks * 32 + (l >> 4) * 8];
            #pragma unroll
            for (int i = 0; i < 4; i++)
                #pragma unroll
                for (int j = 0; j < 4; j++)
                    acc[i][j] = __builtin_amdgcn_mfma_f32_16x16x32_bf16(af[i], bfr[j], acc[i][j], 0, 0, 0);
        }
    }
    int zz = blockIdx.z;
    #pragma unroll
    for (int i = 0; i < 4; i++) {
        int row = bm + wr * 64 + i * 16 + (l >> 4) * 4;
        #pragma unroll
        for (int j = 0; j < 4; j++) {
            int col = bn + wc * 64 + j * 16 + (l & 15);
            int head = col >> 6, d = col & 63;
            #pragma unroll
            for (int r = 0; r < 4; r++) {
                int m = row + r;
                int b = m >> 10, t = m & 1023;
                __hip_bfloat16 val = __float2bfloat16(acc[i][j][r]);
                if (zz == 0)      ko[(((size_t)(b * HH + head)) * TT + t) * DD + d] = val;
                else if (zz == 1) qo[(((size_t)(b * HH + head)) * TT + t) * DD + d] = val;
                else              vto[(((size_t)(b * HH + head)) * DD + d) * TT + t] = val;
            }
        }
    }
}

// ---------------- MFMA flash attention (quirk: k plays query role)
__global__ __launch_bounds__(256) void attn_mfma(const __hip_bfloat16* __restrict__ kq,
                                                 const __hip_bfloat16* __restrict__ qk,
                                                 const __hip_bfloat16* __restrict__ vt,
                                                 __hip_bfloat16* __restrict__ oc) {
    __shared__ __hip_bfloat16 Qs[KVBLK * 64];
    __shared__ __hip_bfloat16 Vs[64 * KVBLK];
    __shared__ __hip_bfloat16 Ps[QBLK * KVBLK];
    int tid = threadIdx.x;
    int l = tid & 63, w = tid >> 6;
    int t0 = blockIdx.x * QBLK;
    size_t bh = (size_t)(blockIdx.z * HH + blockIdx.y);
    const __hip_bfloat16* kqp = kq + bh * TT * DD;
    const __hip_bfloat16* qkp = qk + bh * TT * DD;
    const __hip_bfloat16* vtp = vt + bh * DD * TT;

    bf16x8 af[2][2];
    #pragma unroll
    for (int i = 0; i < 2; i++)
        #pragma unroll
        for (int ks = 0; ks < 2; ks++)
            af[i][ks] = *(const bf16x8*)&kqp[(size_t)(t0 + w * 32 + i * 16 + (l & 15)) * DD
                                             + ks * 32 + (l >> 4) * 8];

    f32x4 acc_o[2][4] = {};
    float mrow[2][4], lrow[2][4];
    #pragma unroll
    for (int i = 0; i < 2; i++)
        #pragma unroll
        for (int r = 0; r < 4; r++) { mrow[i][r] = -1e30f; lrow[i][r] = 0.f; }

    for (int s0 = 0; s0 < t0 + QBLK; s0 += KVBLK) {
        __syncthreads();
        #pragma unroll
        for (int it = 0; it < 2; it++) {
            int chunk = w * 2 + it;
            int o = chunk * 1024 + l * 16;
            int row = o >> 7;
            int cb = (o & 127) ^ ((row & 7) << 4);
            gload_lds16(qkp + (size_t)(s0 + row) * DD + (cb >> 1),
                        (char*)Qs + chunk * 1024);
            gload_lds16(vtp + (size_t)row * TT + s0 + (cb >> 1),
                        (char*)Vs + chunk * 1024);
        }
        __syncthreads();

        f32x4 sa[2][4] = {};
        #pragma unroll
        for (int ks = 0; ks < 2; ks++) {
            bf16x8 bfr[4];
            #pragma unroll
            for (int j = 0; j < 4; j++) {
                int row = j * 16 + (l & 15);
                int cb = (ks * 64 + (l >> 4) * 16) ^ ((row & 7) << 4);
                bfr[j] = *(const bf16x8*)((const char*)Qs + row * 128 + cb);
            }
            #pragma unroll
            for (int i = 0; i < 2; i++)
                #pragma unroll
                for (int j = 0; j < 4; j++)
                    sa[i][j] = __builtin_amdgcn_mfma_f32_16x16x32_bf16(af[i][ks], bfr[j], sa[i][j], 0, 0, 0);
        }

        #pragma unroll
        for (int i = 0; i < 2; i++) {
            #pragma unroll
            for (int r = 0; r < 4; r++) {
                int t = t0 + w * 32 + i * 16 + (l >> 4) * 4 + r;
                float pv[4];
                float rmax = -1e30f;
                #pragma unroll
                for (int j = 0; j < 4; j++) {
                    int s = s0 + j * 16 + (l & 15);
                    float v = sa[i][j][r] * 0.125f;
                    v = (s <= t) ? v : -1e30f;
                    pv[j] = v;
                    rmax = fmaxf(rmax, v);
                }
                #pragma unroll
                for (int msk = 1; msk < 16; msk <<= 1)
                    rmax = fmaxf(rmax, __shfl_xor(rmax, msk));
                float mo = mrow[i][r];
                float mn = fmaxf(mo, rmax);
                float fac = __expf(mo - mn);
                float ls = 0.f;
                int prow = w * 32 + i * 16 + (l >> 4) * 4 + r;
                #pragma unroll
                for (int j = 0; j < 4; j++) {
                    float e = __expf(pv[j] - mn);
                    ls += e;
                    int cb = (j * 32 + (l & 15) * 2) ^ ((prow & 7) << 4);
                    *(__hip_bfloat16*)((char*)Ps + prow * 128 + cb) = __float2bfloat16(e);
                }
                #pragma unroll
                for (int msk = 1; msk < 16; msk <<= 1)
                    ls += __shfl_xor(ls, msk);
                mrow[i][r] = mn;
                lrow[i][r] = lrow[i][r] * fac + ls;
                #pragma unroll
                for (int jd = 0; jd < 4; jd++)
                    acc_o[i][jd][r] *= fac;
            }
        }
        __syncthreads();

        #pragma unroll
        for (int ks = 0; ks < 2; ks++) {
            bf16x8 pa[2], vf[4];
            #pragma unroll
            for (int i = 0; i < 2; i++) {
                int row = w * 32 + i * 16 + (l & 15);
                int cb = (ks * 64 + (l >> 4) * 16) ^ ((row & 7) << 4);
                pa[i] = *(const bf16x8*)((const char*)Ps + row * 128 + cb);
            }
            #pragma unroll
            for (int jd = 0; jd < 4; jd++) {
                int row = jd * 16 + (l & 15);
                int cb = (ks * 64 + (l >> 4) * 16) ^ ((row & 7) << 4);
                vf[jd] = *(const bf16x8*)((const char*)Vs + row * 128 + cb);
            }
            #pragma unroll
            for (int i = 0; i < 2; i++)
                #pragma unroll
                for (int jd = 0; jd < 4; jd++)
                    acc_o[i][jd] = __builtin_amdgcn_mfma_f32_16x16x32_bf16(pa[i], vf[jd], acc_o[i][jd], 0, 0, 0);
        }
    }

    int b = blockIdx.z, hh = blockIdx.y;
    #pragma unroll
    for (int i = 0; i < 2; i++) {
        #pragma unroll
        for (int r = 0; r < 4; r++) {
            float inv = 1.f / lrow[i][r];
            int t = t0 + w * 32 + i * 16 + (l >> 4) * 4 + r;
            #pragma unroll
            for (int jd = 0; jd < 4; jd++) {
                int d = jd * 16 + (l & 15);
                oc[((size_t)(b * TT + t)) * CC + hh * DD + d] =
                    __float2bfloat16(acc_o[i][jd][r] * inv);
            }
        }
    }
}

// ---------------- h = LN(h + t); writes f32 h and bf16 hb
__global__ __launch_bounds__(256) void resid_ln(float* __restrict__ h,
                                                const float* __restrict__ t,
                                                const float* __restrict__ g,
                                                const float* __restrict__ bta,
                                                __hip_bfloat16* __restrict__ hb) {
    int row = blockIdx.x;
    int tid = threadIdx.x;
    __shared__ float red[256];
    float x[3];
    float s = 0.f;
    #pragma unroll
    for (int i = 0; i < 3; i++) {
        int c = tid + i * 256;
        x[i] = h[(size_t)row * CC + c] + t[(size_t)row * CC + c];
        s += x[i];
    }
    red[tid] = s; __syncthreads();
    for (int off = 128; off > 0; off >>= 1) {
        if (tid < off) red[tid] += red[tid + off];
        __syncthreads();
    }
    float mean = red[0] * (1.f / CC); __syncthreads();
    float s2 = 0.f;
    #pragma unroll
    for (int i = 0; i < 3; i++) { float dd = x[i] - mean; s2 += dd * dd; }
    red[tid] = s2; __syncthreads();
    for (int off = 128; off > 0; off >>= 1) {
        if (tid < off) red[tid] += red[tid + off];
        __syncthreads();
    }
    float inv = rsqrtf(red[0] * (1.f / CC) + 1e-5f);
    #pragma unroll
    for (int i = 0; i < 3; i++) {
        int c = tid + i * 256;
        float o = (x[i] - mean) * inv * g[c] + bta[c];
        h[(size_t)row * CC + c] = o;
        hb[(size_t)row * CC + c] = __float2bfloat16(o);
    }
}

__global__ __launch_bounds__(256) void loss_reduce(const float* __restrict__ rl,
                                                   float* __restrict__ out) {
    int tid = threadIdx.x;
    __shared__ float red[256];
    float s = 0.f;
    for (int i = tid; i < MROWS; i += 256) s += rl[i];
    red[tid] = s; __syncthreads();
    for (int off = 128; off > 0; off >>= 1) {
        if (tid < off) red[tid] += red[tid + off];
        __syncthreads();
    }
    if (tid == 0) out[0] = red[0] * (1.f / MROWS);
}

extern "C" void kernel_launch(void* const* d_in, const int* in_sizes, int n_in,
                              void* d_out, int out_size, void* d_ws, size_t ws_size,
                              hipStream_t stream) {
    const int*   x     = (const int*)d_in[0];
    const int*   y     = (const int*)d_in[1];
    const float* tok   = (const float*)d_in[2];
    const float* pos   = (const float*)d_in[3];
    const float* Wk    = (const float*)d_in[4];
    const float* Wq    = (const float*)d_in[5];
    const float* Wv    = (const float*)d_in[6];
    const float* Wproj = (const float*)d_in[7];
    const float* bproj = (const float*)d_in[8];
    const float* ln1g  = (const float*)d_in[9];
    const float* ln1b  = (const float*)d_in[10];
    const float* W1    = (const float*)d_in[11];
    const float* b1    = (const float*)d_in[12];
    const float* W2    = (const float*)d_in[13];
    const float* b2    = (const float*)d_in[14];
    const float* ln2g  = (const float*)d_in[15];
    const float* ln2b  = (const float*)d_in[16];
    const float* Wlm   = (const float*)d_in[17];
    const float* blm   = (const float*)d_in[18];

    float* logits = (float*)d_out;
    float* lossp  = (float*)d_out + ((size_t)out_size - 1);

    char* p = (char*)d_ws;
    auto alloc = [&](size_t bytes) { char* r = p; p += (bytes + 255) & ~255ULL; return r; };
    const size_t S_HC = (size_t)MROWS * CC;

    float* h    = (float*)alloc(S_HC * 4);
    float* tmpf = (float*)alloc(S_HC * 4);
    float* rl   = (float*)alloc(MROWS * 4);
    float* pm   = (float*)alloc((size_t)MROWS * NPART * 4);
    float* ps   = (float*)alloc((size_t)MROWS * NPART * 4);
    __hip_bfloat16* kbb  = (__hip_bfloat16*)alloc(S_HC * 2);
    __hip_bfloat16* qbb  = (__hip_bfloat16*)alloc(S_HC * 2);
    __hip_bfloat16* vtb  = (__hip_bfloat16*)alloc(S_HC * 2);
    __hip_bfloat16* hb   = (__hip_bfloat16*)alloc(S_HC * 2);
    __hip_bfloat16* ocb  = (__hip_bfloat16*)alloc(S_HC * 2);
    __hip_bfloat16* ff1b = (__hip_bfloat16*)alloc((size_t)MROWS * FFH * 2);
    __hip_bfloat16* kT   = (__hip_bfloat16*)alloc((size_t)LL * CC * CC * 2);
    __hip_bfloat16* qT   = (__hip_bfloat16*)alloc((size_t)LL * CC * CC * 2);
    __hip_bfloat16* vT   = (__hip_bfloat16*)alloc((size_t)LL * CC * CC * 2);
    __hip_bfloat16* pT   = (__hip_bfloat16*)alloc((size_t)LL * CC * CC * 2);
    __hip_bfloat16* w1T  = (__hip_bfloat16*)alloc((size_t)LL * CC * FFH * 2);
    __hip_bfloat16* w2T  = (__hip_bfloat16*)alloc((size_t)LL * FFH * CC * 2);
    __hip_bfloat16* lmT  = (__hip_bfloat16*)alloc((size_t)VPAD * CC * 2);

    dim3 blk(256);

    cvtT_qkv<<<dim3(24, 2, 3 * 144), blk, 0, stream>>>(Wk, Wq, Wv, kT, qT, vT);
    cvtT_mat<<<dim3(24, 24, LL), blk, 0, stream>>>(Wproj, pT, CC, CC,
                                                   (size_t)CC * CC, (size_t)CC * CC);
    cvtT_mat<<<dim3(96, 24, LL), blk, 0, stream>>>(W1, w1T, CC, FFH,
                                                   (size_t)CC * FFH, (size_t)FFH * CC);
    cvtT_mat<<<dim3(24, 96, LL), blk, 0, stream>>>(W2, w2T, FFH, CC,
                                                   (size_t)FFH * CC, (size_t)CC * FFH);
    cvtT_mat<<<dim3(VPAD / 32, 24, 1), blk, 0, stream>>>(Wlm, lmT, CC, VV, 0, 0);

    embed_kernel<<<dim3((MROWS * CC + 255) / 256), blk, 0, stream>>>(x, tok, pos, h, hb);

    for (int l = 0; l < LL; l++) {
        const __hip_bfloat16* kT_l = kT + (size_t)l * CC * CC;
        const __hip_bfloat16* qT_l = qT + (size_t)l * CC * CC;
        const __hip_bfloat16* vT_l = vT + (size_t)l * CC * CC;
        const __hip_bfloat16* pT_l = pT + (size_t)l * CC * CC;
        const __hip_bfloat16* w1T_l = w1T + (size_t)l * CC * FFH;
        const __hip_bfloat16* w2T_l = w2T + (size_t)l * FFH * CC;

        gemm_qkv_mfma<<<dim3(CC / 128, MROWS / 128, 3), blk, 0, stream>>>(
            hb, kT_l, qT_l, vT_l, kbb, qbb, vtb);
        attn_mfma<<<dim3(TT / QBLK, HH, BB), blk, 0, stream>>>(kbb, qbb, vtb, ocb);
        gemm_mfma<<<dim3(CC / 128, MROWS / 128), blk, 0, stream>>>(
            ocb, pT_l, bproj + (size_t)l * CC, tmpf, (__hip_bfloat16*)nullptr,
            MROWS, CC, CC, 0);
        resid_ln<<<dim3(MROWS), blk, 0, stream>>>(h, tmpf, ln1g + (size_t)l * CC,
                                                  ln1b + (size_t)l * CC, hb);
        gemm_mfma<<<dim3(FFH / 128, MROWS / 128), blk, 0, stream>>>(
            hb, w1T_l, b1 + (size_t)l * FFH, (float*)nullptr, ff1b,
            MROWS, FFH, CC, 1);
        gemm_mfma<<<dim3(CC / 128, MROWS / 128), blk, 0, stream>>>(
            ff1b, w2T_l, b2 + (size_t)l * CC, tmpf, (__hip_bfloat16*)nullptr,
            MROWS, CC, FFH, 0);
        resid_ln<<<dim3(MROWS), blk, 0, stream>>>(h, tmpf, ln2g + (size_t)l * CC,
                                                  ln2b + (size_t)l * CC, hb);
    }

    // LM head (row-fastest grid, fused LSE partials) -> logits + pm/ps
    lm_head_mfma<<<dim3(MROWS / 128, VPAD / 128), blk, 0, stream>>>(
        hb, lmT, blm, logits, pm, ps);
    // combine partials -> per-row NLL -> loss
    nll_combine<<<dim3(MROWS), blk, 0, stream>>>(pm, ps, logits, y, rl);
    loss_reduce<<<dim3(1), blk, 0, stream>>>(rl, lossp);
}

// Round 5
// 4408.926 us; speedup vs baseline: 12.1200x; 1.1027x over previous
//
#include <hip/hip_runtime.h>
#include <hip/hip_bf16.h>
#include <math.h>

#define BB 4
#define TT 1024
#define VV 50257
#define VPAD 50304
#define CC 768
#define HH 12
#define DD 64
#define LL 12
#define FFH 3072
#define MROWS (BB*TT)   // 4096
#define QBLK 128
#define KVBLK 64
#define NPART (2 * (VPAD / 128))   // 786 partials per row

typedef __bf16 bf16x8 __attribute__((ext_vector_type(8)));
typedef float  f32x4  __attribute__((ext_vector_type(4)));
typedef unsigned int u32;
#define AS1 __attribute__((address_space(1)))
#define AS3 __attribute__((address_space(3)))

static __device__ __forceinline__ void gload_lds16(const void* g, void* l) {
    __builtin_amdgcn_global_load_lds((const AS1 u32*)g, (AS3 u32*)l, 16, 0, 0);
}

// ---------------- embedding: h = tok_emb[x] + pos_emb[x]; also bf16 copy
__global__ void embed_kernel(const int* __restrict__ x, const float* __restrict__ tok,
                             const float* __restrict__ pos, float* __restrict__ h,
                             __hip_bfloat16* __restrict__ hb) {
    int idx = blockIdx.x * 256 + threadIdx.x;
    if (idx >= MROWS * CC) return;
    int row = idx / CC, c = idx - row * CC;
    int id = x[row];
    float v = tok[(size_t)id * CC + c] + pos[(size_t)id * CC + c];
    h[idx] = v;
    hb[idx] = __float2bfloat16(v);
}

// ---------------- convert + transpose: out[b][n][k] = (n<Nin ? in[b][k][n] : 0), bf16
__global__ __launch_bounds__(256) void cvtT_mat(const float* __restrict__ in,
                                                __hip_bfloat16* __restrict__ out,
                                                int K, int Nin,
                                                size_t ibs, size_t obs) {
    __shared__ float t[32][33];
    const float* ip = in + blockIdx.z * ibs;
    __hip_bfloat16* op = out + blockIdx.z * obs;
    int n0 = blockIdx.x * 32, k0 = blockIdx.y * 32;
    int tx = threadIdx.x & 31, ty = threadIdx.x >> 5;   // 32x8
    #pragma unroll
    for (int i = 0; i < 4; i++) {
        int k = k0 + ty + i * 8, n = n0 + tx;
        t[ty + i * 8][tx] = (n < Nin) ? ip[(size_t)k * Nin + n] : 0.f;
    }
    __syncthreads();
    #pragma unroll
    for (int i = 0; i < 4; i++) {
        int n = n0 + ty + i * 8, k = k0 + tx;
        op[(size_t)n * K + k] = __float2bfloat16(t[tx][ty + i * 8]);
    }
}

// ---------------- QKV weights (L,H,C,D) -> per-layer [768][768] bf16, row n=h*64+d, col c
__global__ __launch_bounds__(256) void cvtT_qkv(const float* __restrict__ Wk,
                                                const float* __restrict__ Wq,
                                                const float* __restrict__ Wv,
                                                __hip_bfloat16* __restrict__ kT,
                                                __hip_bfloat16* __restrict__ qT,
                                                __hip_bfloat16* __restrict__ vT) {
    int z = blockIdx.z;
    int tensor = z / 144, lh = z % 144;
    int l = lh / HH, hh = lh % HH;
    const float* in = (tensor == 0 ? Wk : tensor == 1 ? Wq : Wv) + (size_t)lh * CC * DD;
    __hip_bfloat16* out = (tensor == 0 ? kT : tensor == 1 ? qT : vT)
                          + ((size_t)l * CC + hh * DD) * CC;
    __shared__ float t[32][33];
    int c0 = blockIdx.x * 32, d0 = blockIdx.y * 32;
    int tx = threadIdx.x & 31, ty = threadIdx.x >> 5;
    #pragma unroll
    for (int i = 0; i < 4; i++)
        t[ty + i * 8][tx] = in[(size_t)(c0 + ty + i * 8) * DD + d0 + tx];
    __syncthreads();
    #pragma unroll
    for (int i = 0; i < 4; i++)
        out[(size_t)(d0 + ty + i * 8) * CC + c0 + tx] = __float2bfloat16(t[tx][ty + i * 8]);
}

// ---------------- MFMA GEMM: C = A[M,K]bf16 @ Bt[Npad,K]bf16^T (+bias, relu)
// T2: linear LDS dest for global_load_lds, pre-swizzled global source column,
// same XOR on fragment reads -> conflict-free ds_read_b128.
__global__ __launch_bounds__(256) void gemm_mfma(const __hip_bfloat16* __restrict__ A,
                                                 const __hip_bfloat16* __restrict__ Bt,
                                                 const float* __restrict__ bias,
                                                 float* __restrict__ Cf,
                                                 __hip_bfloat16* __restrict__ Cb,
                                                 int M, int N, int K, int relu) {
    __shared__ __hip_bfloat16 As[128][64];
    __shared__ __hip_bfloat16 Bs[128][64];
    int tid = threadIdx.x;
    int l = tid & 63, w = tid >> 6;
    int wr = w >> 1, wc = w & 1;
    int bm = blockIdx.y * 128, bn = blockIdx.x * 128;

    f32x4 acc[4][4] = {};

    for (int k0 = 0; k0 < K; k0 += 64) {
        __syncthreads();
        #pragma unroll
        for (int it = 0; it < 4; it++) {
            int chunk = w * 4 + it;
            int o = chunk * 1024 + l * 16;          // physical LDS byte offset
            int row = o >> 7;                       // 128B rows
            int cb = (o & 127) ^ ((row & 7) << 4);  // swizzled source column byte
            gload_lds16(A + (size_t)(bm + row) * K + k0 + (cb >> 1),
                        (char*)&As[0][0] + chunk * 1024);
            gload_lds16(Bt + (size_t)(bn + row) * K + k0 + (cb >> 1),
                        (char*)&Bs[0][0] + chunk * 1024);
        }
        __syncthreads();
        #pragma unroll
        for (int ks = 0; ks < 2; ks++) {
            bf16x8 af[4], bfr[4];
            #pragma unroll
            for (int i = 0; i < 4; i++) {
                int row = wr * 64 + i * 16 + (l & 15);
                int cb = (ks * 64 + (l >> 4) * 16) ^ ((row & 7) << 4);
                af[i] = *(const bf16x8*)((const char*)&As[0][0] + row * 128 + cb);
            }
            #pragma unroll
            for (int j = 0; j < 4; j++) {
                int row = wc * 64 + j * 16 + (l & 15);
                int cb = (ks * 64 + (l >> 4) * 16) ^ ((row & 7) << 4);
                bfr[j] = *(const bf16x8*)((const char*)&Bs[0][0] + row * 128 + cb);
            }
            #pragma unroll
            for (int i = 0; i < 4; i++)
                #pragma unroll
                for (int j = 0; j < 4; j++)
                    acc[i][j] = __builtin_amdgcn_mfma_f32_16x16x32_bf16(af[i], bfr[j], acc[i][j], 0, 0, 0);
        }
    }
    #pragma unroll
    for (int i = 0; i < 4; i++) {
        int row = bm + wr * 64 + i * 16 + (l >> 4) * 4;
        #pragma unroll
        for (int j = 0; j < 4; j++) {
            int col = bn + wc * 64 + j * 16 + (l & 15);
            if (col < N) {
                float bv = bias ? bias[col] : 0.f;
                #pragma unroll
                for (int r = 0; r < 4; r++) {
                    float v = acc[i][j][r] + bv;
                    if (relu) v = fmaxf(v, 0.f);
                    if (Cf) Cf[(size_t)(row + r) * N + col] = v;
                    if (Cb) Cb[(size_t)(row + r) * N + col] = __float2bfloat16(v);
                }
            }
        }
    }
}

// ---------------- LM head: col-fastest grid (empirically faster) + fused LSE partials.
__global__ __launch_bounds__(256) void lm_head_mfma(const __hip_bfloat16* __restrict__ A,
                                                    const __hip_bfloat16* __restrict__ Bt,
                                                    const float* __restrict__ bias,
                                                    float* __restrict__ Cf,
                                                    float* __restrict__ pm,
                                                    float* __restrict__ ps) {
    __shared__ __hip_bfloat16 As[128][64];
    __shared__ __hip_bfloat16 Bs[128][64];
    int tid = threadIdx.x;
    int l = tid & 63, w = tid >> 6;
    int wr = w >> 1, wc = w & 1;
    int bm = blockIdx.y * 128, bn = blockIdx.x * 128;   // col-fastest

    f32x4 acc[4][4] = {};

    for (int k0 = 0; k0 < CC; k0 += 64) {
        __syncthreads();
        #pragma unroll
        for (int it = 0; it < 4; it++) {
            int chunk = w * 4 + it;
            int o = chunk * 1024 + l * 16;
            int row = o >> 7;
            int cb = (o & 127) ^ ((row & 7) << 4);
            gload_lds16(A + (size_t)(bm + row) * CC + k0 + (cb >> 1),
                        (char*)&As[0][0] + chunk * 1024);
            gload_lds16(Bt + (size_t)(bn + row) * CC + k0 + (cb >> 1),
                        (char*)&Bs[0][0] + chunk * 1024);
        }
        __syncthreads();
        #pragma unroll
        for (int ks = 0; ks < 2; ks++) {
            bf16x8 af[4], bfr[4];
            #pragma unroll
            for (int i = 0; i < 4; i++) {
                int row = wr * 64 + i * 16 + (l & 15);
                int cb = (ks * 64 + (l >> 4) * 16) ^ ((row & 7) << 4);
                af[i] = *(const bf16x8*)((const char*)&As[0][0] + row * 128 + cb);
            }
            #pragma unroll
            for (int j = 0; j < 4; j++) {
                int row = wc * 64 + j * 16 + (l & 15);
                int cb = (ks * 64 + (l >> 4) * 16) ^ ((row & 7) << 4);
                bfr[j] = *(const bf16x8*)((const char*)&Bs[0][0] + row * 128 + cb);
            }
            #pragma unroll
            for (int i = 0; i < 4; i++)
                #pragma unroll
                for (int j = 0; j < 4; j++)
                    acc[i][j] = __builtin_amdgcn_mfma_f32_16x16x32_bf16(af[i], bfr[j], acc[i][j], 0, 0, 0);
        }
    }
    int pidx = blockIdx.x * 2 + wc;
    #pragma unroll
    for (int i = 0; i < 4; i++) {
        int row = bm + wr * 64 + i * 16 + (l >> 4) * 4;
        #pragma unroll
        for (int r = 0; r < 4; r++) {
            float pv[4];
            float rmax = -1e30f;
            #pragma unroll
            for (int j = 0; j < 4; j++) {
                int col = bn + wc * 64 + j * 16 + (l & 15);
                float v = -1e30f;
                if (col < VV) {
                    v = acc[i][j][r] + bias[col];
                    Cf[(size_t)(row + r) * VV + col] = v;
                }
                pv[j] = v;
                rmax = fmaxf(rmax, v);
            }
            #pragma unroll
            for (int msk = 1; msk < 16; msk <<= 1)
                rmax = fmaxf(rmax, __shfl_xor(rmax, msk));
            float s = 0.f;
            #pragma unroll
            for (int j = 0; j < 4; j++) s += __expf(pv[j] - rmax);
            #pragma unroll
            for (int msk = 1; msk < 16; msk <<= 1)
                s += __shfl_xor(s, msk);
            if ((l & 15) == 0) {
                pm[(size_t)(row + r) * NPART + pidx] = rmax;
                ps[(size_t)(row + r) * NPART + pidx] = s;
            }
        }
    }
}

// ---------------- combine LSE partials -> per-row NLL
__global__ __launch_bounds__(256) void nll_combine(const float* __restrict__ pm,
                                                   const float* __restrict__ ps,
                                                   const float* __restrict__ logits,
                                                   const int* __restrict__ y,
                                                   float* __restrict__ rl) {
    int m = blockIdx.x, tid = threadIdx.x;
    __shared__ float rm[256], rs[256];
    float mt = -1e30f, st = 0.f;
    for (int i = tid; i < NPART; i += 256) {
        float mi = pm[(size_t)m * NPART + i];
        float si = ps[(size_t)m * NPART + i];
        float mn = fmaxf(mt, mi);
        st = st * __expf(mt - mn) + si * __expf(mi - mn);
        mt = mn;
    }
    rm[tid] = mt; rs[tid] = st; __syncthreads();
    for (int off = 128; off > 0; off >>= 1) {
        if (tid < off) {
            float ma = rm[tid], mb = rm[tid + off];
            float mn = fmaxf(ma, mb);
            rs[tid] = rs[tid] * __expf(ma - mn) + rs[tid + off] * __expf(mb - mn);
            rm[tid] = mn;
        }
        __syncthreads();
    }
    if (tid == 0)
        rl[m] = logf(rs[0]) + rm[0] - logits[(size_t)m * VV + y[m]];
}

// ---------------- QKV MFMA GEMM: A=hb [4096,768]; k,q -> bf16 [B,H,T,D]; v -> bf16 [B,H,D,T]
__global__ __launch_bounds__(256) void gemm_qkv_mfma(const __hip_bfloat16* __restrict__ A,
                                                     const __hip_bfloat16* __restrict__ kT,
                                                     const __hip_bfloat16* __restrict__ qT,
                                                     const __hip_bfloat16* __restrict__ vT,
                                                     __hip_bfloat16* __restrict__ ko,
                                                     __hip_bfloat16* __restrict__ qo,
                                                     __hip_bfloat16* __restrict__ vto) {
    const __hip_bfloat16* Bt = (blockIdx.z == 0) ? kT : (blockIdx.z == 1) ? qT : vT;
    __shared__ __hip_bfloat16 As[128][64];
    __shared__ __hip_bfloat16 Bs[128][64];
    int tid = threadIdx.x;
    int l = tid & 63, w = tid >> 6;
    int wr = w >> 1, wc = w & 1;
    int bm = blockIdx.y * 128, bn = blockIdx.x * 128;

    f32x4 acc[4][4] = {};

    for (int k0 = 0; k0 < CC; k0 += 64) {
        __syncthreads();
        #pragma unroll
        for (int it = 0; it < 4; it++) {
            int chunk = w * 4 + it;
            int o = chunk * 1024 + l * 16;
            int row = o >> 7;
            int cb = (o & 127) ^ ((row & 7) << 4);
            gload_lds16(A + (size_t)(bm + row) * CC + k0 + (cb >> 1),
                        (char*)&As[0][0] + chunk * 1024);
            gload_lds16(Bt + (size_t)(bn + row) * CC + k0 + (cb >> 1),
                        (char*)&Bs[0][0] + chunk * 1024);
        }
        __syncthreads();
        #pragma unroll
        for (int ks = 0; ks < 2; ks++) {
            bf16x8 af[4], bfr[4];
            #pragma unroll
            for (int i = 0; i < 4; i++) {
                int row = wr * 64 + i * 16 + (l & 15);
                int cb = (ks * 64 + (l >> 4) * 16) ^ ((row & 7) << 4);
                af[i] = *(const bf16x8*)((const char*)&As[0][0] + row * 128 + cb);
            }
            #pragma unroll
            for (int j = 0; j < 4; j++) {
                int row = wc * 64 + j * 16 + (l & 15);
                int cb = (ks * 64 + (l >> 4) * 16) ^ ((row & 7) << 4);
                bfr[j] = *(const bf16x8*)((const char*)&Bs[0][0] + row * 128 + cb);
            }
            #pragma unroll
            for (int i = 0; i < 4; i++)
                #pragma unroll
                for (int j = 0; j < 4; j++)
                    acc[i][j] = __builtin_amdgcn_mfma_f32_16x16x32_bf16(af[i], bfr[j], acc[i][j], 0, 0, 0);
        }
    }
    int zz = blockIdx.z;
    #pragma unroll
    for (int i = 0; i < 4; i++) {
        int row = bm + wr * 64 + i * 16 + (l >> 4) * 4;
        #pragma unroll
        for (int j = 0; j < 4; j++) {
            int col = bn + wc * 64 + j * 16 + (l & 15);
            int head = col >> 6, d = col & 63;
            #pragma unroll
            for (int r = 0; r < 4; r++) {
                int m = row + r;
                int b = m >> 10, t = m & 1023;
                __hip_bfloat16 val = __float2bfloat16(acc[i][j][r]);
                if (zz == 0)      ko[(((size_t)(b * HH + head)) * TT + t) * DD + d] = val;
                else if (zz == 1) qo[(((size_t)(b * HH + head)) * TT + t) * DD + d] = val;
                else              vto[(((size_t)(b * HH + head)) * DD + d) * TT + t] = val;
            }
        }
    }
}

// ---------------- MFMA flash attention (quirk: k plays query role)
__global__ __launch_bounds__(256) void attn_mfma(const __hip_bfloat16* __restrict__ kq,
                                                 const __hip_bfloat16* __restrict__ qk,
                                                 const __hip_bfloat16* __restrict__ vt,
                                                 __hip_bfloat16* __restrict__ oc) {
    __shared__ __hip_bfloat16 Qs[KVBLK * 64];
    __shared__ __hip_bfloat16 Vs[64 * KVBLK];
    __shared__ __hip_bfloat16 Ps[QBLK * KVBLK];
    int tid = threadIdx.x;
    int l = tid & 63, w = tid >> 6;
    int t0 = blockIdx.x * QBLK;
    size_t bh = (size_t)(blockIdx.z * HH + blockIdx.y);
    const __hip_bfloat16* kqp = kq + bh * TT * DD;
    const __hip_bfloat16* qkp = qk + bh * TT * DD;
    const __hip_bfloat16* vtp = vt + bh * DD * TT;

    bf16x8 af[2][2];
    #pragma unroll
    for (int i = 0; i < 2; i++)
        #pragma unroll
        for (int ks = 0; ks < 2; ks++)
            af[i][ks] = *(const bf16x8*)&kqp[(size_t)(t0 + w * 32 + i * 16 + (l & 15)) * DD
                                             + ks * 32 + (l >> 4) * 8];

    f32x4 acc_o[2][4] = {};
    float mrow[2][4], lrow[2][4];
    #pragma unroll
    for (int i = 0; i < 2; i++)
        #pragma unroll
        for (int r = 0; r < 4; r++) { mrow[i][r] = -1e30f; lrow[i][r] = 0.f; }

    for (int s0 = 0; s0 < t0 + QBLK; s0 += KVBLK) {
        __syncthreads();
        #pragma unroll
        for (int it = 0; it < 2; it++) {
            int chunk = w * 2 + it;
            int o = chunk * 1024 + l * 16;
            int row = o >> 7;
            int cb = (o & 127) ^ ((row & 7) << 4);
            gload_lds16(qkp + (size_t)(s0 + row) * DD + (cb >> 1),
                        (char*)Qs + chunk * 1024);
            gload_lds16(vtp + (size_t)row * TT + s0 + (cb >> 1),
                        (char*)Vs + chunk * 1024);
        }
        __syncthreads();

        f32x4 sa[2][4] = {};
        #pragma unroll
        for (int ks = 0; ks < 2; ks++) {
            bf16x8 bfr[4];
            #pragma unroll
            for (int j = 0; j < 4; j++) {
                int row = j * 16 + (l & 15);
                int cb = (ks * 64 + (l >> 4) * 16) ^ ((row & 7) << 4);
                bfr[j] = *(const bf16x8*)((const char*)Qs + row * 128 + cb);
            }
            #pragma unroll
            for (int i = 0; i < 2; i++)
                #pragma unroll
                for (int j = 0; j < 4; j++)
                    sa[i][j] = __builtin_amdgcn_mfma_f32_16x16x32_bf16(af[i][ks], bfr[j], sa[i][j], 0, 0, 0);
        }

        #pragma unroll
        for (int i = 0; i < 2; i++) {
            #pragma unroll
            for (int r = 0; r < 4; r++) {
                int t = t0 + w * 32 + i * 16 + (l >> 4) * 4 + r;
                float pv[4];
                float rmax = -1e30f;
                #pragma unroll
                for (int j = 0; j < 4; j++) {
                    int s = s0 + j * 16 + (l & 15);
                    float v = sa[i][j][r] * 0.125f;
                    v = (s <= t) ? v : -1e30f;
                    pv[j] = v;
                    rmax = fmaxf(rmax, v);
                }
                #pragma unroll
                for (int msk = 1; msk < 16; msk <<= 1)
                    rmax = fmaxf(rmax, __shfl_xor(rmax, msk));
                float mo = mrow[i][r];
                float mn = fmaxf(mo, rmax);
                float fac = __expf(mo - mn);
                float ls = 0.f;
                int prow = w * 32 + i * 16 + (l >> 4) * 4 + r;
                #pragma unroll
                for (int j = 0; j < 4; j++) {
                    float e = __expf(pv[j] - mn);
                    ls += e;
                    int cb = (j * 32 + (l & 15) * 2) ^ ((prow & 7) << 4);
                    *(__hip_bfloat16*)((char*)Ps + prow * 128 + cb) = __float2bfloat16(e);
                }
                #pragma unroll
                for (int msk = 1; msk < 16; msk <<= 1)
                    ls += __shfl_xor(ls, msk);
                mrow[i][r] = mn;
                lrow[i][r] = lrow[i][r] * fac + ls;
                #pragma unroll
                for (int jd = 0; jd < 4; jd++)
                    acc_o[i][jd][r] *= fac;
            }
        }
        __syncthreads();

        #pragma unroll
        for (int ks = 0; ks < 2; ks++) {
            bf16x8 pa[2], vf[4];
            #pragma unroll
            for (int i = 0; i < 2; i++) {
                int row = w * 32 + i * 16 + (l & 15);
                int cb = (ks * 64 + (l >> 4) * 16) ^ ((row & 7) << 4);
                pa[i] = *(const bf16x8*)((const char*)Ps + row * 128 + cb);
            }
            #pragma unroll
            for (int jd = 0; jd < 4; jd++) {
                int row = jd * 16 + (l & 15);
                int cb = (ks * 64 + (l >> 4) * 16) ^ ((row & 7) << 4);
                vf[jd] = *(const bf16x8*)((const char*)Vs + row * 128 + cb);
            }
            #pragma unroll
            for (int i = 0; i < 2; i++)
                #pragma unroll
                for (int jd = 0; jd < 4; jd++)
                    acc_o[i][jd] = __builtin_amdgcn_mfma_f32_16x16x32_bf16(pa[i], vf[jd], acc_o[i][jd], 0, 0, 0);
        }
    }

    int b = blockIdx.z, hh = blockIdx.y;
    #pragma unroll
    for (int i = 0; i < 2; i++) {
        #pragma unroll
        for (int r = 0; r < 4; r++) {
            float inv = 1.f / lrow[i][r];
            int t = t0 + w * 32 + i * 16 + (l >> 4) * 4 + r;
            #pragma unroll
            for (int jd = 0; jd < 4; jd++) {
                int d = jd * 16 + (l & 15);
                oc[((size_t)(b * TT + t)) * CC + hh * DD + d] =
                    __float2bfloat16(acc_o[i][jd][r] * inv);
            }
        }
    }
}

// ---------------- h = LN(h + t); writes f32 h and bf16 hb
__global__ __launch_bounds__(256) void resid_ln(float* __restrict__ h,
                                                const float* __restrict__ t,
                                                const float* __restrict__ g,
                                                const float* __restrict__ bta,
                                                __hip_bfloat16* __restrict__ hb) {
    int row = blockIdx.x;
    int tid = threadIdx.x;
    __shared__ float red[256];
    float x[3];
    float s = 0.f;
    #pragma unroll
    for (int i = 0; i < 3; i++) {
        int c = tid + i * 256;
        x[i] = h[(size_t)row * CC + c] + t[(size_t)row * CC + c];
        s += x[i];
    }
    red[tid] = s; __syncthreads();
    for (int off = 128; off > 0; off >>= 1) {
        if (tid < off) red[tid] += red[tid + off];
        __syncthreads();
    }
    float mean = red[0] * (1.f / CC); __syncthreads();
    float s2 = 0.f;
    #pragma unroll
    for (int i = 0; i < 3; i++) { float dd = x[i] - mean; s2 += dd * dd; }
    red[tid] = s2; __syncthreads();
    for (int off = 128; off > 0; off >>= 1) {
        if (tid < off) red[tid] += red[tid + off];
        __syncthreads();
    }
    float inv = rsqrtf(red[0] * (1.f / CC) + 1e-5f);
    #pragma unroll
    for (int i = 0; i < 3; i++) {
        int c = tid + i * 256;
        float o = (x[i] - mean) * inv * g[c] + bta[c];
        h[(size_t)row * CC + c] = o;
        hb[(size_t)row * CC + c] = __float2bfloat16(o);
    }
}

__global__ __launch_bounds__(256) void loss_reduce(const float* __restrict__ rl,
                                                   float* __restrict__ out) {
    int tid = threadIdx.x;
    __shared__ float red[256];
    float s = 0.f;
    for (int i = tid; i < MROWS; i += 256) s += rl[i];
    red[tid] = s; __syncthreads();
    for (int off = 128; off > 0; off >>= 1) {
        if (tid < off) red[tid] += red[tid + off];
        __syncthreads();
    }
    if (tid == 0) out[0] = red[0] * (1.f / MROWS);
}

extern "C" void kernel_launch(void* const* d_in, const int* in_sizes, int n_in,
                              void* d_out, int out_size, void* d_ws, size_t ws_size,
                              hipStream_t stream) {
    const int*   x     = (const int*)d_in[0];
    const int*   y     = (const int*)d_in[1];
    const float* tok   = (const float*)d_in[2];
    const float* pos   = (const float*)d_in[3];
    const float* Wk    = (const float*)d_in[4];
    const float* Wq    = (const float*)d_in[5];
    const float* Wv    = (const float*)d_in[6];
    const float* Wproj = (const float*)d_in[7];
    const float* bproj = (const float*)d_in[8];
    const float* ln1g  = (const float*)d_in[9];
    const float* ln1b  = (const float*)d_in[10];
    const float* W1    = (const float*)d_in[11];
    const float* b1    = (const float*)d_in[12];
    const float* W2    = (const float*)d_in[13];
    const float* b2    = (const float*)d_in[14];
    const float* ln2g  = (const float*)d_in[15];
    const float* ln2b  = (const float*)d_in[16];
    const float* Wlm   = (const float*)d_in[17];
    const float* blm   = (const float*)d_in[18];

    float* logits = (float*)d_out;
    float* lossp  = (float*)d_out + ((size_t)out_size - 1);

    char* p = (char*)d_ws;
    auto alloc = [&](size_t bytes) { char* r = p; p += (bytes + 255) & ~255ULL; return r; };
    const size_t S_HC = (size_t)MROWS * CC;

    float* h    = (float*)alloc(S_HC * 4);
    float* tmpf = (float*)alloc(S_HC * 4);
    float* rl   = (float*)alloc(MROWS * 4);
    float* pm   = (float*)alloc((size_t)MROWS * NPART * 4);
    float* ps   = (float*)alloc((size_t)MROWS * NPART * 4);
    __hip_bfloat16* kbb  = (__hip_bfloat16*)alloc(S_HC * 2);
    __hip_bfloat16* qbb  = (__hip_bfloat16*)alloc(S_HC * 2);
    __hip_bfloat16* vtb  = (__hip_bfloat16*)alloc(S_HC * 2);
    __hip_bfloat16* hb   = (__hip_bfloat16*)alloc(S_HC * 2);
    __hip_bfloat16* ocb  = (__hip_bfloat16*)alloc(S_HC * 2);
    __hip_bfloat16* ff1b = (__hip_bfloat16*)alloc((size_t)MROWS * FFH * 2);
    __hip_bfloat16* kT   = (__hip_bfloat16*)alloc((size_t)LL * CC * CC * 2);
    __hip_bfloat16* qT   = (__hip_bfloat16*)alloc((size_t)LL * CC * CC * 2);
    __hip_bfloat16* vT   = (__hip_bfloat16*)alloc((size_t)LL * CC * CC * 2);
    __hip_bfloat16* pT   = (__hip_bfloat16*)alloc((size_t)LL * CC * CC * 2);
    __hip_bfloat16* w1T  = (__hip_bfloat16*)alloc((size_t)LL * CC * FFH * 2);
    __hip_bfloat16* w2T  = (__hip_bfloat16*)alloc((size_t)LL * FFH * CC * 2);
    __hip_bfloat16* lmT  = (__hip_bfloat16*)alloc((size_t)VPAD * CC * 2);

    dim3 blk(256);

    cvtT_qkv<<<dim3(24, 2, 3 * 144), blk, 0, stream>>>(Wk, Wq, Wv, kT, qT, vT);
    cvtT_mat<<<dim3(24, 24, LL), blk, 0, stream>>>(Wproj, pT, CC, CC,
                                                   (size_t)CC * CC, (size_t)CC * CC);
    cvtT_mat<<<dim3(96, 24, LL), blk, 0, stream>>>(W1, w1T, CC, FFH,
                                                   (size_t)CC * FFH, (size_t)FFH * CC);
    cvtT_mat<<<dim3(24, 96, LL), blk, 0, stream>>>(W2, w2T, FFH, CC,
                                                   (size_t)FFH * CC, (size_t)CC * FFH);
    cvtT_mat<<<dim3(VPAD / 32, 24, 1), blk, 0, stream>>>(Wlm, lmT, CC, VV, 0, 0);

    embed_kernel<<<dim3((MROWS * CC + 255) / 256), blk, 0, stream>>>(x, tok, pos, h, hb);

    for (int l = 0; l < LL; l++) {
        const __hip_bfloat16* kT_l = kT + (size_t)l * CC * CC;
        const __hip_bfloat16* qT_l = qT + (size_t)l * CC * CC;
        const __hip_bfloat16* vT_l = vT + (size_t)l * CC * CC;
        const __hip_bfloat16* pT_l = pT + (size_t)l * CC * CC;
        const __hip_bfloat16* w1T_l = w1T + (size_t)l * CC * FFH;
        const __hip_bfloat16* w2T_l = w2T + (size_t)l * FFH * CC;

        gemm_qkv_mfma<<<dim3(CC / 128, MROWS / 128, 3), blk, 0, stream>>>(
            hb, kT_l, qT_l, vT_l, kbb, qbb, vtb);
        attn_mfma<<<dim3(TT / QBLK, HH, BB), blk, 0, stream>>>(kbb, qbb, vtb, ocb);
        gemm_mfma<<<dim3(CC / 128, MROWS / 128), blk, 0, stream>>>(
            ocb, pT_l, bproj + (size_t)l * CC, tmpf, (__hip_bfloat16*)nullptr,
            MROWS, CC, CC, 0);
        resid_ln<<<dim3(MROWS), blk, 0, stream>>>(h, tmpf, ln1g + (size_t)l * CC,
                                                  ln1b + (size_t)l * CC, hb);
        gemm_mfma<<<dim3(FFH / 128, MROWS / 128), blk, 0, stream>>>(
            hb, w1T_l, b1 + (size_t)l * FFH, (float*)nullptr, ff1b,
            MROWS, FFH, CC, 1);
        gemm_mfma<<<dim3(CC / 128, MROWS / 128), blk, 0, stream>>>(
            ff1b, w2T_l, b2 + (size_t)l * CC, tmpf, (__hip_bfloat16*)nullptr,
            MROWS, CC, FFH, 0);
        resid_ln<<<dim3(MROWS), blk, 0, stream>>>(h, tmpf, ln2g + (size_t)l * CC,
                                                  ln2b + (size_t)l * CC, hb);
    }

    lm_head_mfma<<<dim3(VPAD / 128, MROWS / 128), blk, 0, stream>>>(
        hb, lmT, blm, logits, pm, ps);
    nll_combine<<<dim3(MROWS), blk, 0, stream>>>(pm, ps, logits, y, rl);
    loss_reduce<<<dim3(1), blk, 0, stream>>>(rl, lossp);
}

// Round 6
// 4154.606 us; speedup vs baseline: 12.8619x; 1.0612x over previous
//
#include <hip/hip_runtime.h>
#include <hip/hip_bf16.h>
#include <math.h>

#define BB 4
#define TT 1024
#define VV 50257
#define VPAD 50304
#define CC 768
#define HH 12
#define DD 64
#define LL 12
#define FFH 3072
#define MROWS (BB*TT)   // 4096
#define QBLK 128
#define KVBLK 64
#define NPART (2 * (VPAD / 128))   // 786 partials per row

typedef __bf16 bf16x8 __attribute__((ext_vector_type(8)));
typedef float  f32x4  __attribute__((ext_vector_type(4)));
typedef unsigned int u32;
#define AS1 __attribute__((address_space(1)))
#define AS3 __attribute__((address_space(3)))

static __device__ __forceinline__ void gload_lds16(const void* g, void* l) {
    __builtin_amdgcn_global_load_lds((const AS1 u32*)g, (AS3 u32*)l, 16, 0, 0);
}

// stage one 128x64 bf16 tile pair (A,B) into linear LDS, source pre-swizzled
static __device__ __forceinline__ void stage_tile(const __hip_bfloat16* __restrict__ A,
                                                  const __hip_bfloat16* __restrict__ Bt,
                                                  int Kld, int k0, int bm, int bn,
                                                  int w, int l,
                                                  __hip_bfloat16* As, __hip_bfloat16* Bs) {
    #pragma unroll
    for (int it = 0; it < 4; it++) {
        int chunk = w * 4 + it;
        int o = chunk * 1024 + l * 16;
        int row = o >> 7;
        int cb = (o & 127) ^ ((row & 7) << 4);
        gload_lds16(A + (size_t)(bm + row) * Kld + k0 + (cb >> 1), (char*)As + chunk * 1024);
        gload_lds16(Bt + (size_t)(bn + row) * Kld + k0 + (cb >> 1), (char*)Bs + chunk * 1024);
    }
}

// ---------------- embedding: h = tok_emb[x] + pos_emb[x]; also bf16 copy
__global__ void embed_kernel(const int* __restrict__ x, const float* __restrict__ tok,
                             const float* __restrict__ pos, float* __restrict__ h,
                             __hip_bfloat16* __restrict__ hb) {
    int idx = blockIdx.x * 256 + threadIdx.x;
    if (idx >= MROWS * CC) return;
    int row = idx / CC, c = idx - row * CC;
    int id = x[row];
    float v = tok[(size_t)id * CC + c] + pos[(size_t)id * CC + c];
    h[idx] = v;
    hb[idx] = __float2bfloat16(v);
}

// ---------------- convert + transpose: out[b][n][k] = (n<Nin ? in[b][k][n] : 0), bf16
__global__ __launch_bounds__(256) void cvtT_mat(const float* __restrict__ in,
                                                __hip_bfloat16* __restrict__ out,
                                                int K, int Nin,
                                                size_t ibs, size_t obs) {
    __shared__ float t[32][33];
    const float* ip = in + blockIdx.z * ibs;
    __hip_bfloat16* op = out + blockIdx.z * obs;
    int n0 = blockIdx.x * 32, k0 = blockIdx.y * 32;
    int tx = threadIdx.x & 31, ty = threadIdx.x >> 5;   // 32x8
    #pragma unroll
    for (int i = 0; i < 4; i++) {
        int k = k0 + ty + i * 8, n = n0 + tx;
        t[ty + i * 8][tx] = (n < Nin) ? ip[(size_t)k * Nin + n] : 0.f;
    }
    __syncthreads();
    #pragma unroll
    for (int i = 0; i < 4; i++) {
        int n = n0 + ty + i * 8, k = k0 + tx;
        op[(size_t)n * K + k] = __float2bfloat16(t[tx][ty + i * 8]);
    }
}

// ---------------- QKV weights (L,H,C,D) -> per-layer [768][768] bf16, row n=h*64+d, col c
__global__ __launch_bounds__(256) void cvtT_qkv(const float* __restrict__ Wk,
                                                const float* __restrict__ Wq,
                                                const float* __restrict__ Wv,
                                                __hip_bfloat16* __restrict__ kT,
                                                __hip_bfloat16* __restrict__ qT,
                                                __hip_bfloat16* __restrict__ vT) {
    int z = blockIdx.z;
    int tensor = z / 144, lh = z % 144;
    int l = lh / HH, hh = lh % HH;
    const float* in = (tensor == 0 ? Wk : tensor == 1 ? Wq : Wv) + (size_t)lh * CC * DD;
    __hip_bfloat16* out = (tensor == 0 ? kT : tensor == 1 ? qT : vT)
                          + ((size_t)l * CC + hh * DD) * CC;
    __shared__ float t[32][33];
    int c0 = blockIdx.x * 32, d0 = blockIdx.y * 32;
    int tx = threadIdx.x & 31, ty = threadIdx.x >> 5;
    #pragma unroll
    for (int i = 0; i < 4; i++)
        t[ty + i * 8][tx] = in[(size_t)(c0 + ty + i * 8) * DD + d0 + tx];
    __syncthreads();
    #pragma unroll
    for (int i = 0; i < 4; i++)
        out[(size_t)(d0 + ty + i * 8) * CC + c0 + tx] = __float2bfloat16(t[tx][ty + i * 8]);
}

// ---------------- MFMA GEMM, double-buffered: stage(t+1) issued before compute(t),
// single __syncthreads per K-tile (implicit vmcnt(0) drains loads issued a full tile ago).
__global__ __launch_bounds__(256) void gemm_mfma(const __hip_bfloat16* __restrict__ A,
                                                 const __hip_bfloat16* __restrict__ Bt,
                                                 const float* __restrict__ bias,
                                                 float* __restrict__ Cf,
                                                 __hip_bfloat16* __restrict__ Cb,
                                                 int M, int N, int K, int relu) {
    __shared__ __hip_bfloat16 As[2][128 * 64];
    __shared__ __hip_bfloat16 Bs[2][128 * 64];
    int tid = threadIdx.x;
    int l = tid & 63, w = tid >> 6;
    int wr = w >> 1, wc = w & 1;
    int bm = blockIdx.y * 128, bn = blockIdx.x * 128;

    f32x4 acc[4][4] = {};

    stage_tile(A, Bt, K, 0, bm, bn, w, l, As[0], Bs[0]);
    int p = 0;
    for (int k0 = 0; k0 < K; k0 += 64) {
        __syncthreads();                       // tile t landed; prev reads of buf p^1 retired
        if (k0 + 64 < K)
            stage_tile(A, Bt, K, k0 + 64, bm, bn, w, l, As[p ^ 1], Bs[p ^ 1]);
        const char* Ab = (const char*)As[p];
        const char* Bb = (const char*)Bs[p];
        #pragma unroll
        for (int ks = 0; ks < 2; ks++) {
            bf16x8 af[4], bfr[4];
            #pragma unroll
            for (int i = 0; i < 4; i++) {
                int row = wr * 64 + i * 16 + (l & 15);
                int cb = (ks * 64 + (l >> 4) * 16) ^ ((row & 7) << 4);
                af[i] = *(const bf16x8*)(Ab + row * 128 + cb);
            }
            #pragma unroll
            for (int j = 0; j < 4; j++) {
                int row = wc * 64 + j * 16 + (l & 15);
                int cb = (ks * 64 + (l >> 4) * 16) ^ ((row & 7) << 4);
                bfr[j] = *(const bf16x8*)(Bb + row * 128 + cb);
            }
            #pragma unroll
            for (int i = 0; i < 4; i++)
                #pragma unroll
                for (int j = 0; j < 4; j++)
                    acc[i][j] = __builtin_amdgcn_mfma_f32_16x16x32_bf16(af[i], bfr[j], acc[i][j], 0, 0, 0);
        }
        p ^= 1;
    }
    #pragma unroll
    for (int i = 0; i < 4; i++) {
        int row = bm + wr * 64 + i * 16 + (l >> 4) * 4;
        #pragma unroll
        for (int j = 0; j < 4; j++) {
            int col = bn + wc * 64 + j * 16 + (l & 15);
            if (col < N) {
                float bv = bias ? bias[col] : 0.f;
                #pragma unroll
                for (int r = 0; r < 4; r++) {
                    float v = acc[i][j][r] + bv;
                    if (relu) v = fmaxf(v, 0.f);
                    if (Cf) Cf[(size_t)(row + r) * N + col] = v;
                    if (Cb) Cb[(size_t)(row + r) * N + col] = __float2bfloat16(v);
                }
            }
        }
    }
}

// ---------------- LM head: col-fastest grid + dbuf + fused LSE partials.
__global__ __launch_bounds__(256) void lm_head_mfma(const __hip_bfloat16* __restrict__ A,
                                                    const __hip_bfloat16* __restrict__ Bt,
                                                    const float* __restrict__ bias,
                                                    float* __restrict__ Cf,
                                                    float* __restrict__ pm,
                                                    float* __restrict__ ps) {
    __shared__ __hip_bfloat16 As[2][128 * 64];
    __shared__ __hip_bfloat16 Bs[2][128 * 64];
    int tid = threadIdx.x;
    int l = tid & 63, w = tid >> 6;
    int wr = w >> 1, wc = w & 1;
    int bm = blockIdx.y * 128, bn = blockIdx.x * 128;   // col-fastest

    f32x4 acc[4][4] = {};

    stage_tile(A, Bt, CC, 0, bm, bn, w, l, As[0], Bs[0]);
    int p = 0;
    for (int k0 = 0; k0 < CC; k0 += 64) {
        __syncthreads();
        if (k0 + 64 < CC)
            stage_tile(A, Bt, CC, k0 + 64, bm, bn, w, l, As[p ^ 1], Bs[p ^ 1]);
        const char* Ab = (const char*)As[p];
        const char* Bb = (const char*)Bs[p];
        #pragma unroll
        for (int ks = 0; ks < 2; ks++) {
            bf16x8 af[4], bfr[4];
            #pragma unroll
            for (int i = 0; i < 4; i++) {
                int row = wr * 64 + i * 16 + (l & 15);
                int cb = (ks * 64 + (l >> 4) * 16) ^ ((row & 7) << 4);
                af[i] = *(const bf16x8*)(Ab + row * 128 + cb);
            }
            #pragma unroll
            for (int j = 0; j < 4; j++) {
                int row = wc * 64 + j * 16 + (l & 15);
                int cb = (ks * 64 + (l >> 4) * 16) ^ ((row & 7) << 4);
                bfr[j] = *(const bf16x8*)(Bb + row * 128 + cb);
            }
            #pragma unroll
            for (int i = 0; i < 4; i++)
                #pragma unroll
                for (int j = 0; j < 4; j++)
                    acc[i][j] = __builtin_amdgcn_mfma_f32_16x16x32_bf16(af[i], bfr[j], acc[i][j], 0, 0, 0);
        }
        p ^= 1;
    }
    int pidx = blockIdx.x * 2 + wc;
    #pragma unroll
    for (int i = 0; i < 4; i++) {
        int row = bm + wr * 64 + i * 16 + (l >> 4) * 4;
        #pragma unroll
        for (int r = 0; r < 4; r++) {
            float pv[4];
            float rmax = -1e30f;
            #pragma unroll
            for (int j = 0; j < 4; j++) {
                int col = bn + wc * 64 + j * 16 + (l & 15);
                float v = -1e30f;
                if (col < VV) {
                    v = acc[i][j][r] + bias[col];
                    Cf[(size_t)(row + r) * VV + col] = v;
                }
                pv[j] = v;
                rmax = fmaxf(rmax, v);
            }
            #pragma unroll
            for (int msk = 1; msk < 16; msk <<= 1)
                rmax = fmaxf(rmax, __shfl_xor(rmax, msk));
            float s = 0.f;
            #pragma unroll
            for (int j = 0; j < 4; j++) s += __expf(pv[j] - rmax);
            #pragma unroll
            for (int msk = 1; msk < 16; msk <<= 1)
                s += __shfl_xor(s, msk);
            if ((l & 15) == 0) {
                pm[(size_t)(row + r) * NPART + pidx] = rmax;
                ps[(size_t)(row + r) * NPART + pidx] = s;
            }
        }
    }
}

// ---------------- combine LSE partials -> per-row NLL
__global__ __launch_bounds__(256) void nll_combine(const float* __restrict__ pm,
                                                   const float* __restrict__ ps,
                                                   const float* __restrict__ logits,
                                                   const int* __restrict__ y,
                                                   float* __restrict__ rl) {
    int m = blockIdx.x, tid = threadIdx.x;
    __shared__ float rm[256], rs[256];
    float mt = -1e30f, st = 0.f;
    for (int i = tid; i < NPART; i += 256) {
        float mi = pm[(size_t)m * NPART + i];
        float si = ps[(size_t)m * NPART + i];
        float mn = fmaxf(mt, mi);
        st = st * __expf(mt - mn) + si * __expf(mi - mn);
        mt = mn;
    }
    rm[tid] = mt; rs[tid] = st; __syncthreads();
    for (int off = 128; off > 0; off >>= 1) {
        if (tid < off) {
            float ma = rm[tid], mb = rm[tid + off];
            float mn = fmaxf(ma, mb);
            rs[tid] = rs[tid] * __expf(ma - mn) + rs[tid + off] * __expf(mb - mn);
            rm[tid] = mn;
        }
        __syncthreads();
    }
    if (tid == 0)
        rl[m] = logf(rs[0]) + rm[0] - logits[(size_t)m * VV + y[m]];
}

// ---------------- QKV MFMA GEMM (dbuf): k,q -> bf16 [B,H,T,D]; v -> bf16 [B,H,D,T]
__global__ __launch_bounds__(256) void gemm_qkv_mfma(const __hip_bfloat16* __restrict__ A,
                                                     const __hip_bfloat16* __restrict__ kT,
                                                     const __hip_bfloat16* __restrict__ qT,
                                                     const __hip_bfloat16* __restrict__ vT,
                                                     __hip_bfloat16* __restrict__ ko,
                                                     __hip_bfloat16* __restrict__ qo,
                                                     __hip_bfloat16* __restrict__ vto) {
    const __hip_bfloat16* Bt = (blockIdx.z == 0) ? kT : (blockIdx.z == 1) ? qT : vT;
    __shared__ __hip_bfloat16 As[2][128 * 64];
    __shared__ __hip_bfloat16 Bs[2][128 * 64];
    int tid = threadIdx.x;
    int l = tid & 63, w = tid >> 6;
    int wr = w >> 1, wc = w & 1;
    int bm = blockIdx.y * 128, bn = blockIdx.x * 128;

    f32x4 acc[4][4] = {};

    stage_tile(A, Bt, CC, 0, bm, bn, w, l, As[0], Bs[0]);
    int p = 0;
    for (int k0 = 0; k0 < CC; k0 += 64) {
        __syncthreads();
        if (k0 + 64 < CC)
            stage_tile(A, Bt, CC, k0 + 64, bm, bn, w, l, As[p ^ 1], Bs[p ^ 1]);
        const char* Ab = (const char*)As[p];
        const char* Bb = (const char*)Bs[p];
        #pragma unroll
        for (int ks = 0; ks < 2; ks++) {
            bf16x8 af[4], bfr[4];
            #pragma unroll
            for (int i = 0; i < 4; i++) {
                int row = wr * 64 + i * 16 + (l & 15);
                int cb = (ks * 64 + (l >> 4) * 16) ^ ((row & 7) << 4);
                af[i] = *(const bf16x8*)(Ab + row * 128 + cb);
            }
            #pragma unroll
            for (int j = 0; j < 4; j++) {
                int row = wc * 64 + j * 16 + (l & 15);
                int cb = (ks * 64 + (l >> 4) * 16) ^ ((row & 7) << 4);
                bfr[j] = *(const bf16x8*)(Bb + row * 128 + cb);
            }
            #pragma unroll
            for (int i = 0; i < 4; i++)
                #pragma unroll
                for (int j = 0; j < 4; j++)
                    acc[i][j] = __builtin_amdgcn_mfma_f32_16x16x32_bf16(af[i], bfr[j], acc[i][j], 0, 0, 0);
        }
        p ^= 1;
    }
    int zz = blockIdx.z;
    #pragma unroll
    for (int i = 0; i < 4; i++) {
        int row = bm + wr * 64 + i * 16 + (l >> 4) * 4;
        #pragma unroll
        for (int j = 0; j < 4; j++) {
            int col = bn + wc * 64 + j * 16 + (l & 15);
            int head = col >> 6, d = col & 63;
            #pragma unroll
            for (int r = 0; r < 4; r++) {
                int m = row + r;
                int b = m >> 10, t = m & 1023;
                __hip_bfloat16 val = __float2bfloat16(acc[i][j][r]);
                if (zz == 0)      ko[(((size_t)(b * HH + head)) * TT + t) * DD + d] = val;
                else if (zz == 1) qo[(((size_t)(b * HH + head)) * TT + t) * DD + d] = val;
                else              vto[(((size_t)(b * HH + head)) * DD + d) * TT + t] = val;
            }
        }
    }
}

// ---------------- MFMA flash attention (quirk: k plays query role)
// dbuf K/V staging; single barrier per KV tile (P is wave-private -> no mid barrier).
__global__ __launch_bounds__(256) void attn_mfma(const __hip_bfloat16* __restrict__ kq,
                                                 const __hip_bfloat16* __restrict__ qk,
                                                 const __hip_bfloat16* __restrict__ vt,
                                                 __hip_bfloat16* __restrict__ oc) {
    __shared__ __hip_bfloat16 Qs[2][KVBLK * 64];
    __shared__ __hip_bfloat16 Vs[2][64 * KVBLK];
    __shared__ __hip_bfloat16 Ps[QBLK * KVBLK];
    int tid = threadIdx.x;
    int l = tid & 63, w = tid >> 6;
    int t0 = blockIdx.x * QBLK;
    size_t bh = (size_t)(blockIdx.z * HH + blockIdx.y);
    const __hip_bfloat16* kqp = kq + bh * TT * DD;
    const __hip_bfloat16* qkp = qk + bh * TT * DD;
    const __hip_bfloat16* vtp = vt + bh * DD * TT;

    bf16x8 af[2][2];
    #pragma unroll
    for (int i = 0; i < 2; i++)
        #pragma unroll
        for (int ks = 0; ks < 2; ks++)
            af[i][ks] = *(const bf16x8*)&kqp[(size_t)(t0 + w * 32 + i * 16 + (l & 15)) * DD
                                             + ks * 32 + (l >> 4) * 8];

    f32x4 acc_o[2][4] = {};
    float mrow[2][4], lrow[2][4];
    #pragma unroll
    for (int i = 0; i < 2; i++)
        #pragma unroll
        for (int r = 0; r < 4; r++) { mrow[i][r] = -1e30f; lrow[i][r] = 0.f; }

    auto stageKV = [&](int pp, int s0) {
        #pragma unroll
        for (int it = 0; it < 2; it++) {
            int chunk = w * 2 + it;
            int o = chunk * 1024 + l * 16;
            int row = o >> 7;
            int cb = (o & 127) ^ ((row & 7) << 4);
            gload_lds16(qkp + (size_t)(s0 + row) * DD + (cb >> 1),
                        (char*)Qs[pp] + chunk * 1024);
            gload_lds16(vtp + (size_t)row * TT + s0 + (cb >> 1),
                        (char*)Vs[pp] + chunk * 1024);
        }
    };

    int nt = (t0 + QBLK) / KVBLK;
    stageKV(0, 0);
    int p = 0;
    for (int ti = 0; ti < nt; ti++) {
        int s0 = ti * KVBLK;
        __syncthreads();                       // KV tile ti landed; prev Vs/Qs reads retired
        if (ti + 1 < nt) stageKV(p ^ 1, s0 + KVBLK);

        // S = k @ q^T for this tile
        f32x4 sa[2][4] = {};
        #pragma unroll
        for (int ks = 0; ks < 2; ks++) {
            bf16x8 bfr[4];
            #pragma unroll
            for (int j = 0; j < 4; j++) {
                int row = j * 16 + (l & 15);
                int cb = (ks * 64 + (l >> 4) * 16) ^ ((row & 7) << 4);
                bfr[j] = *(const bf16x8*)((const char*)Qs[p] + row * 128 + cb);
            }
            #pragma unroll
            for (int i = 0; i < 2; i++)
                #pragma unroll
                for (int j = 0; j < 4; j++)
                    sa[i][j] = __builtin_amdgcn_mfma_f32_16x16x32_bf16(af[i][ks], bfr[j], sa[i][j], 0, 0, 0);
        }

        // online softmax -> Ps (wave-private 32-row band; same-wave RAW via lgkmcnt)
        #pragma unroll
        for (int i = 0; i < 2; i++) {
            #pragma unroll
            for (int r = 0; r < 4; r++) {
                int t = t0 + w * 32 + i * 16 + (l >> 4) * 4 + r;
                float pv[4];
                float rmax = -1e30f;
                #pragma unroll
                for (int j = 0; j < 4; j++) {
                    int s = s0 + j * 16 + (l & 15);
                    float v = sa[i][j][r] * 0.125f;
                    v = (s <= t) ? v : -1e30f;
                    pv[j] = v;
                    rmax = fmaxf(rmax, v);
                }
                #pragma unroll
                for (int msk = 1; msk < 16; msk <<= 1)
                    rmax = fmaxf(rmax, __shfl_xor(rmax, msk));
                float mo = mrow[i][r];
                float mn = fmaxf(mo, rmax);
                float fac = __expf(mo - mn);
                float ls = 0.f;
                int prow = w * 32 + i * 16 + (l >> 4) * 4 + r;
                #pragma unroll
                for (int j = 0; j < 4; j++) {
                    float e = __expf(pv[j] - mn);
                    ls += e;
                    int cb = (j * 32 + (l & 15) * 2) ^ ((prow & 7) << 4);
                    *(__hip_bfloat16*)((char*)Ps + prow * 128 + cb) = __float2bfloat16(e);
                }
                #pragma unroll
                for (int msk = 1; msk < 16; msk <<= 1)
                    ls += __shfl_xor(ls, msk);
                mrow[i][r] = mn;
                lrow[i][r] = lrow[i][r] * fac + ls;
                #pragma unroll
                for (int jd = 0; jd < 4; jd++)
                    acc_o[i][jd][r] *= fac;
            }
        }

        // O += P @ V  (A = own P rows, B = Vt rows)
        #pragma unroll
        for (int ks = 0; ks < 2; ks++) {
            bf16x8 pa[2], vf[4];
            #pragma unroll
            for (int i = 0; i < 2; i++) {
                int row = w * 32 + i * 16 + (l & 15);
                int cb = (ks * 64 + (l >> 4) * 16) ^ ((row & 7) << 4);
                pa[i] = *(const bf16x8*)((const char*)Ps + row * 128 + cb);
            }
            #pragma unroll
            for (int jd = 0; jd < 4; jd++) {
                int row = jd * 16 + (l & 15);
                int cb = (ks * 64 + (l >> 4) * 16) ^ ((row & 7) << 4);
                vf[jd] = *(const bf16x8*)((const char*)Vs[p] + row * 128 + cb);
            }
            #pragma unroll
            for (int i = 0; i < 2; i++)
                #pragma unroll
                for (int jd = 0; jd < 4; jd++)
                    acc_o[i][jd] = __builtin_amdgcn_mfma_f32_16x16x32_bf16(pa[i], vf[jd], acc_o[i][jd], 0, 0, 0);
        }
        p ^= 1;
    }

    int b = blockIdx.z, hh = blockIdx.y;
    #pragma unroll
    for (int i = 0; i < 2; i++) {
        #pragma unroll
        for (int r = 0; r < 4; r++) {
            float inv = 1.f / lrow[i][r];
            int t = t0 + w * 32 + i * 16 + (l >> 4) * 4 + r;
            #pragma unroll
            for (int jd = 0; jd < 4; jd++) {
                int d = jd * 16 + (l & 15);
                oc[((size_t)(b * TT + t)) * CC + hh * DD + d] =
                    __float2bfloat16(acc_o[i][jd][r] * inv);
            }
        }
    }
}

// ---------------- h = LN(h + t); writes f32 h and bf16 hb
__global__ __launch_bounds__(256) void resid_ln(float* __restrict__ h,
                                                const float* __restrict__ t,
                                                const float* __restrict__ g,
                                                const float* __restrict__ bta,
                                                __hip_bfloat16* __restrict__ hb) {
    int row = blockIdx.x;
    int tid = threadIdx.x;
    __shared__ float red[256];
    float x[3];
    float s = 0.f;
    #pragma unroll
    for (int i = 0; i < 3; i++) {
        int c = tid + i * 256;
        x[i] = h[(size_t)row * CC + c] + t[(size_t)row * CC + c];
        s += x[i];
    }
    red[tid] = s; __syncthreads();
    for (int off = 128; off > 0; off >>= 1) {
        if (tid < off) red[tid] += red[tid + off];
        __syncthreads();
    }
    float mean = red[0] * (1.f / CC); __syncthreads();
    float s2 = 0.f;
    #pragma unroll
    for (int i = 0; i < 3; i++) { float dd = x[i] - mean; s2 += dd * dd; }
    red[tid] = s2; __syncthreads();
    for (int off = 128; off > 0; off >>= 1) {
        if (tid < off) red[tid] += red[tid + off];
        __syncthreads();
    }
    float inv = rsqrtf(red[0] * (1.f / CC) + 1e-5f);
    #pragma unroll
    for (int i = 0; i < 3; i++) {
        int c = tid + i * 256;
        float o = (x[i] - mean) * inv * g[c] + bta[c];
        h[(size_t)row * CC + c] = o;
        hb[(size_t)row * CC + c] = __float2bfloat16(o);
    }
}

__global__ __launch_bounds__(256) void loss_reduce(const float* __restrict__ rl,
                                                   float* __restrict__ out) {
    int tid = threadIdx.x;
    __shared__ float red[256];
    float s = 0.f;
    for (int i = tid; i < MROWS; i += 256) s += rl[i];
    red[tid] = s; __syncthreads();
    for (int off = 128; off > 0; off >>= 1) {
        if (tid < off) red[tid] += red[tid + off];
        __syncthreads();
    }
    if (tid == 0) out[0] = red[0] * (1.f / MROWS);
}

extern "C" void kernel_launch(void* const* d_in, const int* in_sizes, int n_in,
                              void* d_out, int out_size, void* d_ws, size_t ws_size,
                              hipStream_t stream) {
    const int*   x     = (const int*)d_in[0];
    const int*   y     = (const int*)d_in[1];
    const float* tok   = (const float*)d_in[2];
    const float* pos   = (const float*)d_in[3];
    const float* Wk    = (const float*)d_in[4];
    const float* Wq    = (const float*)d_in[5];
    const float* Wv    = (const float*)d_in[6];
    const float* Wproj = (const float*)d_in[7];
    const float* bproj = (const float*)d_in[8];
    const float* ln1g  = (const float*)d_in[9];
    const float* ln1b  = (const float*)d_in[10];
    const float* W1    = (const float*)d_in[11];
    const float* b1    = (const float*)d_in[12];
    const float* W2    = (const float*)d_in[13];
    const float* b2    = (const float*)d_in[14];
    const float* ln2g  = (const float*)d_in[15];
    const float* ln2b  = (const float*)d_in[16];
    const float* Wlm   = (const float*)d_in[17];
    const float* blm   = (const float*)d_in[18];

    float* logits = (float*)d_out;
    float* lossp  = (float*)d_out + ((size_t)out_size - 1);

    char* p = (char*)d_ws;
    auto alloc = [&](size_t bytes) { char* r = p; p += (bytes + 255) & ~255ULL; return r; };
    const size_t S_HC = (size_t)MROWS * CC;

    float* h    = (float*)alloc(S_HC * 4);
    float* tmpf = (float*)alloc(S_HC * 4);
    float* rl   = (float*)alloc(MROWS * 4);
    float* pm   = (float*)alloc((size_t)MROWS * NPART * 4);
    float* ps   = (float*)alloc((size_t)MROWS * NPART * 4);
    __hip_bfloat16* kbb  = (__hip_bfloat16*)alloc(S_HC * 2);
    __hip_bfloat16* qbb  = (__hip_bfloat16*)alloc(S_HC * 2);
    __hip_bfloat16* vtb  = (__hip_bfloat16*)alloc(S_HC * 2);
    __hip_bfloat16* hb   = (__hip_bfloat16*)alloc(S_HC * 2);
    __hip_bfloat16* ocb  = (__hip_bfloat16*)alloc(S_HC * 2);
    __hip_bfloat16* ff1b = (__hip_bfloat16*)alloc((size_t)MROWS * FFH * 2);
    __hip_bfloat16* kT   = (__hip_bfloat16*)alloc((size_t)LL * CC * CC * 2);
    __hip_bfloat16* qT   = (__hip_bfloat16*)alloc((size_t)LL * CC * CC * 2);
    __hip_bfloat16* vT   = (__hip_bfloat16*)alloc((size_t)LL * CC * CC * 2);
    __hip_bfloat16* pT   = (__hip_bfloat16*)alloc((size_t)LL * CC * CC * 2);
    __hip_bfloat16* w1T  = (__hip_bfloat16*)alloc((size_t)LL * CC * FFH * 2);
    __hip_bfloat16* w2T  = (__hip_bfloat16*)alloc((size_t)LL * FFH * CC * 2);
    __hip_bfloat16* lmT  = (__hip_bfloat16*)alloc((size_t)VPAD * CC * 2);

    dim3 blk(256);

    cvtT_qkv<<<dim3(24, 2, 3 * 144), blk, 0, stream>>>(Wk, Wq, Wv, kT, qT, vT);
    cvtT_mat<<<dim3(24, 24, LL), blk, 0, stream>>>(Wproj, pT, CC, CC,
                                                   (size_t)CC * CC, (size_t)CC * CC);
    cvtT_mat<<<dim3(96, 24, LL), blk, 0, stream>>>(W1, w1T, CC, FFH,
                                                   (size_t)CC * FFH, (size_t)FFH * CC);
    cvtT_mat<<<dim3(24, 96, LL), blk, 0, stream>>>(W2, w2T, FFH, CC,
                                                   (size_t)FFH * CC, (size_t)CC * FFH);
    cvtT_mat<<<dim3(VPAD / 32, 24, 1), blk, 0, stream>>>(Wlm, lmT, CC, VV, 0, 0);

    embed_kernel<<<dim3((MROWS * CC + 255) / 256), blk, 0, stream>>>(x, tok, pos, h, hb);

    for (int l = 0; l < LL; l++) {
        const __hip_bfloat16* kT_l = kT + (size_t)l * CC * CC;
        const __hip_bfloat16* qT_l = qT + (size_t)l * CC * CC;
        const __hip_bfloat16* vT_l = vT + (size_t)l * CC * CC;
        const __hip_bfloat16* pT_l = pT + (size_t)l * CC * CC;
        const __hip_bfloat16* w1T_l = w1T + (size_t)l * CC * FFH;
        const __hip_bfloat16* w2T_l = w2T + (size_t)l * FFH * CC;

        gemm_qkv_mfma<<<dim3(CC / 128, MROWS / 128, 3), blk, 0, stream>>>(
            hb, kT_l, qT_l, vT_l, kbb, qbb, vtb);
        attn_mfma<<<dim3(TT / QBLK, HH, BB), blk, 0, stream>>>(kbb, qbb, vtb, ocb);
        gemm_mfma<<<dim3(CC / 128, MROWS / 128), blk, 0, stream>>>(
            ocb, pT_l, bproj + (size_t)l * CC, tmpf, (__hip_bfloat16*)nullptr,
            MROWS, CC, CC, 0);
        resid_ln<<<dim3(MROWS), blk, 0, stream>>>(h, tmpf, ln1g + (size_t)l * CC,
                                                  ln1b + (size_t)l * CC, hb);
        gemm_mfma<<<dim3(FFH / 128, MROWS / 128), blk, 0, stream>>>(
            hb, w1T_l, b1 + (size_t)l * FFH, (float*)nullptr, ff1b,
            MROWS, FFH, CC, 1);
        gemm_mfma<<<dim3(CC / 128, MROWS / 128), blk, 0, stream>>>(
            ff1b, w2T_l, b2 + (size_t)l * CC, tmpf, (__hip_bfloat16*)nullptr,
            MROWS, CC, FFH, 0);
        resid_ln<<<dim3(MROWS), blk, 0, stream>>>(h, tmpf, ln2g + (size_t)l * CC,
                                                  ln2b + (size_t)l * CC, hb);
    }

    lm_head_mfma<<<dim3(VPAD / 128, MROWS / 128), blk, 0, stream>>>(
        hb, lmT, blm, logits, pm, ps);
    nll_combine<<<dim3(MROWS), blk, 0, stream>>>(pm, ps, logits, y, rl);
    loss_reduce<<<dim3(1), blk, 0, stream>>>(rl, lossp);
}

// Round 7
// 4053.510 us; speedup vs baseline: 13.1827x; 1.0249x over previous
//
#include <hip/hip_runtime.h>
#include <hip/hip_bf16.h>
#include <math.h>

#define BB 4
#define TT 1024
#define VV 50257
#define VPAD2 50432               // multiple of 256 for the 256-wide LM head
#define CC 768
#define HH 12
#define DD 64
#define LL 12
#define FFH 3072
#define MROWS (BB*TT)   // 4096
#define QBLK 128
#define KVBLK 64
#define NPART (VPAD2 / 64)        // 788 partials per row (one per 64-col group)

typedef __bf16 bf16x8 __attribute__((ext_vector_type(8)));
typedef float  f32x4  __attribute__((ext_vector_type(4)));
typedef unsigned int u32;
#define AS1 __attribute__((address_space(1)))
#define AS3 __attribute__((address_space(3)))

static __device__ __forceinline__ void gload_lds16(const void* g, void* l) {
    __builtin_amdgcn_global_load_lds((const AS1 u32*)g, (AS3 u32*)l, 16, 0, 0);
}

// stage one 128x64 bf16 tile pair (A,B) into linear LDS, source pre-swizzled (4 waves)
static __device__ __forceinline__ void stage_tile(const __hip_bfloat16* __restrict__ A,
                                                  const __hip_bfloat16* __restrict__ Bt,
                                                  int Kld, int k0, int bm, int bn,
                                                  int w, int l,
                                                  __hip_bfloat16* As, __hip_bfloat16* Bs) {
    #pragma unroll
    for (int it = 0; it < 4; it++) {
        int chunk = w * 4 + it;
        int o = chunk * 1024 + l * 16;
        int row = o >> 7;
        int cb = (o & 127) ^ ((row & 7) << 4);
        gload_lds16(A + (size_t)(bm + row) * Kld + k0 + (cb >> 1), (char*)As + chunk * 1024);
        gload_lds16(Bt + (size_t)(bn + row) * Kld + k0 + (cb >> 1), (char*)Bs + chunk * 1024);
    }
}

// stage one 256x64 bf16 tile pair into linear LDS (8 waves / 512 threads)
static __device__ __forceinline__ void stage_tile256(const __hip_bfloat16* __restrict__ A,
                                                     const __hip_bfloat16* __restrict__ Bt,
                                                     int Kld, int k0, int bm, int bn,
                                                     int w, int l,
                                                     __hip_bfloat16* As, __hip_bfloat16* Bs) {
    #pragma unroll
    for (int it = 0; it < 4; it++) {
        int chunk = w * 4 + it;                 // 32 chunks of 1KB per tensor
        int o = chunk * 1024 + l * 16;
        int row = o >> 7;                       // 0..255
        int cb = (o & 127) ^ ((row & 7) << 4);
        gload_lds16(A + (size_t)(bm + row) * Kld + k0 + (cb >> 1), (char*)As + chunk * 1024);
        gload_lds16(Bt + (size_t)(bn + row) * Kld + k0 + (cb >> 1), (char*)Bs + chunk * 1024);
    }
}

// ---------------- embedding: h = tok_emb[x] + pos_emb[x]; also bf16 copy
__global__ void embed_kernel(const int* __restrict__ x, const float* __restrict__ tok,
                             const float* __restrict__ pos, float* __restrict__ h,
                             __hip_bfloat16* __restrict__ hb) {
    int idx = blockIdx.x * 256 + threadIdx.x;
    if (idx >= MROWS * CC) return;
    int row = idx / CC, c = idx - row * CC;
    int id = x[row];
    float v = tok[(size_t)id * CC + c] + pos[(size_t)id * CC + c];
    h[idx] = v;
    hb[idx] = __float2bfloat16(v);
}

// ---------------- convert + transpose: out[b][n][k] = (n<Nin ? in[b][k][n] : 0), bf16
__global__ __launch_bounds__(256) void cvtT_mat(const float* __restrict__ in,
                                                __hip_bfloat16* __restrict__ out,
                                                int K, int Nin,
                                                size_t ibs, size_t obs) {
    __shared__ float t[32][33];
    const float* ip = in + blockIdx.z * ibs;
    __hip_bfloat16* op = out + blockIdx.z * obs;
    int n0 = blockIdx.x * 32, k0 = blockIdx.y * 32;
    int tx = threadIdx.x & 31, ty = threadIdx.x >> 5;   // 32x8
    #pragma unroll
    for (int i = 0; i < 4; i++) {
        int k = k0 + ty + i * 8, n = n0 + tx;
        t[ty + i * 8][tx] = (n < Nin) ? ip[(size_t)k * Nin + n] : 0.f;
    }
    __syncthreads();
    #pragma unroll
    for (int i = 0; i < 4; i++) {
        int n = n0 + ty + i * 8, k = k0 + tx;
        op[(size_t)n * K + k] = __float2bfloat16(t[tx][ty + i * 8]);
    }
}

// ---------------- QKV weights (L,H,C,D) -> per-layer [768][768] bf16, row n=h*64+d, col c
__global__ __launch_bounds__(256) void cvtT_qkv(const float* __restrict__ Wk,
                                                const float* __restrict__ Wq,
                                                const float* __restrict__ Wv,
                                                __hip_bfloat16* __restrict__ kT,
                                                __hip_bfloat16* __restrict__ qT,
                                                __hip_bfloat16* __restrict__ vT) {
    int z = blockIdx.z;
    int tensor = z / 144, lh = z % 144;
    int l = lh / HH, hh = lh % HH;
    const float* in = (tensor == 0 ? Wk : tensor == 1 ? Wq : Wv) + (size_t)lh * CC * DD;
    __hip_bfloat16* out = (tensor == 0 ? kT : tensor == 1 ? qT : vT)
                          + ((size_t)l * CC + hh * DD) * CC;
    __shared__ float t[32][33];
    int c0 = blockIdx.x * 32, d0 = blockIdx.y * 32;
    int tx = threadIdx.x & 31, ty = threadIdx.x >> 5;
    #pragma unroll
    for (int i = 0; i < 4; i++)
        t[ty + i * 8][tx] = in[(size_t)(c0 + ty + i * 8) * DD + d0 + tx];
    __syncthreads();
    #pragma unroll
    for (int i = 0; i < 4; i++)
        out[(size_t)(d0 + ty + i * 8) * CC + c0 + tx] = __float2bfloat16(t[tx][ty + i * 8]);
}

// ---------------- MFMA GEMM, 128x128, double-buffered 2-phase
__global__ __launch_bounds__(256) void gemm_mfma(const __hip_bfloat16* __restrict__ A,
                                                 const __hip_bfloat16* __restrict__ Bt,
                                                 const float* __restrict__ bias,
                                                 float* __restrict__ Cf,
                                                 __hip_bfloat16* __restrict__ Cb,
                                                 int M, int N, int K, int relu) {
    __shared__ __hip_bfloat16 As[2][128 * 64];
    __shared__ __hip_bfloat16 Bs[2][128 * 64];
    int tid = threadIdx.x;
    int l = tid & 63, w = tid >> 6;
    int wr = w >> 1, wc = w & 1;
    int bm = blockIdx.y * 128, bn = blockIdx.x * 128;

    f32x4 acc[4][4] = {};

    stage_tile(A, Bt, K, 0, bm, bn, w, l, As[0], Bs[0]);
    int p = 0;
    for (int k0 = 0; k0 < K; k0 += 64) {
        __syncthreads();
        if (k0 + 64 < K)
            stage_tile(A, Bt, K, k0 + 64, bm, bn, w, l, As[p ^ 1], Bs[p ^ 1]);
        const char* Ab = (const char*)As[p];
        const char* Bb = (const char*)Bs[p];
        #pragma unroll
        for (int ks = 0; ks < 2; ks++) {
            bf16x8 af[4], bfr[4];
            #pragma unroll
            for (int i = 0; i < 4; i++) {
                int row = wr * 64 + i * 16 + (l & 15);
                int cb = (ks * 64 + (l >> 4) * 16) ^ ((row & 7) << 4);
                af[i] = *(const bf16x8*)(Ab + row * 128 + cb);
            }
            #pragma unroll
            for (int j = 0; j < 4; j++) {
                int row = wc * 64 + j * 16 + (l & 15);
                int cb = (ks * 64 + (l >> 4) * 16) ^ ((row & 7) << 4);
                bfr[j] = *(const bf16x8*)(Bb + row * 128 + cb);
            }
            #pragma unroll
            for (int i = 0; i < 4; i++)
                #pragma unroll
                for (int j = 0; j < 4; j++)
                    acc[i][j] = __builtin_amdgcn_mfma_f32_16x16x32_bf16(af[i], bfr[j], acc[i][j], 0, 0, 0);
        }
        p ^= 1;
    }
    #pragma unroll
    for (int i = 0; i < 4; i++) {
        int row = bm + wr * 64 + i * 16 + (l >> 4) * 4;
        #pragma unroll
        for (int j = 0; j < 4; j++) {
            int col = bn + wc * 64 + j * 16 + (l & 15);
            if (col < N) {
                float bv = bias ? bias[col] : 0.f;
                #pragma unroll
                for (int r = 0; r < 4; r++) {
                    float v = acc[i][j][r] + bv;
                    if (relu) v = fmaxf(v, 0.f);
                    if (Cf) Cf[(size_t)(row + r) * N + col] = v;
                    if (Cb) Cb[(size_t)(row + r) * N + col] = __float2bfloat16(v);
                }
            }
        }
    }
}

// ---------------- LM head: 256x256 tile, 512 threads (8 waves, 2Mx4N), dbuf 2-phase,
// row-fastest grid (x=row-block) so concurrent blocks reuse B panels in L2;
// fused LSE partials per (row, 64-col group).
__global__ __launch_bounds__(512) void lm_head_mfma256(const __hip_bfloat16* __restrict__ A,
                                                       const __hip_bfloat16* __restrict__ Bt,
                                                       const float* __restrict__ bias,
                                                       float* __restrict__ Cf,
                                                       float* __restrict__ pm,
                                                       float* __restrict__ ps) {
    __shared__ __hip_bfloat16 As[2][256 * 64];
    __shared__ __hip_bfloat16 Bs[2][256 * 64];
    int tid = threadIdx.x;
    int l = tid & 63, w = tid >> 6;          // 8 waves
    int wr = w >> 2, wc = w & 3;             // 2 x 4 wave grid
    int bm = blockIdx.x * 256, bn = blockIdx.y * 256;   // row-fastest

    f32x4 acc[8][4] = {};

    stage_tile256(A, Bt, CC, 0, bm, bn, w, l, As[0], Bs[0]);
    int p = 0;
    for (int k0 = 0; k0 < CC; k0 += 64) {
        __syncthreads();
        if (k0 + 64 < CC)
            stage_tile256(A, Bt, CC, k0 + 64, bm, bn, w, l, As[p ^ 1], Bs[p ^ 1]);
        const char* Ab = (const char*)As[p];
        const char* Bb = (const char*)Bs[p];
        #pragma unroll
        for (int ks = 0; ks < 2; ks++) {
            bf16x8 af[8], bfr[4];
            #pragma unroll
            for (int i = 0; i < 8; i++) {
                int row = wr * 128 + i * 16 + (l & 15);
                int cb = (ks * 64 + (l >> 4) * 16) ^ ((row & 7) << 4);
                af[i] = *(const bf16x8*)(Ab + row * 128 + cb);
            }
            #pragma unroll
            for (int j = 0; j < 4; j++) {
                int row = wc * 64 + j * 16 + (l & 15);
                int cb = (ks * 64 + (l >> 4) * 16) ^ ((row & 7) << 4);
                bfr[j] = *(const bf16x8*)(Bb + row * 128 + cb);
            }
            #pragma unroll
            for (int i = 0; i < 8; i++)
                #pragma unroll
                for (int j = 0; j < 4; j++)
                    acc[i][j] = __builtin_amdgcn_mfma_f32_16x16x32_bf16(af[i], bfr[j], acc[i][j], 0, 0, 0);
        }
        p ^= 1;
    }
    int pidx = blockIdx.y * 4 + wc;
    #pragma unroll
    for (int i = 0; i < 8; i++) {
        int row = bm + wr * 128 + i * 16 + (l >> 4) * 4;
        #pragma unroll
        for (int r = 0; r < 4; r++) {
            float pv[4];
            float rmax = -1e30f;
            #pragma unroll
            for (int j = 0; j < 4; j++) {
                int col = bn + wc * 64 + j * 16 + (l & 15);
                float v = -1e30f;
                if (col < VV) {
                    v = acc[i][j][r] + bias[col];
                    Cf[(size_t)(row + r) * VV + col] = v;
                }
                pv[j] = v;
                rmax = fmaxf(rmax, v);
            }
            #pragma unroll
            for (int msk = 1; msk < 16; msk <<= 1)
                rmax = fmaxf(rmax, __shfl_xor(rmax, msk));
            float s = 0.f;
            #pragma unroll
            for (int j = 0; j < 4; j++) s += __expf(pv[j] - rmax);
            #pragma unroll
            for (int msk = 1; msk < 16; msk <<= 1)
                s += __shfl_xor(s, msk);
            if ((l & 15) == 0) {
                pm[(size_t)(row + r) * NPART + pidx] = rmax;
                ps[(size_t)(row + r) * NPART + pidx] = s;
            }
        }
    }
}

// ---------------- combine LSE partials -> per-row NLL
__global__ __launch_bounds__(256) void nll_combine(const float* __restrict__ pm,
                                                   const float* __restrict__ ps,
                                                   const float* __restrict__ logits,
                                                   const int* __restrict__ y,
                                                   float* __restrict__ rl) {
    int m = blockIdx.x, tid = threadIdx.x;
    __shared__ float rm[256], rs[256];
    float mt = -1e30f, st = 0.f;
    for (int i = tid; i < NPART; i += 256) {
        float mi = pm[(size_t)m * NPART + i];
        float si = ps[(size_t)m * NPART + i];
        float mn = fmaxf(mt, mi);
        st = st * __expf(mt - mn) + si * __expf(mi - mn);
        mt = mn;
    }
    rm[tid] = mt; rs[tid] = st; __syncthreads();
    for (int off = 128; off > 0; off >>= 1) {
        if (tid < off) {
            float ma = rm[tid], mb = rm[tid + off];
            float mn = fmaxf(ma, mb);
            rs[tid] = rs[tid] * __expf(ma - mn) + rs[tid + off] * __expf(mb - mn);
            rm[tid] = mn;
        }
        __syncthreads();
    }
    if (tid == 0)
        rl[m] = logf(rs[0]) + rm[0] - logits[(size_t)m * VV + y[m]];
}

// ---------------- QKV MFMA GEMM (dbuf): k,q -> bf16 [B,H,T,D]; v -> bf16 [B,H,D,T]
__global__ __launch_bounds__(256) void gemm_qkv_mfma(const __hip_bfloat16* __restrict__ A,
                                                     const __hip_bfloat16* __restrict__ kT,
                                                     const __hip_bfloat16* __restrict__ qT,
                                                     const __hip_bfloat16* __restrict__ vT,
                                                     __hip_bfloat16* __restrict__ ko,
                                                     __hip_bfloat16* __restrict__ qo,
                                                     __hip_bfloat16* __restrict__ vto) {
    const __hip_bfloat16* Bt = (blockIdx.z == 0) ? kT : (blockIdx.z == 1) ? qT : vT;
    __shared__ __hip_bfloat16 As[2][128 * 64];
    __shared__ __hip_bfloat16 Bs[2][128 * 64];
    int tid = threadIdx.x;
    int l = tid & 63, w = tid >> 6;
    int wr = w >> 1, wc = w & 1;
    int bm = blockIdx.y * 128, bn = blockIdx.x * 128;

    f32x4 acc[4][4] = {};

    stage_tile(A, Bt, CC, 0, bm, bn, w, l, As[0], Bs[0]);
    int p = 0;
    for (int k0 = 0; k0 < CC; k0 += 64) {
        __syncthreads();
        if (k0 + 64 < CC)
            stage_tile(A, Bt, CC, k0 + 64, bm, bn, w, l, As[p ^ 1], Bs[p ^ 1]);
        const char* Ab = (const char*)As[p];
        const char* Bb = (const char*)Bs[p];
        #pragma unroll
        for (int ks = 0; ks < 2; ks++) {
            bf16x8 af[4], bfr[4];
            #pragma unroll
            for (int i = 0; i < 4; i++) {
                int row = wr * 64 + i * 16 + (l & 15);
                int cb = (ks * 64 + (l >> 4) * 16) ^ ((row & 7) << 4);
                af[i] = *(const bf16x8*)(Ab + row * 128 + cb);
            }
            #pragma unroll
            for (int j = 0; j < 4; j++) {
                int row = wc * 64 + j * 16 + (l & 15);
                int cb = (ks * 64 + (l >> 4) * 16) ^ ((row & 7) << 4);
                bfr[j] = *(const bf16x8*)(Bb + row * 128 + cb);
            }
            #pragma unroll
            for (int i = 0; i < 4; i++)
                #pragma unroll
                for (int j = 0; j < 4; j++)
                    acc[i][j] = __builtin_amdgcn_mfma_f32_16x16x32_bf16(af[i], bfr[j], acc[i][j], 0, 0, 0);
        }
        p ^= 1;
    }
    int zz = blockIdx.z;
    #pragma unroll
    for (int i = 0; i < 4; i++) {
        int row = bm + wr * 64 + i * 16 + (l >> 4) * 4;
        #pragma unroll
        for (int j = 0; j < 4; j++) {
            int col = bn + wc * 64 + j * 16 + (l & 15);
            int head = col >> 6, d = col & 63;
            #pragma unroll
            for (int r = 0; r < 4; r++) {
                int m = row + r;
                int b = m >> 10, t = m & 1023;
                __hip_bfloat16 val = __float2bfloat16(acc[i][j][r]);
                if (zz == 0)      ko[(((size_t)(b * HH + head)) * TT + t) * DD + d] = val;
                else if (zz == 1) qo[(((size_t)(b * HH + head)) * TT + t) * DD + d] = val;
                else              vto[(((size_t)(b * HH + head)) * DD + d) * TT + t] = val;
            }
        }
    }
}

// ---------------- MFMA flash attention (quirk: k plays query role)
__global__ __launch_bounds__(256) void attn_mfma(const __hip_bfloat16* __restrict__ kq,
                                                 const __hip_bfloat16* __restrict__ qk,
                                                 const __hip_bfloat16* __restrict__ vt,
                                                 __hip_bfloat16* __restrict__ oc) {
    __shared__ __hip_bfloat16 Qs[2][KVBLK * 64];
    __shared__ __hip_bfloat16 Vs[2][64 * KVBLK];
    __shared__ __hip_bfloat16 Ps[QBLK * KVBLK];
    int tid = threadIdx.x;
    int l = tid & 63, w = tid >> 6;
    int t0 = blockIdx.x * QBLK;
    size_t bh = (size_t)(blockIdx.z * HH + blockIdx.y);
    const __hip_bfloat16* kqp = kq + bh * TT * DD;
    const __hip_bfloat16* qkp = qk + bh * TT * DD;
    const __hip_bfloat16* vtp = vt + bh * DD * TT;

    bf16x8 af[2][2];
    #pragma unroll
    for (int i = 0; i < 2; i++)
        #pragma unroll
        for (int ks = 0; ks < 2; ks++)
            af[i][ks] = *(const bf16x8*)&kqp[(size_t)(t0 + w * 32 + i * 16 + (l & 15)) * DD
                                             + ks * 32 + (l >> 4) * 8];

    f32x4 acc_o[2][4] = {};
    float mrow[2][4], lrow[2][4];
    #pragma unroll
    for (int i = 0; i < 2; i++)
        #pragma unroll
        for (int r = 0; r < 4; r++) { mrow[i][r] = -1e30f; lrow[i][r] = 0.f; }

    auto stageKV = [&](int pp, int s0) {
        #pragma unroll
        for (int it = 0; it < 2; it++) {
            int chunk = w * 2 + it;
            int o = chunk * 1024 + l * 16;
            int row = o >> 7;
            int cb = (o & 127) ^ ((row & 7) << 4);
            gload_lds16(qkp + (size_t)(s0 + row) * DD + (cb >> 1),
                        (char*)Qs[pp] + chunk * 1024);
            gload_lds16(vtp + (size_t)row * TT + s0 + (cb >> 1),
                        (char*)Vs[pp] + chunk * 1024);
        }
    };

    int nt = (t0 + QBLK) / KVBLK;
    stageKV(0, 0);
    int p = 0;
    for (int ti = 0; ti < nt; ti++) {
        int s0 = ti * KVBLK;
        __syncthreads();
        if (ti + 1 < nt) stageKV(p ^ 1, s0 + KVBLK);

        f32x4 sa[2][4] = {};
        #pragma unroll
        for (int ks = 0; ks < 2; ks++) {
            bf16x8 bfr[4];
            #pragma unroll
            for (int j = 0; j < 4; j++) {
                int row = j * 16 + (l & 15);
                int cb = (ks * 64 + (l >> 4) * 16) ^ ((row & 7) << 4);
                bfr[j] = *(const bf16x8*)((const char*)Qs[p] + row * 128 + cb);
            }
            #pragma unroll
            for (int i = 0; i < 2; i++)
                #pragma unroll
                for (int j = 0; j < 4; j++)
                    sa[i][j] = __builtin_amdgcn_mfma_f32_16x16x32_bf16(af[i][ks], bfr[j], sa[i][j], 0, 0, 0);
        }

        #pragma unroll
        for (int i = 0; i < 2; i++) {
            #pragma unroll
            for (int r = 0; r < 4; r++) {
                int t = t0 + w * 32 + i * 16 + (l >> 4) * 4 + r;
                float pv[4];
                float rmax = -1e30f;
                #pragma unroll
                for (int j = 0; j < 4; j++) {
                    int s = s0 + j * 16 + (l & 15);
                    float v = sa[i][j][r] * 0.125f;
                    v = (s <= t) ? v : -1e30f;
                    pv[j] = v;
                    rmax = fmaxf(rmax, v);
                }
                #pragma unroll
                for (int msk = 1; msk < 16; msk <<= 1)
                    rmax = fmaxf(rmax, __shfl_xor(rmax, msk));
                float mo = mrow[i][r];
                float mn = fmaxf(mo, rmax);
                float fac = __expf(mo - mn);
                float ls = 0.f;
                int prow = w * 32 + i * 16 + (l >> 4) * 4 + r;
                #pragma unroll
                for (int j = 0; j < 4; j++) {
                    float e = __expf(pv[j] - mn);
                    ls += e;
                    int cb = (j * 32 + (l & 15) * 2) ^ ((prow & 7) << 4);
                    *(__hip_bfloat16*)((char*)Ps + prow * 128 + cb) = __float2bfloat16(e);
                }
                #pragma unroll
                for (int msk = 1; msk < 16; msk <<= 1)
                    ls += __shfl_xor(ls, msk);
                mrow[i][r] = mn;
                lrow[i][r] = lrow[i][r] * fac + ls;
                #pragma unroll
                for (int jd = 0; jd < 4; jd++)
                    acc_o[i][jd][r] *= fac;
            }
        }

        #pragma unroll
        for (int ks = 0; ks < 2; ks++) {
            bf16x8 pa[2], vf[4];
            #pragma unroll
            for (int i = 0; i < 2; i++) {
                int row = w * 32 + i * 16 + (l & 15);
                int cb = (ks * 64 + (l >> 4) * 16) ^ ((row & 7) << 4);
                pa[i] = *(const bf16x8*)((const char*)Ps + row * 128 + cb);
            }
            #pragma unroll
            for (int jd = 0; jd < 4; jd++) {
                int row = jd * 16 + (l & 15);
                int cb = (ks * 64 + (l >> 4) * 16) ^ ((row & 7) << 4);
                vf[jd] = *(const bf16x8*)((const char*)Vs[p] + row * 128 + cb);
            }
            #pragma unroll
            for (int i = 0; i < 2; i++)
                #pragma unroll
                for (int jd = 0; jd < 4; jd++)
                    acc_o[i][jd] = __builtin_amdgcn_mfma_f32_16x16x32_bf16(pa[i], vf[jd], acc_o[i][jd], 0, 0, 0);
        }
        p ^= 1;
    }

    int b = blockIdx.z, hh = blockIdx.y;
    #pragma unroll
    for (int i = 0; i < 2; i++) {
        #pragma unroll
        for (int r = 0; r < 4; r++) {
            float inv = 1.f / lrow[i][r];
            int t = t0 + w * 32 + i * 16 + (l >> 4) * 4 + r;
            #pragma unroll
            for (int jd = 0; jd < 4; jd++) {
                int d = jd * 16 + (l & 15);
                oc[((size_t)(b * TT + t)) * CC + hh * DD + d] =
                    __float2bfloat16(acc_o[i][jd][r] * inv);
            }
        }
    }
}

// ---------------- h = LN(h + t); writes f32 h and bf16 hb
__global__ __launch_bounds__(256) void resid_ln(float* __restrict__ h,
                                                const float* __restrict__ t,
                                                const float* __restrict__ g,
                                                const float* __restrict__ bta,
                                                __hip_bfloat16* __restrict__ hb) {
    int row = blockIdx.x;
    int tid = threadIdx.x;
    __shared__ float red[256];
    float x[3];
    float s = 0.f;
    #pragma unroll
    for (int i = 0; i < 3; i++) {
        int c = tid + i * 256;
        x[i] = h[(size_t)row * CC + c] + t[(size_t)row * CC + c];
        s += x[i];
    }
    red[tid] = s; __syncthreads();
    for (int off = 128; off > 0; off >>= 1) {
        if (tid < off) red[tid] += red[tid + off];
        __syncthreads();
    }
    float mean = red[0] * (1.f / CC); __syncthreads();
    float s2 = 0.f;
    #pragma unroll
    for (int i = 0; i < 3; i++) { float dd = x[i] - mean; s2 += dd * dd; }
    red[tid] = s2; __syncthreads();
    for (int off = 128; off > 0; off >>= 1) {
        if (tid < off) red[tid] += red[tid + off];
        __syncthreads();
    }
    float inv = rsqrtf(red[0] * (1.f / CC) + 1e-5f);
    #pragma unroll
    for (int i = 0; i < 3; i++) {
        int c = tid + i * 256;
        float o = (x[i] - mean) * inv * g[c] + bta[c];
        h[(size_t)row * CC + c] = o;
        hb[(size_t)row * CC + c] = __float2bfloat16(o);
    }
}

__global__ __launch_bounds__(256) void loss_reduce(const float* __restrict__ rl,
                                                   float* __restrict__ out) {
    int tid = threadIdx.x;
    __shared__ float red[256];
    float s = 0.f;
    for (int i = tid; i < MROWS; i += 256) s += rl[i];
    red[tid] = s; __syncthreads();
    for (int off = 128; off > 0; off >>= 1) {
        if (tid < off) red[tid] += red[tid + off];
        __syncthreads();
    }
    if (tid == 0) out[0] = red[0] * (1.f / MROWS);
}

extern "C" void kernel_launch(void* const* d_in, const int* in_sizes, int n_in,
                              void* d_out, int out_size, void* d_ws, size_t ws_size,
                              hipStream_t stream) {
    const int*   x     = (const int*)d_in[0];
    const int*   y     = (const int*)d_in[1];
    const float* tok   = (const float*)d_in[2];
    const float* pos   = (const float*)d_in[3];
    const float* Wk    = (const float*)d_in[4];
    const float* Wq    = (const float*)d_in[5];
    const float* Wv    = (const float*)d_in[6];
    const float* Wproj = (const float*)d_in[7];
    const float* bproj = (const float*)d_in[8];
    const float* ln1g  = (const float*)d_in[9];
    const float* ln1b  = (const float*)d_in[10];
    const float* W1    = (const float*)d_in[11];
    const float* b1    = (const float*)d_in[12];
    const float* W2    = (const float*)d_in[13];
    const float* b2    = (const float*)d_in[14];
    const float* ln2g  = (const float*)d_in[15];
    const float* ln2b  = (const float*)d_in[16];
    const float* Wlm   = (const float*)d_in[17];
    const float* blm   = (const float*)d_in[18];

    float* logits = (float*)d_out;
    float* lossp  = (float*)d_out + ((size_t)out_size - 1);

    char* p = (char*)d_ws;
    auto alloc = [&](size_t bytes) { char* r = p; p += (bytes + 255) & ~255ULL; return r; };
    const size_t S_HC = (size_t)MROWS * CC;

    float* h    = (float*)alloc(S_HC * 4);
    float* tmpf = (float*)alloc(S_HC * 4);
    float* rl   = (float*)alloc(MROWS * 4);
    float* pm   = (float*)alloc((size_t)MROWS * NPART * 4);
    float* ps   = (float*)alloc((size_t)MROWS * NPART * 4);
    __hip_bfloat16* kbb  = (__hip_bfloat16*)alloc(S_HC * 2);
    __hip_bfloat16* qbb  = (__hip_bfloat16*)alloc(S_HC * 2);
    __hip_bfloat16* vtb  = (__hip_bfloat16*)alloc(S_HC * 2);
    __hip_bfloat16* hb   = (__hip_bfloat16*)alloc(S_HC * 2);
    __hip_bfloat16* ocb  = (__hip_bfloat16*)alloc(S_HC * 2);
    __hip_bfloat16* ff1b = (__hip_bfloat16*)alloc((size_t)MROWS * FFH * 2);
    __hip_bfloat16* kT   = (__hip_bfloat16*)alloc((size_t)LL * CC * CC * 2);
    __hip_bfloat16* qT   = (__hip_bfloat16*)alloc((size_t)LL * CC * CC * 2);
    __hip_bfloat16* vT   = (__hip_bfloat16*)alloc((size_t)LL * CC * CC * 2);
    __hip_bfloat16* pT   = (__hip_bfloat16*)alloc((size_t)LL * CC * CC * 2);
    __hip_bfloat16* w1T  = (__hip_bfloat16*)alloc((size_t)LL * CC * FFH * 2);
    __hip_bfloat16* w2T  = (__hip_bfloat16*)alloc((size_t)LL * FFH * CC * 2);
    __hip_bfloat16* lmT  = (__hip_bfloat16*)alloc((size_t)VPAD2 * CC * 2);

    dim3 blk(256);

    cvtT_qkv<<<dim3(24, 2, 3 * 144), blk, 0, stream>>>(Wk, Wq, Wv, kT, qT, vT);
    cvtT_mat<<<dim3(24, 24, LL), blk, 0, stream>>>(Wproj, pT, CC, CC,
                                                   (size_t)CC * CC, (size_t)CC * CC);
    cvtT_mat<<<dim3(96, 24, LL), blk, 0, stream>>>(W1, w1T, CC, FFH,
                                                   (size_t)CC * FFH, (size_t)FFH * CC);
    cvtT_mat<<<dim3(24, 96, LL), blk, 0, stream>>>(W2, w2T, FFH, CC,
                                                   (size_t)FFH * CC, (size_t)CC * FFH);
    cvtT_mat<<<dim3(VPAD2 / 32, 24, 1), blk, 0, stream>>>(Wlm, lmT, CC, VV, 0, 0);

    embed_kernel<<<dim3((MROWS * CC + 255) / 256), blk, 0, stream>>>(x, tok, pos, h, hb);

    for (int l = 0; l < LL; l++) {
        const __hip_bfloat16* kT_l = kT + (size_t)l * CC * CC;
        const __hip_bfloat16* qT_l = qT + (size_t)l * CC * CC;
        const __hip_bfloat16* vT_l = vT + (size_t)l * CC * CC;
        const __hip_bfloat16* pT_l = pT + (size_t)l * CC * CC;
        const __hip_bfloat16* w1T_l = w1T + (size_t)l * CC * FFH;
        const __hip_bfloat16* w2T_l = w2T + (size_t)l * FFH * CC;

        gemm_qkv_mfma<<<dim3(CC / 128, MROWS / 128, 3), blk, 0, stream>>>(
            hb, kT_l, qT_l, vT_l, kbb, qbb, vtb);
        attn_mfma<<<dim3(TT / QBLK, HH, BB), blk, 0, stream>>>(kbb, qbb, vtb, ocb);
        gemm_mfma<<<dim3(CC / 128, MROWS / 128), blk, 0, stream>>>(
            ocb, pT_l, bproj + (size_t)l * CC, tmpf, (__hip_bfloat16*)nullptr,
            MROWS, CC, CC, 0);
        resid_ln<<<dim3(MROWS), blk, 0, stream>>>(h, tmpf, ln1g + (size_t)l * CC,
                                                  ln1b + (size_t)l * CC, hb);
        gemm_mfma<<<dim3(FFH / 128, MROWS / 128), blk, 0, stream>>>(
            hb, w1T_l, b1 + (size_t)l * FFH, (float*)nullptr, ff1b,
            MROWS, FFH, CC, 1);
        gemm_mfma<<<dim3(CC / 128, MROWS / 128), blk, 0, stream>>>(
            ff1b, w2T_l, b2 + (size_t)l * CC, tmpf, (__hip_bfloat16*)nullptr,
            MROWS, CC, FFH, 0);
        resid_ln<<<dim3(MROWS), blk, 0, stream>>>(h, tmpf, ln2g + (size_t)l * CC,
                                                  ln2b + (size_t)l * CC, hb);
    }

    // LM head: 256x256 tile, row-fastest grid
    lm_head_mfma256<<<dim3(MROWS / 256, VPAD2 / 256), dim3(512), 0, stream>>>(
        hb, lmT, blm, logits, pm, ps);
    nll_combine<<<dim3(MROWS), blk, 0, stream>>>(pm, ps, logits, y, rl);
    loss_reduce<<<dim3(1), blk, 0, stream>>>(rl, lossp);
}

// Round 8
// 3393.998 us; speedup vs baseline: 15.7443x; 1.1943x over previous
//
#include <hip/hip_runtime.h>
#include <hip/hip_bf16.h>
#include <math.h>

#define BB 4
#define TT 1024
#define VV 50257
#define VPAD2 50432               // multiple of 256 for the 256-wide LM head
#define CC 768
#define HH 12
#define DD 64
#define LL 12
#define FFH 3072
#define MROWS (BB*TT)   // 4096
#define QBLK 128
#define KVBLK 64
#define NPART (VPAD2 / 64)        // 788 partials per row

typedef __bf16 bf16x8 __attribute__((ext_vector_type(8)));
typedef float  f32x4  __attribute__((ext_vector_type(4)));
typedef unsigned int u32;
#define AS1 __attribute__((address_space(1)))
#define AS3 __attribute__((address_space(3)))

static __device__ __forceinline__ void gload_lds16(const void* g, void* l) {
    __builtin_amdgcn_global_load_lds((const AS1 u32*)g, (AS3 u32*)l, 16, 0, 0);
}

// stage one 128x64 bf16 tile pair into linear LDS, source pre-swizzled (4 waves)
static __device__ __forceinline__ void stage_tile(const __hip_bfloat16* __restrict__ A,
                                                  const __hip_bfloat16* __restrict__ Bt,
                                                  int Kld, int k0, int bm, int bn,
                                                  int w, int l, char* As, char* Bs) {
    #pragma unroll
    for (int it = 0; it < 4; it++) {
        int chunk = w * 4 + it;
        int o = chunk * 1024 + l * 16;
        int row = o >> 7;
        int cb = (o & 127) ^ ((row & 7) << 4);
        gload_lds16(A + (size_t)(bm + row) * Kld + k0 + (cb >> 1), As + chunk * 1024);
        gload_lds16(Bt + (size_t)(bn + row) * Kld + k0 + (cb >> 1), Bs + chunk * 1024);
    }
}

// stage one 256x64 bf16 tile pair into linear LDS (8 waves / 512 threads)
static __device__ __forceinline__ void stage_tile256(const __hip_bfloat16* __restrict__ A,
                                                     const __hip_bfloat16* __restrict__ Bt,
                                                     int Kld, int k0, int bm, int bn,
                                                     int w, int l, char* As, char* Bs) {
    #pragma unroll
    for (int it = 0; it < 4; it++) {
        int chunk = w * 4 + it;
        int o = chunk * 1024 + l * 16;
        int row = o >> 7;
        int cb = (o & 127) ^ ((row & 7) << 4);
        gload_lds16(A + (size_t)(bm + row) * Kld + k0 + (cb >> 1), As + chunk * 1024);
        gload_lds16(Bt + (size_t)(bn + row) * Kld + k0 + (cb >> 1), Bs + chunk * 1024);
    }
}

// ---------------- embedding
__global__ void embed_kernel(const int* __restrict__ x, const float* __restrict__ tok,
                             const float* __restrict__ pos, float* __restrict__ h,
                             __hip_bfloat16* __restrict__ hb) {
    int idx = blockIdx.x * 256 + threadIdx.x;
    if (idx >= MROWS * CC) return;
    int row = idx / CC, c = idx - row * CC;
    int id = x[row];
    float v = tok[(size_t)id * CC + c] + pos[(size_t)id * CC + c];
    h[idx] = v;
    hb[idx] = __float2bfloat16(v);
}

// ---------------- convert + transpose weights
__global__ __launch_bounds__(256) void cvtT_mat(const float* __restrict__ in,
                                                __hip_bfloat16* __restrict__ out,
                                                int K, int Nin,
                                                size_t ibs, size_t obs) {
    __shared__ float t[32][33];
    const float* ip = in + blockIdx.z * ibs;
    __hip_bfloat16* op = out + blockIdx.z * obs;
    int n0 = blockIdx.x * 32, k0 = blockIdx.y * 32;
    int tx = threadIdx.x & 31, ty = threadIdx.x >> 5;
    #pragma unroll
    for (int i = 0; i < 4; i++) {
        int k = k0 + ty + i * 8, n = n0 + tx;
        t[ty + i * 8][tx] = (n < Nin) ? ip[(size_t)k * Nin + n] : 0.f;
    }
    __syncthreads();
    #pragma unroll
    for (int i = 0; i < 4; i++) {
        int n = n0 + ty + i * 8, k = k0 + tx;
        op[(size_t)n * K + k] = __float2bfloat16(t[tx][ty + i * 8]);
    }
}

__global__ __launch_bounds__(256) void cvtT_qkv(const float* __restrict__ Wk,
                                                const float* __restrict__ Wq,
                                                const float* __restrict__ Wv,
                                                __hip_bfloat16* __restrict__ kT,
                                                __hip_bfloat16* __restrict__ qT,
                                                __hip_bfloat16* __restrict__ vT) {
    int z = blockIdx.z;
    int tensor = z / 144, lh = z % 144;
    int l = lh / HH, hh = lh % HH;
    const float* in = (tensor == 0 ? Wk : tensor == 1 ? Wq : Wv) + (size_t)lh * CC * DD;
    __hip_bfloat16* out = (tensor == 0 ? kT : tensor == 1 ? qT : vT)
                          + ((size_t)l * CC + hh * DD) * CC;
    __shared__ float t[32][33];
    int c0 = blockIdx.x * 32, d0 = blockIdx.y * 32;
    int tx = threadIdx.x & 31, ty = threadIdx.x >> 5;
    #pragma unroll
    for (int i = 0; i < 4; i++)
        t[ty + i * 8][tx] = in[(size_t)(c0 + ty + i * 8) * DD + d0 + tx];
    __syncthreads();
    #pragma unroll
    for (int i = 0; i < 4; i++)
        out[(size_t)(d0 + ty + i * 8) * CC + c0 + tx] = __float2bfloat16(t[tx][ty + i * 8]);
}

// ---------------- MFMA GEMM 128x128 dbuf + LDS-staged coalesced epilogue.
// Writes EITHER Cf (f32) OR Cb (bf16). N must be a multiple of 128.
__global__ __launch_bounds__(256) void gemm_mfma(const __hip_bfloat16* __restrict__ A,
                                                 const __hip_bfloat16* __restrict__ Bt,
                                                 const float* __restrict__ bias,
                                                 float* __restrict__ Cf,
                                                 __hip_bfloat16* __restrict__ Cb,
                                                 int M, int N, int K, int relu) {
    __shared__ __align__(16) char smem[65536];   // As[2](32K) + Bs[2](32K); reused by epilogue
    int tid = threadIdx.x;
    int l = tid & 63, w = tid >> 6;
    int wr = w >> 1, wc = w & 1;
    int bm = blockIdx.y * 128, bn = blockIdx.x * 128;

    f32x4 acc[4][4] = {};

    stage_tile(A, Bt, K, 0, bm, bn, w, l, smem, smem + 32768);
    int p = 0;
    for (int k0 = 0; k0 < K; k0 += 64) {
        __syncthreads();
        if (k0 + 64 < K)
            stage_tile(A, Bt, K, k0 + 64, bm, bn, w, l,
                       smem + (p ^ 1) * 16384, smem + 32768 + (p ^ 1) * 16384);
        const char* Ab = smem + p * 16384;
        const char* Bb = smem + 32768 + p * 16384;
        #pragma unroll
        for (int ks = 0; ks < 2; ks++) {
            bf16x8 af[4], bfr[4];
            #pragma unroll
            for (int i = 0; i < 4; i++) {
                int row = wr * 64 + i * 16 + (l & 15);
                int cb = (ks * 64 + (l >> 4) * 16) ^ ((row & 7) << 4);
                af[i] = *(const bf16x8*)(Ab + row * 128 + cb);
            }
            #pragma unroll
            for (int j = 0; j < 4; j++) {
                int row = wc * 64 + j * 16 + (l & 15);
                int cb = (ks * 64 + (l >> 4) * 16) ^ ((row & 7) << 4);
                bfr[j] = *(const bf16x8*)(Bb + row * 128 + cb);
            }
            #pragma unroll
            for (int i = 0; i < 4; i++)
                #pragma unroll
                for (int j = 0; j < 4; j++)
                    acc[i][j] = __builtin_amdgcn_mfma_f32_16x16x32_bf16(af[i], bfr[j], acc[i][j], 0, 0, 0);
        }
        p ^= 1;
    }

    if (Cb) {
        // whole 128x128 bf16 tile staged (stride 136), then 16B coalesced stores
        __hip_bfloat16* ebh = (__hip_bfloat16*)smem;
        __syncthreads();
        #pragma unroll
        for (int i = 0; i < 4; i++) {
            #pragma unroll
            for (int j = 0; j < 4; j++) {
                int colt = wc * 64 + j * 16 + (l & 15);
                float bv = bias ? bias[bn + colt] : 0.f;
                #pragma unroll
                for (int r = 0; r < 4; r++) {
                    int rowc = wr * 64 + i * 16 + (l >> 4) * 4 + r;
                    float v = acc[i][j][r] + bv;
                    if (relu) v = fmaxf(v, 0.f);
                    ebh[rowc * 136 + colt] = __float2bfloat16(v);
                }
            }
        }
        __syncthreads();
        #pragma unroll
        for (int pass = 0; pass < 8; pass++) {
            int idx = pass * 256 + tid;
            int rowc = idx >> 4, colq = idx & 15;
            *(bf16x8*)&Cb[(size_t)(bm + rowc) * N + bn + colq * 8] =
                *(const bf16x8*)&ebh[rowc * 136 + colq * 8];
        }
    } else {
        // two 64-row f32 chunks (stride 132), then 16B coalesced stores
        float* eb = (float*)smem;
        #pragma unroll
        for (int c = 0; c < 2; c++) {
            __syncthreads();
            if (wr == c) {
                #pragma unroll
                for (int i = 0; i < 4; i++) {
                    #pragma unroll
                    for (int j = 0; j < 4; j++) {
                        int colt = wc * 64 + j * 16 + (l & 15);
                        float bv = bias ? bias[bn + colt] : 0.f;
                        #pragma unroll
                        for (int r = 0; r < 4; r++) {
                            int rowc = i * 16 + (l >> 4) * 4 + r;
                            float v = acc[i][j][r] + bv;
                            if (relu) v = fmaxf(v, 0.f);
                            eb[rowc * 132 + colt] = v;
                        }
                    }
                }
            }
            __syncthreads();
            #pragma unroll
            for (int pass = 0; pass < 8; pass++) {
                int idx = pass * 256 + tid;
                int rowc = idx >> 5, colq = idx & 31;
                *(f32x4*)&Cf[(size_t)(bm + c * 64 + rowc) * N + bn + colq * 4] =
                    *(const f32x4*)&eb[rowc * 132 + colq * 4];
            }
        }
    }
}

// ---------------- LM head: 256x256, 8 waves, dbuf, fused LSE + staged coalesced stores
__global__ __launch_bounds__(512) void lm_head_mfma256(const __hip_bfloat16* __restrict__ A,
                                                       const __hip_bfloat16* __restrict__ Bt,
                                                       const float* __restrict__ bias,
                                                       float* __restrict__ Cf,
                                                       float* __restrict__ pm,
                                                       float* __restrict__ ps) {
    __shared__ __align__(16) char smem[131072];  // As[2](64K)+Bs[2](64K); epilogue reuses
    int tid = threadIdx.x;
    int l = tid & 63, w = tid >> 6;
    int wr = w >> 2, wc = w & 3;
    int bm = blockIdx.x * 256, bn = blockIdx.y * 256;   // row-fastest

    f32x4 acc[8][4] = {};

    stage_tile256(A, Bt, CC, 0, bm, bn, w, l, smem, smem + 65536);
    int p = 0;
    for (int k0 = 0; k0 < CC; k0 += 64) {
        __syncthreads();
        if (k0 + 64 < CC)
            stage_tile256(A, Bt, CC, k0 + 64, bm, bn, w, l,
                          smem + (p ^ 1) * 32768, smem + 65536 + (p ^ 1) * 32768);
        const char* Ab = smem + p * 32768;
        const char* Bb = smem + 65536 + p * 32768;
        #pragma unroll
        for (int ks = 0; ks < 2; ks++) {
            bf16x8 af[8], bfr[4];
            #pragma unroll
            for (int i = 0; i < 8; i++) {
                int row = wr * 128 + i * 16 + (l & 15);
                int cb = (ks * 64 + (l >> 4) * 16) ^ ((row & 7) << 4);
                af[i] = *(const bf16x8*)(Ab + row * 128 + cb);
            }
            #pragma unroll
            for (int j = 0; j < 4; j++) {
                int row = wc * 64 + j * 16 + (l & 15);
                int cb = (ks * 64 + (l >> 4) * 16) ^ ((row & 7) << 4);
                bfr[j] = *(const bf16x8*)(Bb + row * 128 + cb);
            }
            #pragma unroll
            for (int i = 0; i < 8; i++)
                #pragma unroll
                for (int j = 0; j < 4; j++)
                    acc[i][j] = __builtin_amdgcn_mfma_f32_16x16x32_bf16(af[i], bfr[j], acc[i][j], 0, 0, 0);
        }
        p ^= 1;
    }

    // fold bias into acc (valid cols only)
    #pragma unroll
    for (int j = 0; j < 4; j++) {
        int col = bn + wc * 64 + j * 16 + (l & 15);
        float bv = (col < VV) ? bias[col] : 0.f;
        #pragma unroll
        for (int i = 0; i < 8; i++)
            #pragma unroll
            for (int r = 0; r < 4; r++)
                acc[i][j][r] += bv;
    }

    // LSE partials (registers + 16-lane shfl groups)
    int pidx = blockIdx.y * 4 + wc;
    #pragma unroll
    for (int i = 0; i < 8; i++) {
        int row = bm + wr * 128 + i * 16 + (l >> 4) * 4;
        #pragma unroll
        for (int r = 0; r < 4; r++) {
            float pv[4];
            float rmax = -1e30f;
            #pragma unroll
            for (int j = 0; j < 4; j++) {
                int col = bn + wc * 64 + j * 16 + (l & 15);
                float v = (col < VV) ? acc[i][j][r] : -1e30f;
                pv[j] = v;
                rmax = fmaxf(rmax, v);
            }
            #pragma unroll
            for (int msk = 1; msk < 16; msk <<= 1)
                rmax = fmaxf(rmax, __shfl_xor(rmax, msk));
            float s = 0.f;
            #pragma unroll
            for (int j = 0; j < 4; j++) s += __expf(pv[j] - rmax);
            #pragma unroll
            for (int msk = 1; msk < 16; msk <<= 1)
                s += __shfl_xor(s, msk);
            if ((l & 15) == 0) {
                pm[(size_t)(row + r) * NPART + pidx] = rmax;
                ps[(size_t)(row + r) * NPART + pidx] = s;
            }
        }
    }

    // staged coalesced stores: 4 chunks of 64 rows x 256 cols (stride 264)
    float* eb = (float*)smem;
    #pragma unroll
    for (int c = 0; c < 4; c++) {
        __syncthreads();
        if (wr == (c >> 1)) {
            int i0 = (c & 1) * 4;
            #pragma unroll
            for (int i = 0; i < 4; i++) {
                #pragma unroll
                for (int j = 0; j < 4; j++) {
                    int colt = wc * 64 + j * 16 + (l & 15);
                    #pragma unroll
                    for (int r = 0; r < 4; r++) {
                        int rowc = i * 16 + (l >> 4) * 4 + r;
                        eb[rowc * 264 + colt] = acc[i0 + i][j][r];
                    }
                }
            }
        }
        __syncthreads();
        #pragma unroll
        for (int pass = 0; pass < 32; pass++) {
            int idx = pass * 512 + tid;
            int rowc = idx >> 8, colq = idx & 255;
            int col = bn + colq;
            if (col < VV)
                Cf[(size_t)(bm + c * 64 + rowc) * VV + col] = eb[rowc * 264 + colq];
        }
    }
}

// ---------------- combine LSE partials -> per-row NLL
__global__ __launch_bounds__(256) void nll_combine(const float* __restrict__ pm,
                                                   const float* __restrict__ ps,
                                                   const float* __restrict__ logits,
                                                   const int* __restrict__ y,
                                                   float* __restrict__ rl) {
    int m = blockIdx.x, tid = threadIdx.x;
    __shared__ float rm[256], rs[256];
    float mt = -1e30f, st = 0.f;
    for (int i = tid; i < NPART; i += 256) {
        float mi = pm[(size_t)m * NPART + i];
        float si = ps[(size_t)m * NPART + i];
        float mn = fmaxf(mt, mi);
        st = st * __expf(mt - mn) + si * __expf(mi - mn);
        mt = mn;
    }
    rm[tid] = mt; rs[tid] = st; __syncthreads();
    for (int off = 128; off > 0; off >>= 1) {
        if (tid < off) {
            float ma = rm[tid], mb = rm[tid + off];
            float mn = fmaxf(ma, mb);
            rs[tid] = rs[tid] * __expf(ma - mn) + rs[tid + off] * __expf(mb - mn);
            rm[tid] = mn;
        }
        __syncthreads();
    }
    if (tid == 0)
        rl[m] = logf(rs[0]) + rm[0] - logits[(size_t)m * VV + y[m]];
}

// ---------------- QKV MFMA GEMM (dbuf): k,q -> bf16 [B,H,T,D]; v -> bf16 [B,H,D,T]
__global__ __launch_bounds__(256) void gemm_qkv_mfma(const __hip_bfloat16* __restrict__ A,
                                                     const __hip_bfloat16* __restrict__ kT,
                                                     const __hip_bfloat16* __restrict__ qT,
                                                     const __hip_bfloat16* __restrict__ vT,
                                                     __hip_bfloat16* __restrict__ ko,
                                                     __hip_bfloat16* __restrict__ qo,
                                                     __hip_bfloat16* __restrict__ vto) {
    const __hip_bfloat16* Bt = (blockIdx.z == 0) ? kT : (blockIdx.z == 1) ? qT : vT;
    __shared__ __align__(16) char smem[65536];
    int tid = threadIdx.x;
    int l = tid & 63, w = tid >> 6;
    int wr = w >> 1, wc = w & 1;
    int bm = blockIdx.y * 128, bn = blockIdx.x * 128;

    f32x4 acc[4][4] = {};

    stage_tile(A, Bt, CC, 0, bm, bn, w, l, smem, smem + 32768);
    int p = 0;
    for (int k0 = 0; k0 < CC; k0 += 64) {
        __syncthreads();
        if (k0 + 64 < CC)
            stage_tile(A, Bt, CC, k0 + 64, bm, bn, w, l,
                       smem + (p ^ 1) * 16384, smem + 32768 + (p ^ 1) * 16384);
        const char* Ab = smem + p * 16384;
        const char* Bb = smem + 32768 + p * 16384;
        #pragma unroll
        for (int ks = 0; ks < 2; ks++) {
            bf16x8 af[4], bfr[4];
            #pragma unroll
            for (int i = 0; i < 4; i++) {
                int row = wr * 64 + i * 16 + (l & 15);
                int cb = (ks * 64 + (l >> 4) * 16) ^ ((row & 7) << 4);
                af[i] = *(const bf16x8*)(Ab + row * 128 + cb);
            }
            #pragma unroll
            for (int j = 0; j < 4; j++) {
                int row = wc * 64 + j * 16 + (l & 15);
                int cb = (ks * 64 + (l >> 4) * 16) ^ ((row & 7) << 4);
                bfr[j] = *(const bf16x8*)(Bb + row * 128 + cb);
            }
            #pragma unroll
            for (int i = 0; i < 4; i++)
                #pragma unroll
                for (int j = 0; j < 4; j++)
                    acc[i][j] = __builtin_amdgcn_mfma_f32_16x16x32_bf16(af[i], bfr[j], acc[i][j], 0, 0, 0);
        }
        p ^= 1;
    }
    int zz = blockIdx.z;
    #pragma unroll
    for (int i = 0; i < 4; i++) {
        int row = bm + wr * 64 + i * 16 + (l >> 4) * 4;
        #pragma unroll
        for (int j = 0; j < 4; j++) {
            int col = bn + wc * 64 + j * 16 + (l & 15);
            int head = col >> 6, d = col & 63;
            #pragma unroll
            for (int r = 0; r < 4; r++) {
                int m = row + r;
                int b = m >> 10, t = m & 1023;
                __hip_bfloat16 val = __float2bfloat16(acc[i][j][r]);
                if (zz == 0)      ko[(((size_t)(b * HH + head)) * TT + t) * DD + d] = val;
                else if (zz == 1) qo[(((size_t)(b * HH + head)) * TT + t) * DD + d] = val;
                else              vto[(((size_t)(b * HH + head)) * DD + d) * TT + t] = val;
            }
        }
    }
}

// ---------------- MFMA flash attention (quirk: k plays query role)
__global__ __launch_bounds__(256) void attn_mfma(const __hip_bfloat16* __restrict__ kq,
                                                 const __hip_bfloat16* __restrict__ qk,
                                                 const __hip_bfloat16* __restrict__ vt,
                                                 __hip_bfloat16* __restrict__ oc) {
    __shared__ __hip_bfloat16 Qs[2][KVBLK * 64];
    __shared__ __hip_bfloat16 Vs[2][64 * KVBLK];
    __shared__ __hip_bfloat16 Ps[QBLK * KVBLK];
    int tid = threadIdx.x;
    int l = tid & 63, w = tid >> 6;
    int t0 = blockIdx.x * QBLK;
    size_t bh = (size_t)(blockIdx.z * HH + blockIdx.y);
    const __hip_bfloat16* kqp = kq + bh * TT * DD;
    const __hip_bfloat16* qkp = qk + bh * TT * DD;
    const __hip_bfloat16* vtp = vt + bh * DD * TT;

    bf16x8 af[2][2];
    #pragma unroll
    for (int i = 0; i < 2; i++)
        #pragma unroll
        for (int ks = 0; ks < 2; ks++)
            af[i][ks] = *(const bf16x8*)&kqp[(size_t)(t0 + w * 32 + i * 16 + (l & 15)) * DD
                                             + ks * 32 + (l >> 4) * 8];

    f32x4 acc_o[2][4] = {};
    float mrow[2][4], lrow[2][4];
    #pragma unroll
    for (int i = 0; i < 2; i++)
        #pragma unroll
        for (int r = 0; r < 4; r++) { mrow[i][r] = -1e30f; lrow[i][r] = 0.f; }

    auto stageKV = [&](int pp, int s0) {
        #pragma unroll
        for (int it = 0; it < 2; it++) {
            int chunk = w * 2 + it;
            int o = chunk * 1024 + l * 16;
            int row = o >> 7;
            int cb = (o & 127) ^ ((row & 7) << 4);
            gload_lds16(qkp + (size_t)(s0 + row) * DD + (cb >> 1),
                        (char*)Qs[pp] + chunk * 1024);
            gload_lds16(vtp + (size_t)row * TT + s0 + (cb >> 1),
                        (char*)Vs[pp] + chunk * 1024);
        }
    };

    int nt = (t0 + QBLK) / KVBLK;
    stageKV(0, 0);
    int p = 0;
    for (int ti = 0; ti < nt; ti++) {
        int s0 = ti * KVBLK;
        __syncthreads();
        if (ti + 1 < nt) stageKV(p ^ 1, s0 + KVBLK);

        f32x4 sa[2][4] = {};
        #pragma unroll
        for (int ks = 0; ks < 2; ks++) {
            bf16x8 bfr[4];
            #pragma unroll
            for (int j = 0; j < 4; j++) {
                int row = j * 16 + (l & 15);
                int cb = (ks * 64 + (l >> 4) * 16) ^ ((row & 7) << 4);
                bfr[j] = *(const bf16x8*)((const char*)Qs[p] + row * 128 + cb);
            }
            #pragma unroll
            for (int i = 0; i < 2; i++)
                #pragma unroll
                for (int j = 0; j < 4; j++)
                    sa[i][j] = __builtin_amdgcn_mfma_f32_16x16x32_bf16(af[i][ks], bfr[j], sa[i][j], 0, 0, 0);
        }

        #pragma unroll
        for (int i = 0; i < 2; i++) {
            #pragma unroll
            for (int r = 0; r < 4; r++) {
                int t = t0 + w * 32 + i * 16 + (l >> 4) * 4 + r;
                float pv[4];
                float rmax = -1e30f;
                #pragma unroll
                for (int j = 0; j < 4; j++) {
                    int s = s0 + j * 16 + (l & 15);
                    float v = sa[i][j][r] * 0.125f;
                    v = (s <= t) ? v : -1e30f;
                    pv[j] = v;
                    rmax = fmaxf(rmax, v);
                }
                #pragma unroll
                for (int msk = 1; msk < 16; msk <<= 1)
                    rmax = fmaxf(rmax, __shfl_xor(rmax, msk));
                float mo = mrow[i][r];
                float mn = fmaxf(mo, rmax);
                float fac = __expf(mo - mn);
                float ls = 0.f;
                int prow = w * 32 + i * 16 + (l >> 4) * 4 + r;
                #pragma unroll
                for (int j = 0; j < 4; j++) {
                    float e = __expf(pv[j] - mn);
                    ls += e;
                    int cb = (j * 32 + (l & 15) * 2) ^ ((prow & 7) << 4);
                    *(__hip_bfloat16*)((char*)Ps + prow * 128 + cb) = __float2bfloat16(e);
                }
                #pragma unroll
                for (int msk = 1; msk < 16; msk <<= 1)
                    ls += __shfl_xor(ls, msk);
                mrow[i][r] = mn;
                lrow[i][r] = lrow[i][r] * fac + ls;
                #pragma unroll
                for (int jd = 0; jd < 4; jd++)
                    acc_o[i][jd][r] *= fac;
            }
        }

        #pragma unroll
        for (int ks = 0; ks < 2; ks++) {
            bf16x8 pa[2], vf[4];
            #pragma unroll
            for (int i = 0; i < 2; i++) {
                int row = w * 32 + i * 16 + (l & 15);
                int cb = (ks * 64 + (l >> 4) * 16) ^ ((row & 7) << 4);
                pa[i] = *(const bf16x8*)((const char*)Ps + row * 128 + cb);
            }
            #pragma unroll
            for (int jd = 0; jd < 4; jd++) {
                int row = jd * 16 + (l & 15);
                int cb = (ks * 64 + (l >> 4) * 16) ^ ((row & 7) << 4);
                vf[jd] = *(const bf16x8*)((const char*)Vs[p] + row * 128 + cb);
            }
            #pragma unroll
            for (int i = 0; i < 2; i++)
                #pragma unroll
                for (int jd = 0; jd < 4; jd++)
                    acc_o[i][jd] = __builtin_amdgcn_mfma_f32_16x16x32_bf16(pa[i], vf[jd], acc_o[i][jd], 0, 0, 0);
        }
        p ^= 1;
    }

    int b = blockIdx.z, hh = blockIdx.y;
    #pragma unroll
    for (int i = 0; i < 2; i++) {
        #pragma unroll
        for (int r = 0; r < 4; r++) {
            float inv = 1.f / lrow[i][r];
            int t = t0 + w * 32 + i * 16 + (l >> 4) * 4 + r;
            #pragma unroll
            for (int jd = 0; jd < 4; jd++) {
                int d = jd * 16 + (l & 15);
                oc[((size_t)(b * TT + t)) * CC + hh * DD + d] =
                    __float2bfloat16(acc_o[i][jd][r] * inv);
            }
        }
    }
}

// ---------------- h = LN(h + t); writes f32 h and bf16 hb
__global__ __launch_bounds__(256) void resid_ln(float* __restrict__ h,
                                                const float* __restrict__ t,
                                                const float* __restrict__ g,
                                                const float* __restrict__ bta,
                                                __hip_bfloat16* __restrict__ hb) {
    int row = blockIdx.x;
    int tid = threadIdx.x;
    __shared__ float red[256];
    float x[3];
    float s = 0.f;
    #pragma unroll
    for (int i = 0; i < 3; i++) {
        int c = tid + i * 256;
        x[i] = h[(size_t)row * CC + c] + t[(size_t)row * CC + c];
        s += x[i];
    }
    red[tid] = s; __syncthreads();
    for (int off = 128; off > 0; off >>= 1) {
        if (tid < off) red[tid] += red[tid + off];
        __syncthreads();
    }
    float mean = red[0] * (1.f / CC); __syncthreads();
    float s2 = 0.f;
    #pragma unroll
    for (int i = 0; i < 3; i++) { float dd = x[i] - mean; s2 += dd * dd; }
    red[tid] = s2; __syncthreads();
    for (int off = 128; off > 0; off >>= 1) {
        if (tid < off) red[tid] += red[tid + off];
        __syncthreads();
    }
    float inv = rsqrtf(red[0] * (1.f / CC) + 1e-5f);
    #pragma unroll
    for (int i = 0; i < 3; i++) {
        int c = tid + i * 256;
        float o = (x[i] - mean) * inv * g[c] + bta[c];
        h[(size_t)row * CC + c] = o;
        hb[(size_t)row * CC + c] = __float2bfloat16(o);
    }
}

__global__ __launch_bounds__(256) void loss_reduce(const float* __restrict__ rl,
                                                   float* __restrict__ out) {
    int tid = threadIdx.x;
    __shared__ float red[256];
    float s = 0.f;
    for (int i = tid; i < MROWS; i += 256) s += rl[i];
    red[tid] = s; __syncthreads();
    for (int off = 128; off > 0; off >>= 1) {
        if (tid < off) red[tid] += red[tid + off];
        __syncthreads();
    }
    if (tid == 0) out[0] = red[0] * (1.f / MROWS);
}

extern "C" void kernel_launch(void* const* d_in, const int* in_sizes, int n_in,
                              void* d_out, int out_size, void* d_ws, size_t ws_size,
                              hipStream_t stream) {
    const int*   x     = (const int*)d_in[0];
    const int*   y     = (const int*)d_in[1];
    const float* tok   = (const float*)d_in[2];
    const float* pos   = (const float*)d_in[3];
    const float* Wk    = (const float*)d_in[4];
    const float* Wq    = (const float*)d_in[5];
    const float* Wv    = (const float*)d_in[6];
    const float* Wproj = (const float*)d_in[7];
    const float* bproj = (const float*)d_in[8];
    const float* ln1g  = (const float*)d_in[9];
    const float* ln1b  = (const float*)d_in[10];
    const float* W1    = (const float*)d_in[11];
    const float* b1    = (const float*)d_in[12];
    const float* W2    = (const float*)d_in[13];
    const float* b2    = (const float*)d_in[14];
    const float* ln2g  = (const float*)d_in[15];
    const float* ln2b  = (const float*)d_in[16];
    const float* Wlm   = (const float*)d_in[17];
    const float* blm   = (const float*)d_in[18];

    float* logits = (float*)d_out;
    float* lossp  = (float*)d_out + ((size_t)out_size - 1);

    char* p = (char*)d_ws;
    auto alloc = [&](size_t bytes) { char* r = p; p += (bytes + 255) & ~255ULL; return r; };
    const size_t S_HC = (size_t)MROWS * CC;

    float* h    = (float*)alloc(S_HC * 4);
    float* tmpf = (float*)alloc(S_HC * 4);
    float* rl   = (float*)alloc(MROWS * 4);
    float* pm   = (float*)alloc((size_t)MROWS * NPART * 4);
    float* ps   = (float*)alloc((size_t)MROWS * NPART * 4);
    __hip_bfloat16* kbb  = (__hip_bfloat16*)alloc(S_HC * 2);
    __hip_bfloat16* qbb  = (__hip_bfloat16*)alloc(S_HC * 2);
    __hip_bfloat16* vtb  = (__hip_bfloat16*)alloc(S_HC * 2);
    __hip_bfloat16* hb   = (__hip_bfloat16*)alloc(S_HC * 2);
    __hip_bfloat16* ocb  = (__hip_bfloat16*)alloc(S_HC * 2);
    __hip_bfloat16* ff1b = (__hip_bfloat16*)alloc((size_t)MROWS * FFH * 2);
    __hip_bfloat16* kT   = (__hip_bfloat16*)alloc((size_t)LL * CC * CC * 2);
    __hip_bfloat16* qT   = (__hip_bfloat16*)alloc((size_t)LL * CC * CC * 2);
    __hip_bfloat16* vT   = (__hip_bfloat16*)alloc((size_t)LL * CC * CC * 2);
    __hip_bfloat16* pT   = (__hip_bfloat16*)alloc((size_t)LL * CC * CC * 2);
    __hip_bfloat16* w1T  = (__hip_bfloat16*)alloc((size_t)LL * CC * FFH * 2);
    __hip_bfloat16* w2T  = (__hip_bfloat16*)alloc((size_t)LL * FFH * CC * 2);
    __hip_bfloat16* lmT  = (__hip_bfloat16*)alloc((size_t)VPAD2 * CC * 2);

    dim3 blk(256);

    cvtT_qkv<<<dim3(24, 2, 3 * 144), blk, 0, stream>>>(Wk, Wq, Wv, kT, qT, vT);
    cvtT_mat<<<dim3(24, 24, LL), blk, 0, stream>>>(Wproj, pT, CC, CC,
                                                   (size_t)CC * CC, (size_t)CC * CC);
    cvtT_mat<<<dim3(96, 24, LL), blk, 0, stream>>>(W1, w1T, CC, FFH,
                                                   (size_t)CC * FFH, (size_t)FFH * CC);
    cvtT_mat<<<dim3(24, 96, LL), blk, 0, stream>>>(W2, w2T, FFH, CC,
                                                   (size_t)FFH * CC, (size_t)CC * FFH);
    cvtT_mat<<<dim3(VPAD2 / 32, 24, 1), blk, 0, stream>>>(Wlm, lmT, CC, VV, 0, 0);

    embed_kernel<<<dim3((MROWS * CC + 255) / 256), blk, 0, stream>>>(x, tok, pos, h, hb);

    for (int l = 0; l < LL; l++) {
        const __hip_bfloat16* kT_l = kT + (size_t)l * CC * CC;
        const __hip_bfloat16* qT_l = qT + (size_t)l * CC * CC;
        const __hip_bfloat16* vT_l = vT + (size_t)l * CC * CC;
        const __hip_bfloat16* pT_l = pT + (size_t)l * CC * CC;
        const __hip_bfloat16* w1T_l = w1T + (size_t)l * CC * FFH;
        const __hip_bfloat16* w2T_l = w2T + (size_t)l * FFH * CC;

        gemm_qkv_mfma<<<dim3(CC / 128, MROWS / 128, 3), blk, 0, stream>>>(
            hb, kT_l, qT_l, vT_l, kbb, qbb, vtb);
        attn_mfma<<<dim3(TT / QBLK, HH, BB), blk, 0, stream>>>(kbb, qbb, vtb, ocb);
        gemm_mfma<<<dim3(CC / 128, MROWS / 128), blk, 0, stream>>>(
            ocb, pT_l, bproj + (size_t)l * CC, tmpf, (__hip_bfloat16*)nullptr,
            MROWS, CC, CC, 0);
        resid_ln<<<dim3(MROWS), blk, 0, stream>>>(h, tmpf, ln1g + (size_t)l * CC,
                                                  ln1b + (size_t)l * CC, hb);
        gemm_mfma<<<dim3(FFH / 128, MROWS / 128), blk, 0, stream>>>(
            hb, w1T_l, b1 + (size_t)l * FFH, (float*)nullptr, ff1b,
            MROWS, FFH, CC, 1);
        gemm_mfma<<<dim3(CC / 128, MROWS / 128), blk, 0, stream>>>(
            ff1b, w2T_l, b2 + (size_t)l * CC, tmpf, (__hip_bfloat16*)nullptr,
            MROWS, CC, FFH, 0);
        resid_ln<<<dim3(MROWS), blk, 0, stream>>>(h, tmpf, ln2g + (size_t)l * CC,
                                                  ln2b + (size_t)l * CC, hb);
    }

    lm_head_mfma256<<<dim3(MROWS / 256, VPAD2 / 256), dim3(512), 0, stream>>>(
        hb, lmT, blm, logits, pm, ps);
    nll_combine<<<dim3(MROWS), blk, 0, stream>>>(pm, ps, logits, y, rl);
    loss_reduce<<<dim3(1), blk, 0, stream>>>(rl, lossp);
}

// Round 9
// 3335.974 us; speedup vs baseline: 16.0182x; 1.0174x over previous
//
#include <hip/hip_runtime.h>
#include <hip/hip_bf16.h>
#include <math.h>

#define BB 4
#define TT 1024
#define VV 50257
#define VPAD2 50432
#define CC 768
#define HH 12
#define DD 64
#define LL 12
#define FFH 3072
#define MROWS (BB*TT)   // 4096
#define QBLK 128
#define KVBLK 64
#define NPART (VPAD2 / 64)        // 788 partials per row

typedef __bf16 bf16x8 __attribute__((ext_vector_type(8)));
typedef float  f32x4  __attribute__((ext_vector_type(4)));
typedef unsigned int u32;
#define AS1 __attribute__((address_space(1)))
#define AS3 __attribute__((address_space(3)))

static __device__ __forceinline__ void gload_lds16(const void* g, void* l) {
    __builtin_amdgcn_global_load_lds((const AS1 u32*)g, (AS3 u32*)l, 16, 0, 0);
}

// stage one 128x64 bf16 tile pair into linear LDS, source pre-swizzled (4 waves)
static __device__ __forceinline__ void stage_tile(const __hip_bfloat16* __restrict__ A,
                                                  const __hip_bfloat16* __restrict__ Bt,
                                                  int Kld, int k0, int bm, int bn,
                                                  int w, int l, char* As, char* Bs) {
    #pragma unroll
    for (int it = 0; it < 4; it++) {
        int chunk = w * 4 + it;
        int o = chunk * 1024 + l * 16;
        int row = o >> 7;
        int cb = (o & 127) ^ ((row & 7) << 4);
        gload_lds16(A + (size_t)(bm + row) * Kld + k0 + (cb >> 1), As + chunk * 1024);
        gload_lds16(Bt + (size_t)(bn + row) * Kld + k0 + (cb >> 1), Bs + chunk * 1024);
    }
}

// stage one 256x32 bf16 tile pair into linear LDS (8 waves / 512 threads), 64B rows
static __device__ __forceinline__ void stage_tile256_k32(const __hip_bfloat16* __restrict__ A,
                                                         const __hip_bfloat16* __restrict__ Bt,
                                                         int Kld, int k0, int bm, int bn,
                                                         int w, int l, char* As, char* Bs) {
    #pragma unroll
    for (int it = 0; it < 2; it++) {
        int chunk = w * 2 + it;                 // 0..15, 1KB chunks
        int o = chunk * 1024 + l * 16;
        int row = o >> 6;                       // 0..255 (64B rows)
        int cb = (o & 63) ^ ((row & 3) << 4);   // swizzled source column byte
        gload_lds16(A + (size_t)(bm + row) * Kld + k0 + (cb >> 1), As + chunk * 1024);
        gload_lds16(Bt + (size_t)(bn + row) * Kld + k0 + (cb >> 1), Bs + chunk * 1024);
    }
}

// ---------------- embedding
__global__ void embed_kernel(const int* __restrict__ x, const float* __restrict__ tok,
                             const float* __restrict__ pos, float* __restrict__ h,
                             __hip_bfloat16* __restrict__ hb) {
    int idx = blockIdx.x * 256 + threadIdx.x;
    if (idx >= MROWS * CC) return;
    int row = idx / CC, c = idx - row * CC;
    int id = x[row];
    float v = tok[(size_t)id * CC + c] + pos[(size_t)id * CC + c];
    h[idx] = v;
    hb[idx] = __float2bfloat16(v);
}

// ---------------- convert + transpose weights
__global__ __launch_bounds__(256) void cvtT_mat(const float* __restrict__ in,
                                                __hip_bfloat16* __restrict__ out,
                                                int K, int Nin,
                                                size_t ibs, size_t obs) {
    __shared__ float t[32][33];
    const float* ip = in + blockIdx.z * ibs;
    __hip_bfloat16* op = out + blockIdx.z * obs;
    int n0 = blockIdx.x * 32, k0 = blockIdx.y * 32;
    int tx = threadIdx.x & 31, ty = threadIdx.x >> 5;
    #pragma unroll
    for (int i = 0; i < 4; i++) {
        int k = k0 + ty + i * 8, n = n0 + tx;
        t[ty + i * 8][tx] = (n < Nin) ? ip[(size_t)k * Nin + n] : 0.f;
    }
    __syncthreads();
    #pragma unroll
    for (int i = 0; i < 4; i++) {
        int n = n0 + ty + i * 8, k = k0 + tx;
        op[(size_t)n * K + k] = __float2bfloat16(t[tx][ty + i * 8]);
    }
}

__global__ __launch_bounds__(256) void cvtT_qkv(const float* __restrict__ Wk,
                                                const float* __restrict__ Wq,
                                                const float* __restrict__ Wv,
                                                __hip_bfloat16* __restrict__ kT,
                                                __hip_bfloat16* __restrict__ qT,
                                                __hip_bfloat16* __restrict__ vT) {
    int z = blockIdx.z;
    int tensor = z / 144, lh = z % 144;
    int l = lh / HH, hh = lh % HH;
    const float* in = (tensor == 0 ? Wk : tensor == 1 ? Wq : Wv) + (size_t)lh * CC * DD;
    __hip_bfloat16* out = (tensor == 0 ? kT : tensor == 1 ? qT : vT)
                          + ((size_t)l * CC + hh * DD) * CC;
    __shared__ float t[32][33];
    int c0 = blockIdx.x * 32, d0 = blockIdx.y * 32;
    int tx = threadIdx.x & 31, ty = threadIdx.x >> 5;
    #pragma unroll
    for (int i = 0; i < 4; i++)
        t[ty + i * 8][tx] = in[(size_t)(c0 + ty + i * 8) * DD + d0 + tx];
    __syncthreads();
    #pragma unroll
    for (int i = 0; i < 4; i++)
        out[(size_t)(d0 + ty + i * 8) * CC + c0 + tx] = __float2bfloat16(t[tx][ty + i * 8]);
}

// ---------------- MFMA GEMM 128x128 dbuf + LDS-staged coalesced epilogue.
__global__ __launch_bounds__(256) void gemm_mfma(const __hip_bfloat16* __restrict__ A,
                                                 const __hip_bfloat16* __restrict__ Bt,
                                                 const float* __restrict__ bias,
                                                 float* __restrict__ Cf,
                                                 __hip_bfloat16* __restrict__ Cb,
                                                 int M, int N, int K, int relu) {
    __shared__ __align__(16) char smem[65536];
    int tid = threadIdx.x;
    int l = tid & 63, w = tid >> 6;
    int wr = w >> 1, wc = w & 1;
    int bm = blockIdx.y * 128, bn = blockIdx.x * 128;

    f32x4 acc[4][4] = {};

    stage_tile(A, Bt, K, 0, bm, bn, w, l, smem, smem + 32768);
    int p = 0;
    for (int k0 = 0; k0 < K; k0 += 64) {
        __syncthreads();
        if (k0 + 64 < K)
            stage_tile(A, Bt, K, k0 + 64, bm, bn, w, l,
                       smem + (p ^ 1) * 16384, smem + 32768 + (p ^ 1) * 16384);
        const char* Ab = smem + p * 16384;
        const char* Bb = smem + 32768 + p * 16384;
        #pragma unroll
        for (int ks = 0; ks < 2; ks++) {
            bf16x8 af[4], bfr[4];
            #pragma unroll
            for (int i = 0; i < 4; i++) {
                int row = wr * 64 + i * 16 + (l & 15);
                int cb = (ks * 64 + (l >> 4) * 16) ^ ((row & 7) << 4);
                af[i] = *(const bf16x8*)(Ab + row * 128 + cb);
            }
            #pragma unroll
            for (int j = 0; j < 4; j++) {
                int row = wc * 64 + j * 16 + (l & 15);
                int cb = (ks * 64 + (l >> 4) * 16) ^ ((row & 7) << 4);
                bfr[j] = *(const bf16x8*)(Bb + row * 128 + cb);
            }
            #pragma unroll
            for (int i = 0; i < 4; i++)
                #pragma unroll
                for (int j = 0; j < 4; j++)
                    acc[i][j] = __builtin_amdgcn_mfma_f32_16x16x32_bf16(af[i], bfr[j], acc[i][j], 0, 0, 0);
        }
        p ^= 1;
    }

    if (Cb) {
        __hip_bfloat16* ebh = (__hip_bfloat16*)smem;
        __syncthreads();
        #pragma unroll
        for (int i = 0; i < 4; i++) {
            #pragma unroll
            for (int j = 0; j < 4; j++) {
                int colt = wc * 64 + j * 16 + (l & 15);
                float bv = bias ? bias[bn + colt] : 0.f;
                #pragma unroll
                for (int r = 0; r < 4; r++) {
                    int rowc = wr * 64 + i * 16 + (l >> 4) * 4 + r;
                    float v = acc[i][j][r] + bv;
                    if (relu) v = fmaxf(v, 0.f);
                    ebh[rowc * 136 + colt] = __float2bfloat16(v);
                }
            }
        }
        __syncthreads();
        #pragma unroll
        for (int pass = 0; pass < 8; pass++) {
            int idx = pass * 256 + tid;
            int rowc = idx >> 4, colq = idx & 15;
            *(bf16x8*)&Cb[(size_t)(bm + rowc) * N + bn + colq * 8] =
                *(const bf16x8*)&ebh[rowc * 136 + colq * 8];
        }
    } else {
        float* eb = (float*)smem;
        #pragma unroll
        for (int c = 0; c < 2; c++) {
            __syncthreads();
            if (wr == c) {
                #pragma unroll
                for (int i = 0; i < 4; i++) {
                    #pragma unroll
                    for (int j = 0; j < 4; j++) {
                        int colt = wc * 64 + j * 16 + (l & 15);
                        float bv = bias ? bias[bn + colt] : 0.f;
                        #pragma unroll
                        for (int r = 0; r < 4; r++) {
                            int rowc = i * 16 + (l >> 4) * 4 + r;
                            float v = acc[i][j][r] + bv;
                            if (relu) v = fmaxf(v, 0.f);
                            eb[rowc * 132 + colt] = v;
                        }
                    }
                }
            }
            __syncthreads();
            #pragma unroll
            for (int pass = 0; pass < 8; pass++) {
                int idx = pass * 256 + tid;
                int rowc = idx >> 5, colq = idx & 31;
                *(f32x4*)&Cf[(size_t)(bm + c * 64 + rowc) * N + bn + colq * 4] =
                    *(const f32x4*)&eb[rowc * 132 + colq * 4];
            }
        }
    }
}

// ---------------- LM head: 256x256, 8 waves, BK=32 dbuf (64KB LDS -> 2 blocks/CU),
// fused LSE + staged coalesced stores.
__global__ __launch_bounds__(512) void lm_head_mfma256(const __hip_bfloat16* __restrict__ A,
                                                       const __hip_bfloat16* __restrict__ Bt,
                                                       const float* __restrict__ bias,
                                                       float* __restrict__ Cf,
                                                       float* __restrict__ pm,
                                                       float* __restrict__ ps) {
    __shared__ __align__(16) char smem[65536];   // As[2] 2x16K @0, Bs[2] @32768; epilogue reuses
    int tid = threadIdx.x;
    int l = tid & 63, w = tid >> 6;
    int wr = w >> 2, wc = w & 3;
    int bm = blockIdx.x * 256, bn = blockIdx.y * 256;   // row-fastest

    f32x4 acc[8][4] = {};

    stage_tile256_k32(A, Bt, CC, 0, bm, bn, w, l, smem, smem + 32768);
    int p = 0;
    for (int k0 = 0; k0 < CC; k0 += 32) {
        __syncthreads();
        if (k0 + 32 < CC)
            stage_tile256_k32(A, Bt, CC, k0 + 32, bm, bn, w, l,
                              smem + (p ^ 1) * 16384, smem + 32768 + (p ^ 1) * 16384);
        const char* Ab = smem + p * 16384;
        const char* Bb = smem + 32768 + p * 16384;
        bf16x8 af[8], bfr[4];
        #pragma unroll
        for (int i = 0; i < 8; i++) {
            int row = wr * 128 + i * 16 + (l & 15);
            int cb = ((l >> 4) * 16) ^ ((row & 3) << 4);
            af[i] = *(const bf16x8*)(Ab + row * 64 + cb);
        }
        #pragma unroll
        for (int j = 0; j < 4; j++) {
            int row = wc * 64 + j * 16 + (l & 15);
            int cb = ((l >> 4) * 16) ^ ((row & 3) << 4);
            bfr[j] = *(const bf16x8*)(Bb + row * 64 + cb);
        }
        #pragma unroll
        for (int i = 0; i < 8; i++)
            #pragma unroll
            for (int j = 0; j < 4; j++)
                acc[i][j] = __builtin_amdgcn_mfma_f32_16x16x32_bf16(af[i], bfr[j], acc[i][j], 0, 0, 0);
        p ^= 1;
    }

    // fold bias
    #pragma unroll
    for (int j = 0; j < 4; j++) {
        int col = bn + wc * 64 + j * 16 + (l & 15);
        float bv = (col < VV) ? bias[col] : 0.f;
        #pragma unroll
        for (int i = 0; i < 8; i++)
            #pragma unroll
            for (int r = 0; r < 4; r++)
                acc[i][j][r] += bv;
    }

    // LSE partials
    int pidx = blockIdx.y * 4 + wc;
    #pragma unroll
    for (int i = 0; i < 8; i++) {
        int row = bm + wr * 128 + i * 16 + (l >> 4) * 4;
        #pragma unroll
        for (int r = 0; r < 4; r++) {
            float pv[4];
            float rmax = -1e30f;
            #pragma unroll
            for (int j = 0; j < 4; j++) {
                int col = bn + wc * 64 + j * 16 + (l & 15);
                float v = (col < VV) ? acc[i][j][r] : -1e30f;
                pv[j] = v;
                rmax = fmaxf(rmax, v);
            }
            #pragma unroll
            for (int msk = 1; msk < 16; msk <<= 1)
                rmax = fmaxf(rmax, __shfl_xor(rmax, msk));
            float s = 0.f;
            #pragma unroll
            for (int j = 0; j < 4; j++) s += __expf(pv[j] - rmax);
            #pragma unroll
            for (int msk = 1; msk < 16; msk <<= 1)
                s += __shfl_xor(s, msk);
            if ((l & 15) == 0) {
                pm[(size_t)(row + r) * NPART + pidx] = rmax;
                ps[(size_t)(row + r) * NPART + pidx] = s;
            }
        }
    }

    // staged coalesced stores: 8 chunks of 32 rows x 256 cols (stride 264, 33.8KB)
    float* eb = (float*)smem;
    #pragma unroll
    for (int c = 0; c < 8; c++) {
        __syncthreads();
        if (wr == (c >> 2)) {
            int i0 = (c & 3) * 2;
            #pragma unroll
            for (int ii = 0; ii < 2; ii++) {
                #pragma unroll
                for (int j = 0; j < 4; j++) {
                    int colt = wc * 64 + j * 16 + (l & 15);
                    #pragma unroll
                    for (int r = 0; r < 4; r++) {
                        int rowc = ii * 16 + (l >> 4) * 4 + r;
                        eb[rowc * 264 + colt] = acc[i0 + ii][j][r];
                    }
                }
            }
        }
        __syncthreads();
        #pragma unroll
        for (int pass = 0; pass < 16; pass++) {
            int idx = pass * 512 + tid;
            int rowc = idx >> 8, colq = idx & 255;
            int col = bn + colq;
            if (col < VV)
                Cf[(size_t)(bm + c * 32 + rowc) * VV + col] = eb[rowc * 264 + colq];
        }
    }
}

// ---------------- combine LSE partials -> per-row NLL
__global__ __launch_bounds__(256) void nll_combine(const float* __restrict__ pm,
                                                   const float* __restrict__ ps,
                                                   const float* __restrict__ logits,
                                                   const int* __restrict__ y,
                                                   float* __restrict__ rl) {
    int m = blockIdx.x, tid = threadIdx.x;
    __shared__ float rm[256], rs[256];
    float mt = -1e30f, st = 0.f;
    for (int i = tid; i < NPART; i += 256) {
        float mi = pm[(size_t)m * NPART + i];
        float si = ps[(size_t)m * NPART + i];
        float mn = fmaxf(mt, mi);
        st = st * __expf(mt - mn) + si * __expf(mi - mn);
        mt = mn;
    }
    rm[tid] = mt; rs[tid] = st; __syncthreads();
    for (int off = 128; off > 0; off >>= 1) {
        if (tid < off) {
            float ma = rm[tid], mb = rm[tid + off];
            float mn = fmaxf(ma, mb);
            rs[tid] = rs[tid] * __expf(ma - mn) + rs[tid + off] * __expf(mb - mn);
            rm[tid] = mn;
        }
        __syncthreads();
    }
    if (tid == 0)
        rl[m] = logf(rs[0]) + rm[0] - logits[(size_t)m * VV + y[m]];
}

// ---------------- QKV MFMA GEMM (dbuf): LDS-staged coalesced epilogue.
// k,q -> bf16 [B,H,T,D] (128B head-runs); v -> bf16 [B,H,D,T] (256B t-runs via transpose).
__global__ __launch_bounds__(256) void gemm_qkv_mfma(const __hip_bfloat16* __restrict__ A,
                                                     const __hip_bfloat16* __restrict__ kT,
                                                     const __hip_bfloat16* __restrict__ qT,
                                                     const __hip_bfloat16* __restrict__ vT,
                                                     __hip_bfloat16* __restrict__ ko,
                                                     __hip_bfloat16* __restrict__ qo,
                                                     __hip_bfloat16* __restrict__ vto) {
    const __hip_bfloat16* Bt = (blockIdx.z == 0) ? kT : (blockIdx.z == 1) ? qT : vT;
    __shared__ __align__(16) char smem[65536];
    int tid = threadIdx.x;
    int l = tid & 63, w = tid >> 6;
    int wr = w >> 1, wc = w & 1;
    int bm = blockIdx.y * 128, bn = blockIdx.x * 128;

    f32x4 acc[4][4] = {};

    stage_tile(A, Bt, CC, 0, bm, bn, w, l, smem, smem + 32768);
    int p = 0;
    for (int k0 = 0; k0 < CC; k0 += 64) {
        __syncthreads();
        if (k0 + 64 < CC)
            stage_tile(A, Bt, CC, k0 + 64, bm, bn, w, l,
                       smem + (p ^ 1) * 16384, smem + 32768 + (p ^ 1) * 16384);
        const char* Ab = smem + p * 16384;
        const char* Bb = smem + 32768 + p * 16384;
        #pragma unroll
        for (int ks = 0; ks < 2; ks++) {
            bf16x8 af[4], bfr[4];
            #pragma unroll
            for (int i = 0; i < 4; i++) {
                int row = wr * 64 + i * 16 + (l & 15);
                int cb = (ks * 64 + (l >> 4) * 16) ^ ((row & 7) << 4);
                af[i] = *(const bf16x8*)(Ab + row * 128 + cb);
            }
            #pragma unroll
            for (int j = 0; j < 4; j++) {
                int row = wc * 64 + j * 16 + (l & 15);
                int cb = (ks * 64 + (l >> 4) * 16) ^ ((row & 7) << 4);
                bfr[j] = *(const bf16x8*)(Bb + row * 128 + cb);
            }
            #pragma unroll
            for (int i = 0; i < 4; i++)
                #pragma unroll
                for (int j = 0; j < 4; j++)
                    acc[i][j] = __builtin_amdgcn_mfma_f32_16x16x32_bf16(af[i], bfr[j], acc[i][j], 0, 0, 0);
        }
        p ^= 1;
    }

    int zz = blockIdx.z;
    int b = bm >> 10, tbase = bm & 1023;
    __hip_bfloat16* eb = (__hip_bfloat16*)smem;
    __syncthreads();   // K-loop LDS reads retired; smem reusable
    if (zz != 2) {
        // row-major stage (stride 136), then 16B stores in 128B head-runs
        #pragma unroll
        for (int i = 0; i < 4; i++)
            #pragma unroll
            for (int j = 0; j < 4; j++) {
                int colt = wc * 64 + j * 16 + (l & 15);
                #pragma unroll
                for (int r = 0; r < 4; r++) {
                    int rowc = wr * 64 + i * 16 + (l >> 4) * 4 + r;
                    eb[rowc * 136 + colt] = __float2bfloat16(acc[i][j][r]);
                }
            }
        __syncthreads();
        __hip_bfloat16* O = (zz == 0) ? ko : qo;
        #pragma unroll
        for (int pass = 0; pass < 8; pass++) {
            int idx = pass * 256 + tid;
            int rowc = idx >> 4, colq = idx & 15;
            int head = (bn >> 6) + (colq >> 3);
            int d = (colq & 7) * 8;
            int t = tbase + rowc;
            *(bf16x8*)&O[(((size_t)(b * HH + head)) * TT + t) * DD + d] =
                *(const bf16x8*)&eb[rowc * 136 + colq * 8];
        }
    } else {
        // transposed stage: eb[colt*136 + rowc], then 16B stores along t (256B runs)
        #pragma unroll
        for (int i = 0; i < 4; i++)
            #pragma unroll
            for (int j = 0; j < 4; j++) {
                int colt = wc * 64 + j * 16 + (l & 15);
                #pragma unroll
                for (int r = 0; r < 4; r++) {
                    int rowc = wr * 64 + i * 16 + (l >> 4) * 4 + r;
                    eb[colt * 136 + rowc] = __float2bfloat16(acc[i][j][r]);
                }
            }
        __syncthreads();
        #pragma unroll
        for (int pass = 0; pass < 8; pass++) {
            int idx = pass * 256 + tid;
            int line = idx >> 4, tq = idx & 15;
            int head = (bn >> 6) + (line >> 6);
            int d = line & 63;
            *(bf16x8*)&vto[(((size_t)(b * HH + head)) * DD + d) * TT + tbase + tq * 8] =
                *(const bf16x8*)&eb[line * 136 + tq * 8];
        }
    }
}

// ---------------- MFMA flash attention (quirk: k plays query role)
__global__ __launch_bounds__(256) void attn_mfma(const __hip_bfloat16* __restrict__ kq,
                                                 const __hip_bfloat16* __restrict__ qk,
                                                 const __hip_bfloat16* __restrict__ vt,
                                                 __hip_bfloat16* __restrict__ oc) {
    __shared__ __hip_bfloat16 Qs[2][KVBLK * 64];
    __shared__ __hip_bfloat16 Vs[2][64 * KVBLK];
    __shared__ __hip_bfloat16 Ps[QBLK * KVBLK];
    int tid = threadIdx.x;
    int l = tid & 63, w = tid >> 6;
    int t0 = blockIdx.x * QBLK;
    size_t bh = (size_t)(blockIdx.z * HH + blockIdx.y);
    const __hip_bfloat16* kqp = kq + bh * TT * DD;
    const __hip_bfloat16* qkp = qk + bh * TT * DD;
    const __hip_bfloat16* vtp = vt + bh * DD * TT;

    bf16x8 af[2][2];
    #pragma unroll
    for (int i = 0; i < 2; i++)
        #pragma unroll
        for (int ks = 0; ks < 2; ks++)
            af[i][ks] = *(const bf16x8*)&kqp[(size_t)(t0 + w * 32 + i * 16 + (l & 15)) * DD
                                             + ks * 32 + (l >> 4) * 8];

    f32x4 acc_o[2][4] = {};
    float mrow[2][4], lrow[2][4];
    #pragma unroll
    for (int i = 0; i < 2; i++)
        #pragma unroll
        for (int r = 0; r < 4; r++) { mrow[i][r] = -1e30f; lrow[i][r] = 0.f; }

    auto stageKV = [&](int pp, int s0) {
        #pragma unroll
        for (int it = 0; it < 2; it++) {
            int chunk = w * 2 + it;
            int o = chunk * 1024 + l * 16;
            int row = o >> 7;
            int cb = (o & 127) ^ ((row & 7) << 4);
            gload_lds16(qkp + (size_t)(s0 + row) * DD + (cb >> 1),
                        (char*)Qs[pp] + chunk * 1024);
            gload_lds16(vtp + (size_t)row * TT + s0 + (cb >> 1),
                        (char*)Vs[pp] + chunk * 1024);
        }
    };

    int nt = (t0 + QBLK) / KVBLK;
    stageKV(0, 0);
    int p = 0;
    for (int ti = 0; ti < nt; ti++) {
        int s0 = ti * KVBLK;
        __syncthreads();
        if (ti + 1 < nt) stageKV(p ^ 1, s0 + KVBLK);

        f32x4 sa[2][4] = {};
        #pragma unroll
        for (int ks = 0; ks < 2; ks++) {
            bf16x8 bfr[4];
            #pragma unroll
            for (int j = 0; j < 4; j++) {
                int row = j * 16 + (l & 15);
                int cb = (ks * 64 + (l >> 4) * 16) ^ ((row & 7) << 4);
                bfr[j] = *(const bf16x8*)((const char*)Qs[p] + row * 128 + cb);
            }
            #pragma unroll
            for (int i = 0; i < 2; i++)
                #pragma unroll
                for (int j = 0; j < 4; j++)
                    sa[i][j] = __builtin_amdgcn_mfma_f32_16x16x32_bf16(af[i][ks], bfr[j], sa[i][j], 0, 0, 0);
        }

        #pragma unroll
        for (int i = 0; i < 2; i++) {
            #pragma unroll
            for (int r = 0; r < 4; r++) {
                int t = t0 + w * 32 + i * 16 + (l >> 4) * 4 + r;
                float pv[4];
                float rmax = -1e30f;
                #pragma unroll
                for (int j = 0; j < 4; j++) {
                    int s = s0 + j * 16 + (l & 15);
                    float v = sa[i][j][r] * 0.125f;
                    v = (s <= t) ? v : -1e30f;
                    pv[j] = v;
                    rmax = fmaxf(rmax, v);
                }
                #pragma unroll
                for (int msk = 1; msk < 16; msk <<= 1)
                    rmax = fmaxf(rmax, __shfl_xor(rmax, msk));
                float mo = mrow[i][r];
                float mn = fmaxf(mo, rmax);
                float fac = __expf(mo - mn);
                float ls = 0.f;
                int prow = w * 32 + i * 16 + (l >> 4) * 4 + r;
                #pragma unroll
                for (int j = 0; j < 4; j++) {
                    float e = __expf(pv[j] - mn);
                    ls += e;
                    int cb = (j * 32 + (l & 15) * 2) ^ ((prow & 7) << 4);
                    *(__hip_bfloat16*)((char*)Ps + prow * 128 + cb) = __float2bfloat16(e);
                }
                #pragma unroll
                for (int msk = 1; msk < 16; msk <<= 1)
                    ls += __shfl_xor(ls, msk);
                mrow[i][r] = mn;
                lrow[i][r] = lrow[i][r] * fac + ls;
                #pragma unroll
                for (int jd = 0; jd < 4; jd++)
                    acc_o[i][jd][r] *= fac;
            }
        }

        #pragma unroll
        for (int ks = 0; ks < 2; ks++) {
            bf16x8 pa[2], vf[4];
            #pragma unroll
            for (int i = 0; i < 2; i++) {
                int row = w * 32 + i * 16 + (l & 15);
                int cb = (ks * 64 + (l >> 4) * 16) ^ ((row & 7) << 4);
                pa[i] = *(const bf16x8*)((const char*)Ps + row * 128 + cb);
            }
            #pragma unroll
            for (int jd = 0; jd < 4; jd++) {
                int row = jd * 16 + (l & 15);
                int cb = (ks * 64 + (l >> 4) * 16) ^ ((row & 7) << 4);
                vf[jd] = *(const bf16x8*)((const char*)Vs[p] + row * 128 + cb);
            }
            #pragma unroll
            for (int i = 0; i < 2; i++)
                #pragma unroll
                for (int jd = 0; jd < 4; jd++)
                    acc_o[i][jd] = __builtin_amdgcn_mfma_f32_16x16x32_bf16(pa[i], vf[jd], acc_o[i][jd], 0, 0, 0);
        }
        p ^= 1;
    }

    int b = blockIdx.z, hh = blockIdx.y;
    #pragma unroll
    for (int i = 0; i < 2; i++) {
        #pragma unroll
        for (int r = 0; r < 4; r++) {
            float inv = 1.f / lrow[i][r];
            int t = t0 + w * 32 + i * 16 + (l >> 4) * 4 + r;
            #pragma unroll
            for (int jd = 0; jd < 4; jd++) {
                int d = jd * 16 + (l & 15);
                oc[((size_t)(b * TT + t)) * CC + hh * DD + d] =
                    __float2bfloat16(acc_o[i][jd][r] * inv);
            }
        }
    }
}

// ---------------- h = LN(h + t); writes f32 h and bf16 hb
__global__ __launch_bounds__(256) void resid_ln(float* __restrict__ h,
                                                const float* __restrict__ t,
                                                const float* __restrict__ g,
                                                const float* __restrict__ bta,
                                                __hip_bfloat16* __restrict__ hb) {
    int row = blockIdx.x;
    int tid = threadIdx.x;
    __shared__ float red[256];
    float x[3];
    float s = 0.f;
    #pragma unroll
    for (int i = 0; i < 3; i++) {
        int c = tid + i * 256;
        x[i] = h[(size_t)row * CC + c] + t[(size_t)row * CC + c];
        s += x[i];
    }
    red[tid] = s; __syncthreads();
    for (int off = 128; off > 0; off >>= 1) {
        if (tid < off) red[tid] += red[tid + off];
        __syncthreads();
    }
    float mean = red[0] * (1.f / CC); __syncthreads();
    float s2 = 0.f;
    #pragma unroll
    for (int i = 0; i < 3; i++) { float dd = x[i] - mean; s2 += dd * dd; }
    red[tid] = s2; __syncthreads();
    for (int off = 128; off > 0; off >>= 1) {
        if (tid < off) red[tid] += red[tid + off];
        __syncthreads();
    }
    float inv = rsqrtf(red[0] * (1.f / CC) + 1e-5f);
    #pragma unroll
    for (int i = 0; i < 3; i++) {
        int c = tid + i * 256;
        float o = (x[i] - mean) * inv * g[c] + bta[c];
        h[(size_t)row * CC + c] = o;
        hb[(size_t)row * CC + c] = __float2bfloat16(o);
    }
}

__global__ __launch_bounds__(256) void loss_reduce(const float* __restrict__ rl,
                                                   float* __restrict__ out) {
    int tid = threadIdx.x;
    __shared__ float red[256];
    float s = 0.f;
    for (int i = tid; i < MROWS; i += 256) s += rl[i];
    red[tid] = s; __syncthreads();
    for (int off = 128; off > 0; off >>= 1) {
        if (tid < off) red[tid] += red[tid + off];
        __syncthreads();
    }
    if (tid == 0) out[0] = red[0] * (1.f / MROWS);
}

extern "C" void kernel_launch(void* const* d_in, const int* in_sizes, int n_in,
                              void* d_out, int out_size, void* d_ws, size_t ws_size,
                              hipStream_t stream) {
    const int*   x     = (const int*)d_in[0];
    const int*   y     = (const int*)d_in[1];
    const float* tok   = (const float*)d_in[2];
    const float* pos   = (const float*)d_in[3];
    const float* Wk    = (const float*)d_in[4];
    const float* Wq    = (const float*)d_in[5];
    const float* Wv    = (const float*)d_in[6];
    const float* Wproj = (const float*)d_in[7];
    const float* bproj = (const float*)d_in[8];
    const float* ln1g  = (const float*)d_in[9];
    const float* ln1b  = (const float*)d_in[10];
    const float* W1    = (const float*)d_in[11];
    const float* b1    = (const float*)d_in[12];
    const float* W2    = (const float*)d_in[13];
    const float* b2    = (const float*)d_in[14];
    const float* ln2g  = (const float*)d_in[15];
    const float* ln2b  = (const float*)d_in[16];
    const float* Wlm   = (const float*)d_in[17];
    const float* blm   = (const float*)d_in[18];

    float* logits = (float*)d_out;
    float* lossp  = (float*)d_out + ((size_t)out_size - 1);

    char* p = (char*)d_ws;
    auto alloc = [&](size_t bytes) { char* r = p; p += (bytes + 255) & ~255ULL; return r; };
    const size_t S_HC = (size_t)MROWS * CC;

    float* h    = (float*)alloc(S_HC * 4);
    float* tmpf = (float*)alloc(S_HC * 4);
    float* rl   = (float*)alloc(MROWS * 4);
    float* pm   = (float*)alloc((size_t)MROWS * NPART * 4);
    float* ps   = (float*)alloc((size_t)MROWS * NPART * 4);
    __hip_bfloat16* kbb  = (__hip_bfloat16*)alloc(S_HC * 2);
    __hip_bfloat16* qbb  = (__hip_bfloat16*)alloc(S_HC * 2);
    __hip_bfloat16* vtb  = (__hip_bfloat16*)alloc(S_HC * 2);
    __hip_bfloat16* hb   = (__hip_bfloat16*)alloc(S_HC * 2);
    __hip_bfloat16* ocb  = (__hip_bfloat16*)alloc(S_HC * 2);
    __hip_bfloat16* ff1b = (__hip_bfloat16*)alloc((size_t)MROWS * FFH * 2);
    __hip_bfloat16* kT   = (__hip_bfloat16*)alloc((size_t)LL * CC * CC * 2);
    __hip_bfloat16* qT   = (__hip_bfloat16*)alloc((size_t)LL * CC * CC * 2);
    __hip_bfloat16* vT   = (__hip_bfloat16*)alloc((size_t)LL * CC * CC * 2);
    __hip_bfloat16* pT   = (__hip_bfloat16*)alloc((size_t)LL * CC * CC * 2);
    __hip_bfloat16* w1T  = (__hip_bfloat16*)alloc((size_t)LL * CC * FFH * 2);
    __hip_bfloat16* w2T  = (__hip_bfloat16*)alloc((size_t)LL * FFH * CC * 2);
    __hip_bfloat16* lmT  = (__hip_bfloat16*)alloc((size_t)VPAD2 * CC * 2);

    dim3 blk(256);

    cvtT_qkv<<<dim3(24, 2, 3 * 144), blk, 0, stream>>>(Wk, Wq, Wv, kT, qT, vT);
    cvtT_mat<<<dim3(24, 24, LL), blk, 0, stream>>>(Wproj, pT, CC, CC,
                                                   (size_t)CC * CC, (size_t)CC * CC);
    cvtT_mat<<<dim3(96, 24, LL), blk, 0, stream>>>(W1, w1T, CC, FFH,
                                                   (size_t)CC * FFH, (size_t)FFH * CC);
    cvtT_mat<<<dim3(24, 96, LL), blk, 0, stream>>>(W2, w2T, FFH, CC,
                                                   (size_t)FFH * CC, (size_t)CC * FFH);
    cvtT_mat<<<dim3(VPAD2 / 32, 24, 1), blk, 0, stream>>>(Wlm, lmT, CC, VV, 0, 0);

    embed_kernel<<<dim3((MROWS * CC + 255) / 256), blk, 0, stream>>>(x, tok, pos, h, hb);

    for (int l = 0; l < LL; l++) {
        const __hip_bfloat16* kT_l = kT + (size_t)l * CC * CC;
        const __hip_bfloat16* qT_l = qT + (size_t)l * CC * CC;
        const __hip_bfloat16* vT_l = vT + (size_t)l * CC * CC;
        const __hip_bfloat16* pT_l = pT + (size_t)l * CC * CC;
        const __hip_bfloat16* w1T_l = w1T + (size_t)l * CC * FFH;
        const __hip_bfloat16* w2T_l = w2T + (size_t)l * FFH * CC;

        gemm_qkv_mfma<<<dim3(CC / 128, MROWS / 128, 3), blk, 0, stream>>>(
            hb, kT_l, qT_l, vT_l, kbb, qbb, vtb);
        attn_mfma<<<dim3(TT / QBLK, HH, BB), blk, 0, stream>>>(kbb, qbb, vtb, ocb);
        gemm_mfma<<<dim3(CC / 128, MROWS / 128), blk, 0, stream>>>(
            ocb, pT_l, bproj + (size_t)l * CC, tmpf, (__hip_bfloat16*)nullptr,
            MROWS, CC, CC, 0);
        resid_ln<<<dim3(MROWS), blk, 0, stream>>>(h, tmpf, ln1g + (size_t)l * CC,
                                                  ln1b + (size_t)l * CC, hb);
        gemm_mfma<<<dim3(FFH / 128, MROWS / 128), blk, 0, stream>>>(
            hb, w1T_l, b1 + (size_t)l * FFH, (float*)nullptr, ff1b,
            MROWS, FFH, CC, 1);
        gemm_mfma<<<dim3(CC / 128, MROWS / 128), blk, 0, stream>>>(
            ff1b, w2T_l, b2 + (size_t)l * CC, tmpf, (__hip_bfloat16*)nullptr,
            MROWS, CC, FFH, 0);
        resid_ln<<<dim3(MROWS), blk, 0, stream>>>(h, tmpf, ln2g + (size_t)l * CC,
                                                  ln2b + (size_t)l * CC, hb);
    }

    lm_head_mfma256<<<dim3(MROWS / 256, VPAD2 / 256), dim3(512), 0, stream>>>(
        hb, lmT, blm, logits, pm, ps);
    nll_combine<<<dim3(MROWS), blk, 0, stream>>>(pm, ps, logits, y, rl);
    loss_reduce<<<dim3(1), blk, 0, stream>>>(rl, lossp);
}

// Round 10
// 3287.526 us; speedup vs baseline: 16.2542x; 1.0147x over previous
//
#include <hip/hip_runtime.h>
#include <hip/hip_bf16.h>
#include <math.h>

#define BB 4
#define TT 1024
#define VV 50257
#define VPAD2 50432
#define CC 768
#define HH 12
#define DD 64
#define LL 12
#define FFH 3072
#define MROWS (BB*TT)   // 4096
#define QBLK 128
#define KVBLK 64
#define NPART (VPAD2 / 64)        // 788 partials per row

typedef __bf16 bf16x8 __attribute__((ext_vector_type(8)));
typedef float  f32x4  __attribute__((ext_vector_type(4)));
typedef unsigned int u32;
#define AS1 __attribute__((address_space(1)))
#define AS3 __attribute__((address_space(3)))

static __device__ __forceinline__ void gload_lds16(const void* g, void* l) {
    __builtin_amdgcn_global_load_lds((const AS1 u32*)g, (AS3 u32*)l, 16, 0, 0);
}

// stage one 128x64 bf16 tile pair into linear LDS, source pre-swizzled (4 waves)
static __device__ __forceinline__ void stage_tile(const __hip_bfloat16* __restrict__ A,
                                                  const __hip_bfloat16* __restrict__ Bt,
                                                  int Kld, int k0, int bm, int bn,
                                                  int w, int l, char* As, char* Bs) {
    #pragma unroll
    for (int it = 0; it < 4; it++) {
        int chunk = w * 4 + it;
        int o = chunk * 1024 + l * 16;
        int row = o >> 7;
        int cb = (o & 127) ^ ((row & 7) << 4);
        gload_lds16(A + (size_t)(bm + row) * Kld + k0 + (cb >> 1), As + chunk * 1024);
        gload_lds16(Bt + (size_t)(bn + row) * Kld + k0 + (cb >> 1), Bs + chunk * 1024);
    }
}

// stage one 256x64 bf16 tile pair into linear LDS (8 waves / 512 threads)
static __device__ __forceinline__ void stage_tile256(const __hip_bfloat16* __restrict__ A,
                                                     const __hip_bfloat16* __restrict__ Bt,
                                                     int Kld, int k0, int bm, int bn,
                                                     int w, int l, char* As, char* Bs) {
    #pragma unroll
    for (int it = 0; it < 4; it++) {
        int chunk = w * 4 + it;
        int o = chunk * 1024 + l * 16;
        int row = o >> 7;
        int cb = (o & 127) ^ ((row & 7) << 4);
        gload_lds16(A + (size_t)(bm + row) * Kld + k0 + (cb >> 1), As + chunk * 1024);
        gload_lds16(Bt + (size_t)(bn + row) * Kld + k0 + (cb >> 1), Bs + chunk * 1024);
    }
}

// ---------------- embedding
__global__ void embed_kernel(const int* __restrict__ x, const float* __restrict__ tok,
                             const float* __restrict__ pos, float* __restrict__ h,
                             __hip_bfloat16* __restrict__ hb) {
    int idx = blockIdx.x * 256 + threadIdx.x;
    if (idx >= MROWS * CC) return;
    int row = idx / CC, c = idx - row * CC;
    int id = x[row];
    float v = tok[(size_t)id * CC + c] + pos[(size_t)id * CC + c];
    h[idx] = v;
    hb[idx] = __float2bfloat16(v);
}

// ---------------- convert + transpose weights
__global__ __launch_bounds__(256) void cvtT_mat(const float* __restrict__ in,
                                                __hip_bfloat16* __restrict__ out,
                                                int K, int Nin,
                                                size_t ibs, size_t obs) {
    __shared__ float t[32][33];
    const float* ip = in + blockIdx.z * ibs;
    __hip_bfloat16* op = out + blockIdx.z * obs;
    int n0 = blockIdx.x * 32, k0 = blockIdx.y * 32;
    int tx = threadIdx.x & 31, ty = threadIdx.x >> 5;
    #pragma unroll
    for (int i = 0; i < 4; i++) {
        int k = k0 + ty + i * 8, n = n0 + tx;
        t[ty + i * 8][tx] = (n < Nin) ? ip[(size_t)k * Nin + n] : 0.f;
    }
    __syncthreads();
    #pragma unroll
    for (int i = 0; i < 4; i++) {
        int n = n0 + ty + i * 8, k = k0 + tx;
        op[(size_t)n * K + k] = __float2bfloat16(t[tx][ty + i * 8]);
    }
}

__global__ __launch_bounds__(256) void cvtT_qkv(const float* __restrict__ Wk,
                                                const float* __restrict__ Wq,
                                                const float* __restrict__ Wv,
                                                __hip_bfloat16* __restrict__ kT,
                                                __hip_bfloat16* __restrict__ qT,
                                                __hip_bfloat16* __restrict__ vT) {
    int z = blockIdx.z;
    int tensor = z / 144, lh = z % 144;
    int l = lh / HH, hh = lh % HH;
    const float* in = (tensor == 0 ? Wk : tensor == 1 ? Wq : Wv) + (size_t)lh * CC * DD;
    __hip_bfloat16* out = (tensor == 0 ? kT : tensor == 1 ? qT : vT)
                          + ((size_t)l * CC + hh * DD) * CC;
    __shared__ float t[32][33];
    int c0 = blockIdx.x * 32, d0 = blockIdx.y * 32;
    int tx = threadIdx.x & 31, ty = threadIdx.x >> 5;
    #pragma unroll
    for (int i = 0; i < 4; i++)
        t[ty + i * 8][tx] = in[(size_t)(c0 + ty + i * 8) * DD + d0 + tx];
    __syncthreads();
    #pragma unroll
    for (int i = 0; i < 4; i++)
        out[(size_t)(d0 + ty + i * 8) * CC + c0 + tx] = __float2bfloat16(t[tx][ty + i * 8]);
}

// ---------------- MFMA GEMM 128x128 dbuf + LDS-staged coalesced epilogue.
__global__ __launch_bounds__(256) void gemm_mfma(const __hip_bfloat16* __restrict__ A,
                                                 const __hip_bfloat16* __restrict__ Bt,
                                                 const float* __restrict__ bias,
                                                 float* __restrict__ Cf,
                                                 __hip_bfloat16* __restrict__ Cb,
                                                 int M, int N, int K, int relu) {
    __shared__ __align__(16) char smem[65536];
    int tid = threadIdx.x;
    int l = tid & 63, w = tid >> 6;
    int wr = w >> 1, wc = w & 1;
    int bm = blockIdx.y * 128, bn = blockIdx.x * 128;

    f32x4 acc[4][4] = {};

    stage_tile(A, Bt, K, 0, bm, bn, w, l, smem, smem + 32768);
    int p = 0;
    for (int k0 = 0; k0 < K; k0 += 64) {
        __syncthreads();
        if (k0 + 64 < K)
            stage_tile(A, Bt, K, k0 + 64, bm, bn, w, l,
                       smem + (p ^ 1) * 16384, smem + 32768 + (p ^ 1) * 16384);
        const char* Ab = smem + p * 16384;
        const char* Bb = smem + 32768 + p * 16384;
        #pragma unroll
        for (int ks = 0; ks < 2; ks++) {
            bf16x8 af[4], bfr[4];
            #pragma unroll
            for (int i = 0; i < 4; i++) {
                int row = wr * 64 + i * 16 + (l & 15);
                int cb = (ks * 64 + (l >> 4) * 16) ^ ((row & 7) << 4);
                af[i] = *(const bf16x8*)(Ab + row * 128 + cb);
            }
            #pragma unroll
            for (int j = 0; j < 4; j++) {
                int row = wc * 64 + j * 16 + (l & 15);
                int cb = (ks * 64 + (l >> 4) * 16) ^ ((row & 7) << 4);
                bfr[j] = *(const bf16x8*)(Bb + row * 128 + cb);
            }
            #pragma unroll
            for (int i = 0; i < 4; i++)
                #pragma unroll
                for (int j = 0; j < 4; j++)
                    acc[i][j] = __builtin_amdgcn_mfma_f32_16x16x32_bf16(af[i], bfr[j], acc[i][j], 0, 0, 0);
        }
        p ^= 1;
    }

    if (Cb) {
        __hip_bfloat16* ebh = (__hip_bfloat16*)smem;
        __syncthreads();
        #pragma unroll
        for (int i = 0; i < 4; i++) {
            #pragma unroll
            for (int j = 0; j < 4; j++) {
                int colt = wc * 64 + j * 16 + (l & 15);
                float bv = bias ? bias[bn + colt] : 0.f;
                #pragma unroll
                for (int r = 0; r < 4; r++) {
                    int rowc = wr * 64 + i * 16 + (l >> 4) * 4 + r;
                    float v = acc[i][j][r] + bv;
                    if (relu) v = fmaxf(v, 0.f);
                    ebh[rowc * 136 + colt] = __float2bfloat16(v);
                }
            }
        }
        __syncthreads();
        #pragma unroll
        for (int pass = 0; pass < 8; pass++) {
            int idx = pass * 256 + tid;
            int rowc = idx >> 4, colq = idx & 15;
            *(bf16x8*)&Cb[(size_t)(bm + rowc) * N + bn + colq * 8] =
                *(const bf16x8*)&ebh[rowc * 136 + colq * 8];
        }
    } else {
        float* eb = (float*)smem;
        #pragma unroll
        for (int c = 0; c < 2; c++) {
            __syncthreads();
            if (wr == c) {
                #pragma unroll
                for (int i = 0; i < 4; i++) {
                    #pragma unroll
                    for (int j = 0; j < 4; j++) {
                        int colt = wc * 64 + j * 16 + (l & 15);
                        float bv = bias ? bias[bn + colt] : 0.f;
                        #pragma unroll
                        for (int r = 0; r < 4; r++) {
                            int rowc = i * 16 + (l >> 4) * 4 + r;
                            float v = acc[i][j][r] + bv;
                            if (relu) v = fmaxf(v, 0.f);
                            eb[rowc * 132 + colt] = v;
                        }
                    }
                }
            }
            __syncthreads();
            #pragma unroll
            for (int pass = 0; pass < 8; pass++) {
                int idx = pass * 256 + tid;
                int rowc = idx >> 5, colq = idx & 31;
                *(f32x4*)&Cf[(size_t)(bm + c * 64 + rowc) * N + bn + colq * 4] =
                    *(const f32x4*)&eb[rowc * 132 + colq * 4];
            }
        }
    }
}

// ---------------- LM head: 256x256, 8 waves, BK=64 dbuf, fused LSE,
// barrier-free per-wave staged epilogue (private LDS slices, ping-pong).
__global__ __launch_bounds__(512) void lm_head_mfma256(const __hip_bfloat16* __restrict__ A,
                                                       const __hip_bfloat16* __restrict__ Bt,
                                                       const float* __restrict__ bias,
                                                       float* __restrict__ Cf,
                                                       float* __restrict__ pm,
                                                       float* __restrict__ ps) {
    __shared__ __align__(16) char smem[131072];  // K-loop: As[2] 2x32K @0, Bs[2] @65536
    int tid = threadIdx.x;
    int l = tid & 63, w = tid >> 6;
    int wr = w >> 2, wc = w & 3;
    int bm = blockIdx.x * 256, bn = blockIdx.y * 256;   // row-fastest

    f32x4 acc[8][4] = {};

    stage_tile256(A, Bt, CC, 0, bm, bn, w, l, smem, smem + 65536);
    int p = 0;
    for (int k0 = 0; k0 < CC; k0 += 64) {
        __syncthreads();
        if (k0 + 64 < CC)
            stage_tile256(A, Bt, CC, k0 + 64, bm, bn, w, l,
                          smem + (p ^ 1) * 32768, smem + 65536 + (p ^ 1) * 32768);
        const char* Ab = smem + p * 32768;
        const char* Bb = smem + 65536 + p * 32768;
        #pragma unroll
        for (int ks = 0; ks < 2; ks++) {
            bf16x8 af[8], bfr[4];
            #pragma unroll
            for (int i = 0; i < 8; i++) {
                int row = wr * 128 + i * 16 + (l & 15);
                int cb = (ks * 64 + (l >> 4) * 16) ^ ((row & 7) << 4);
                af[i] = *(const bf16x8*)(Ab + row * 128 + cb);
            }
            #pragma unroll
            for (int j = 0; j < 4; j++) {
                int row = wc * 64 + j * 16 + (l & 15);
                int cb = (ks * 64 + (l >> 4) * 16) ^ ((row & 7) << 4);
                bfr[j] = *(const bf16x8*)(Bb + row * 128 + cb);
            }
            #pragma unroll
            for (int i = 0; i < 8; i++)
                #pragma unroll
                for (int j = 0; j < 4; j++)
                    acc[i][j] = __builtin_amdgcn_mfma_f32_16x16x32_bf16(af[i], bfr[j], acc[i][j], 0, 0, 0);
        }
        p ^= 1;
    }

    // fold bias
    #pragma unroll
    for (int j = 0; j < 4; j++) {
        int col = bn + wc * 64 + j * 16 + (l & 15);
        float bv = (col < VV) ? bias[col] : 0.f;
        #pragma unroll
        for (int i = 0; i < 8; i++)
            #pragma unroll
            for (int r = 0; r < 4; r++)
                acc[i][j][r] += bv;
    }

    // LSE partials (registers + 16-lane shfl groups)
    int pidx = blockIdx.y * 4 + wc;
    #pragma unroll
    for (int i = 0; i < 8; i++) {
        int row = bm + wr * 128 + i * 16 + (l >> 4) * 4;
        #pragma unroll
        for (int r = 0; r < 4; r++) {
            float pv[4];
            float rmax = -1e30f;
            #pragma unroll
            for (int j = 0; j < 4; j++) {
                int col = bn + wc * 64 + j * 16 + (l & 15);
                float v = (col < VV) ? acc[i][j][r] : -1e30f;
                pv[j] = v;
                rmax = fmaxf(rmax, v);
            }
            #pragma unroll
            for (int msk = 1; msk < 16; msk <<= 1)
                rmax = fmaxf(rmax, __shfl_xor(rmax, msk));
            float s = 0.f;
            #pragma unroll
            for (int j = 0; j < 4; j++) s += __expf(pv[j] - rmax);
            #pragma unroll
            for (int msk = 1; msk < 16; msk <<= 1)
                s += __shfl_xor(s, msk);
            if ((l & 15) == 0) {
                pm[(size_t)(row + r) * NPART + pidx] = rmax;
                ps[(size_t)(row + r) * NPART + pidx] = s;
            }
        }
    }

    // barrier-free per-wave epilogue: each wave stages its own 16x64 fragment-row
    // into a private slice (ping-pong x2), reads back full rows, 256B stores.
    __syncthreads();   // retire all K-loop LDS reads before reuse
    float* eb0 = (float*)smem + (size_t)(w * 2 + 0) * (16 * 68);
    float* eb1 = (float*)smem + (size_t)(w * 2 + 1) * (16 * 68);
    int colg = bn + wc * 64 + l;
    bool valid = colg < VV;
    #pragma unroll
    for (int i = 0; i < 8; i++) {
        float* eb = (i & 1) ? eb1 : eb0;
        #pragma unroll
        for (int j = 0; j < 4; j++) {
            int colt = j * 16 + (l & 15);
            #pragma unroll
            for (int r = 0; r < 4; r++) {
                int rowc = (l >> 4) * 4 + r;
                eb[rowc * 68 + colt] = acc[i][j][r];
            }
        }
        int rowbase = bm + wr * 128 + i * 16;
        #pragma unroll
        for (int pp = 0; pp < 16; pp++) {
            float v = eb[pp * 68 + l];
            if (valid) Cf[(size_t)(rowbase + pp) * VV + colg] = v;
        }
    }
}

// ---------------- combine LSE partials -> per-row NLL
__global__ __launch_bounds__(256) void nll_combine(const float* __restrict__ pm,
                                                   const float* __restrict__ ps,
                                                   const float* __restrict__ logits,
                                                   const int* __restrict__ y,
                                                   float* __restrict__ rl) {
    int m = blockIdx.x, tid = threadIdx.x;
    __shared__ float rm[256], rs[256];
    float mt = -1e30f, st = 0.f;
    for (int i = tid; i < NPART; i += 256) {
        float mi = pm[(size_t)m * NPART + i];
        float si = ps[(size_t)m * NPART + i];
        float mn = fmaxf(mt, mi);
        st = st * __expf(mt - mn) + si * __expf(mi - mn);
        mt = mn;
    }
    rm[tid] = mt; rs[tid] = st; __syncthreads();
    for (int off = 128; off > 0; off >>= 1) {
        if (tid < off) {
            float ma = rm[tid], mb = rm[tid + off];
            float mn = fmaxf(ma, mb);
            rs[tid] = rs[tid] * __expf(ma - mn) + rs[tid + off] * __expf(mb - mn);
            rm[tid] = mn;
        }
        __syncthreads();
    }
    if (tid == 0)
        rl[m] = logf(rs[0]) + rm[0] - logits[(size_t)m * VV + y[m]];
}

// ---------------- QKV MFMA GEMM (dbuf): LDS-staged coalesced epilogue.
__global__ __launch_bounds__(256) void gemm_qkv_mfma(const __hip_bfloat16* __restrict__ A,
                                                     const __hip_bfloat16* __restrict__ kT,
                                                     const __hip_bfloat16* __restrict__ qT,
                                                     const __hip_bfloat16* __restrict__ vT,
                                                     __hip_bfloat16* __restrict__ ko,
                                                     __hip_bfloat16* __restrict__ qo,
                                                     __hip_bfloat16* __restrict__ vto) {
    const __hip_bfloat16* Bt = (blockIdx.z == 0) ? kT : (blockIdx.z == 1) ? qT : vT;
    __shared__ __align__(16) char smem[65536];
    int tid = threadIdx.x;
    int l = tid & 63, w = tid >> 6;
    int wr = w >> 1, wc = w & 1;
    int bm = blockIdx.y * 128, bn = blockIdx.x * 128;

    f32x4 acc[4][4] = {};

    stage_tile(A, Bt, CC, 0, bm, bn, w, l, smem, smem + 32768);
    int p = 0;
    for (int k0 = 0; k0 < CC; k0 += 64) {
        __syncthreads();
        if (k0 + 64 < CC)
            stage_tile(A, Bt, CC, k0 + 64, bm, bn, w, l,
                       smem + (p ^ 1) * 16384, smem + 32768 + (p ^ 1) * 16384);
        const char* Ab = smem + p * 16384;
        const char* Bb = smem + 32768 + p * 16384;
        #pragma unroll
        for (int ks = 0; ks < 2; ks++) {
            bf16x8 af[4], bfr[4];
            #pragma unroll
            for (int i = 0; i < 4; i++) {
                int row = wr * 64 + i * 16 + (l & 15);
                int cb = (ks * 64 + (l >> 4) * 16) ^ ((row & 7) << 4);
                af[i] = *(const bf16x8*)(Ab + row * 128 + cb);
            }
            #pragma unroll
            for (int j = 0; j < 4; j++) {
                int row = wc * 64 + j * 16 + (l & 15);
                int cb = (ks * 64 + (l >> 4) * 16) ^ ((row & 7) << 4);
                bfr[j] = *(const bf16x8*)(Bb + row * 128 + cb);
            }
            #pragma unroll
            for (int i = 0; i < 4; i++)
                #pragma unroll
                for (int j = 0; j < 4; j++)
                    acc[i][j] = __builtin_amdgcn_mfma_f32_16x16x32_bf16(af[i], bfr[j], acc[i][j], 0, 0, 0);
        }
        p ^= 1;
    }

    int zz = blockIdx.z;
    int b = bm >> 10, tbase = bm & 1023;
    __hip_bfloat16* eb = (__hip_bfloat16*)smem;
    __syncthreads();   // K-loop LDS reads retired; smem reusable
    if (zz != 2) {
        #pragma unroll
        for (int i = 0; i < 4; i++)
            #pragma unroll
            for (int j = 0; j < 4; j++) {
                int colt = wc * 64 + j * 16 + (l & 15);
                #pragma unroll
                for (int r = 0; r < 4; r++) {
                    int rowc = wr * 64 + i * 16 + (l >> 4) * 4 + r;
                    eb[rowc * 136 + colt] = __float2bfloat16(acc[i][j][r]);
                }
            }
        __syncthreads();
        __hip_bfloat16* O = (zz == 0) ? ko : qo;
        #pragma unroll
        for (int pass = 0; pass < 8; pass++) {
            int idx = pass * 256 + tid;
            int rowc = idx >> 4, colq = idx & 15;
            int head = (bn >> 6) + (colq >> 3);
            int d = (colq & 7) * 8;
            int t = tbase + rowc;
            *(bf16x8*)&O[(((size_t)(b * HH + head)) * TT + t) * DD + d] =
                *(const bf16x8*)&eb[rowc * 136 + colq * 8];
        }
    } else {
        #pragma unroll
        for (int i = 0; i < 4; i++)
            #pragma unroll
            for (int j = 0; j < 4; j++) {
                int colt = wc * 64 + j * 16 + (l & 15);
                #pragma unroll
                for (int r = 0; r < 4; r++) {
                    int rowc = wr * 64 + i * 16 + (l >> 4) * 4 + r;
                    eb[colt * 136 + rowc] = __float2bfloat16(acc[i][j][r]);
                }
            }
        __syncthreads();
        #pragma unroll
        for (int pass = 0; pass < 8; pass++) {
            int idx = pass * 256 + tid;
            int line = idx >> 4, tq = idx & 15;
            int head = (bn >> 6) + (line >> 6);
            int d = line & 63;
            *(bf16x8*)&vto[(((size_t)(b * HH + head)) * DD + d) * TT + tbase + tq * 8] =
                *(const bf16x8*)&eb[line * 136 + tq * 8];
        }
    }
}

// ---------------- MFMA flash attention (quirk: k plays query role)
__global__ __launch_bounds__(256) void attn_mfma(const __hip_bfloat16* __restrict__ kq,
                                                 const __hip_bfloat16* __restrict__ qk,
                                                 const __hip_bfloat16* __restrict__ vt,
                                                 __hip_bfloat16* __restrict__ oc) {
    __shared__ __hip_bfloat16 Qs[2][KVBLK * 64];
    __shared__ __hip_bfloat16 Vs[2][64 * KVBLK];
    __shared__ __hip_bfloat16 Ps[QBLK * KVBLK];
    int tid = threadIdx.x;
    int l = tid & 63, w = tid >> 6;
    int t0 = blockIdx.x * QBLK;
    size_t bh = (size_t)(blockIdx.z * HH + blockIdx.y);
    const __hip_bfloat16* kqp = kq + bh * TT * DD;
    const __hip_bfloat16* qkp = qk + bh * TT * DD;
    const __hip_bfloat16* vtp = vt + bh * DD * TT;

    bf16x8 af[2][2];
    #pragma unroll
    for (int i = 0; i < 2; i++)
        #pragma unroll
        for (int ks = 0; ks < 2; ks++)
            af[i][ks] = *(const bf16x8*)&kqp[(size_t)(t0 + w * 32 + i * 16 + (l & 15)) * DD
                                             + ks * 32 + (l >> 4) * 8];

    f32x4 acc_o[2][4] = {};
    float mrow[2][4], lrow[2][4];
    #pragma unroll
    for (int i = 0; i < 2; i++)
        #pragma unroll
        for (int r = 0; r < 4; r++) { mrow[i][r] = -1e30f; lrow[i][r] = 0.f; }

    auto stageKV = [&](int pp, int s0) {
        #pragma unroll
        for (int it = 0; it < 2; it++) {
            int chunk = w * 2 + it;
            int o = chunk * 1024 + l * 16;
            int row = o >> 7;
            int cb = (o & 127) ^ ((row & 7) << 4);
            gload_lds16(qkp + (size_t)(s0 + row) * DD + (cb >> 1),
                        (char*)Qs[pp] + chunk * 1024);
            gload_lds16(vtp + (size_t)row * TT + s0 + (cb >> 1),
                        (char*)Vs[pp] + chunk * 1024);
        }
    };

    int nt = (t0 + QBLK) / KVBLK;
    stageKV(0, 0);
    int p = 0;
    for (int ti = 0; ti < nt; ti++) {
        int s0 = ti * KVBLK;
        __syncthreads();
        if (ti + 1 < nt) stageKV(p ^ 1, s0 + KVBLK);

        f32x4 sa[2][4] = {};
        #pragma unroll
        for (int ks = 0; ks < 2; ks++) {
            bf16x8 bfr[4];
            #pragma unroll
            for (int j = 0; j < 4; j++) {
                int row = j * 16 + (l & 15);
                int cb = (ks * 64 + (l >> 4) * 16) ^ ((row & 7) << 4);
                bfr[j] = *(const bf16x8*)((const char*)Qs[p] + row * 128 + cb);
            }
            #pragma unroll
            for (int i = 0; i < 2; i++)
                #pragma unroll
                for (int j = 0; j < 4; j++)
                    sa[i][j] = __builtin_amdgcn_mfma_f32_16x16x32_bf16(af[i][ks], bfr[j], sa[i][j], 0, 0, 0);
        }

        #pragma unroll
        for (int i = 0; i < 2; i++) {
            #pragma unroll
            for (int r = 0; r < 4; r++) {
                int t = t0 + w * 32 + i * 16 + (l >> 4) * 4 + r;
                float pv[4];
                float rmax = -1e30f;
                #pragma unroll
                for (int j = 0; j < 4; j++) {
                    int s = s0 + j * 16 + (l & 15);
                    float v = sa[i][j][r] * 0.125f;
                    v = (s <= t) ? v : -1e30f;
                    pv[j] = v;
                    rmax = fmaxf(rmax, v);
                }
                #pragma unroll
                for (int msk = 1; msk < 16; msk <<= 1)
                    rmax = fmaxf(rmax, __shfl_xor(rmax, msk));
                float mo = mrow[i][r];
                float mn = fmaxf(mo, rmax);
                float fac = __expf(mo - mn);
                float ls = 0.f;
                int prow = w * 32 + i * 16 + (l >> 4) * 4 + r;
                #pragma unroll
                for (int j = 0; j < 4; j++) {
                    float e = __expf(pv[j] - mn);
                    ls += e;
                    int cb = (j * 32 + (l & 15) * 2) ^ ((prow & 7) << 4);
                    *(__hip_bfloat16*)((char*)Ps + prow * 128 + cb) = __float2bfloat16(e);
                }
                #pragma unroll
                for (int msk = 1; msk < 16; msk <<= 1)
                    ls += __shfl_xor(ls, msk);
                mrow[i][r] = mn;
                lrow[i][r] = lrow[i][r] * fac + ls;
                #pragma unroll
                for (int jd = 0; jd < 4; jd++)
                    acc_o[i][jd][r] *= fac;
            }
        }

        #pragma unroll
        for (int ks = 0; ks < 2; ks++) {
            bf16x8 pa[2], vf[4];
            #pragma unroll
            for (int i = 0; i < 2; i++) {
                int row = w * 32 + i * 16 + (l & 15);
                int cb = (ks * 64 + (l >> 4) * 16) ^ ((row & 7) << 4);
                pa[i] = *(const bf16x8*)((const char*)Ps + row * 128 + cb);
            }
            #pragma unroll
            for (int jd = 0; jd < 4; jd++) {
                int row = jd * 16 + (l & 15);
                int cb = (ks * 64 + (l >> 4) * 16) ^ ((row & 7) << 4);
                vf[jd] = *(const bf16x8*)((const char*)Vs[p] + row * 128 + cb);
            }
            #pragma unroll
            for (int i = 0; i < 2; i++)
                #pragma unroll
                for (int jd = 0; jd < 4; jd++)
                    acc_o[i][jd] = __builtin_amdgcn_mfma_f32_16x16x32_bf16(pa[i], vf[jd], acc_o[i][jd], 0, 0, 0);
        }
        p ^= 1;
    }

    int b = blockIdx.z, hh = blockIdx.y;
    #pragma unroll
    for (int i = 0; i < 2; i++) {
        #pragma unroll
        for (int r = 0; r < 4; r++) {
            float inv = 1.f / lrow[i][r];
            int t = t0 + w * 32 + i * 16 + (l >> 4) * 4 + r;
            #pragma unroll
            for (int jd = 0; jd < 4; jd++) {
                int d = jd * 16 + (l & 15);
                oc[((size_t)(b * TT + t)) * CC + hh * DD + d] =
                    __float2bfloat16(acc_o[i][jd][r] * inv);
            }
        }
    }
}

// ---------------- h = LN(h + t); writes f32 h and bf16 hb
__global__ __launch_bounds__(256) void resid_ln(float* __restrict__ h,
                                                const float* __restrict__ t,
                                                const float* __restrict__ g,
                                                const float* __restrict__ bta,
                                                __hip_bfloat16* __restrict__ hb) {
    int row = blockIdx.x;
    int tid = threadIdx.x;
    __shared__ float red[256];
    float x[3];
    float s = 0.f;
    #pragma unroll
    for (int i = 0; i < 3; i++) {
        int c = tid + i * 256;
        x[i] = h[(size_t)row * CC + c] + t[(size_t)row * CC + c];
        s += x[i];
    }
    red[tid] = s; __syncthreads();
    for (int off = 128; off > 0; off >>= 1) {
        if (tid < off) red[tid] += red[tid + off];
        __syncthreads();
    }
    float mean = red[0] * (1.f / CC); __syncthreads();
    float s2 = 0.f;
    #pragma unroll
    for (int i = 0; i < 3; i++) { float dd = x[i] - mean; s2 += dd * dd; }
    red[tid] = s2; __syncthreads();
    for (int off = 128; off > 0; off >>= 1) {
        if (tid < off) red[tid] += red[tid + off];
        __syncthreads();
    }
    float inv = rsqrtf(red[0] * (1.f / CC) + 1e-5f);
    #pragma unroll
    for (int i = 0; i < 3; i++) {
        int c = tid + i * 256;
        float o = (x[i] - mean) * inv * g[c] + bta[c];
        h[(size_t)row * CC + c] = o;
        hb[(size_t)row * CC + c] = __float2bfloat16(o);
    }
}

__global__ __launch_bounds__(256) void loss_reduce(const float* __restrict__ rl,
                                                   float* __restrict__ out) {
    int tid = threadIdx.x;
    __shared__ float red[256];
    float s = 0.f;
    for (int i = tid; i < MROWS; i += 256) s += rl[i];
    red[tid] = s; __syncthreads();
    for (int off = 128; off > 0; off >>= 1) {
        if (tid < off) red[tid] += red[tid + off];
        __syncthreads();
    }
    if (tid == 0) out[0] = red[0] * (1.f / MROWS);
}

extern "C" void kernel_launch(void* const* d_in, const int* in_sizes, int n_in,
                              void* d_out, int out_size, void* d_ws, size_t ws_size,
                              hipStream_t stream) {
    const int*   x     = (const int*)d_in[0];
    const int*   y     = (const int*)d_in[1];
    const float* tok   = (const float*)d_in[2];
    const float* pos   = (const float*)d_in[3];
    const float* Wk    = (const float*)d_in[4];
    const float* Wq    = (const float*)d_in[5];
    const float* Wv    = (const float*)d_in[6];
    const float* Wproj = (const float*)d_in[7];
    const float* bproj = (const float*)d_in[8];
    const float* ln1g  = (const float*)d_in[9];
    const float* ln1b  = (const float*)d_in[10];
    const float* W1    = (const float*)d_in[11];
    const float* b1    = (const float*)d_in[12];
    const float* W2    = (const float*)d_in[13];
    const float* b2    = (const float*)d_in[14];
    const float* ln2g  = (const float*)d_in[15];
    const float* ln2b  = (const float*)d_in[16];
    const float* Wlm   = (const float*)d_in[17];
    const float* blm   = (const float*)d_in[18];

    float* logits = (float*)d_out;
    float* lossp  = (float*)d_out + ((size_t)out_size - 1);

    char* p = (char*)d_ws;
    auto alloc = [&](size_t bytes) { char* r = p; p += (bytes + 255) & ~255ULL; return r; };
    const size_t S_HC = (size_t)MROWS * CC;

    float* h    = (float*)alloc(S_HC * 4);
    float* tmpf = (float*)alloc(S_HC * 4);
    float* rl   = (float*)alloc(MROWS * 4);
    float* pm   = (float*)alloc((size_t)MROWS * NPART * 4);
    float* ps   = (float*)alloc((size_t)MROWS * NPART * 4);
    __hip_bfloat16* kbb  = (__hip_bfloat16*)alloc(S_HC * 2);
    __hip_bfloat16* qbb  = (__hip_bfloat16*)alloc(S_HC * 2);
    __hip_bfloat16* vtb  = (__hip_bfloat16*)alloc(S_HC * 2);
    __hip_bfloat16* hb   = (__hip_bfloat16*)alloc(S_HC * 2);
    __hip_bfloat16* ocb  = (__hip_bfloat16*)alloc(S_HC * 2);
    __hip_bfloat16* ff1b = (__hip_bfloat16*)alloc((size_t)MROWS * FFH * 2);
    __hip_bfloat16* kT   = (__hip_bfloat16*)alloc((size_t)LL * CC * CC * 2);
    __hip_bfloat16* qT   = (__hip_bfloat16*)alloc((size_t)LL * CC * CC * 2);
    __hip_bfloat16* vT   = (__hip_bfloat16*)alloc((size_t)LL * CC * CC * 2);
    __hip_bfloat16* pT   = (__hip_bfloat16*)alloc((size_t)LL * CC * CC * 2);
    __hip_bfloat16* w1T  = (__hip_bfloat16*)alloc((size_t)LL * CC * FFH * 2);
    __hip_bfloat16* w2T  = (__hip_bfloat16*)alloc((size_t)LL * FFH * CC * 2);
    __hip_bfloat16* lmT  = (__hip_bfloat16*)alloc((size_t)VPAD2 * CC * 2);

    dim3 blk(256);

    cvtT_qkv<<<dim3(24, 2, 3 * 144), blk, 0, stream>>>(Wk, Wq, Wv, kT, qT, vT);
    cvtT_mat<<<dim3(24, 24, LL), blk, 0, stream>>>(Wproj, pT, CC, CC,
                                                   (size_t)CC * CC, (size_t)CC * CC);
    cvtT_mat<<<dim3(96, 24, LL), blk, 0, stream>>>(W1, w1T, CC, FFH,
                                                   (size_t)CC * FFH, (size_t)FFH * CC);
    cvtT_mat<<<dim3(24, 96, LL), blk, 0, stream>>>(W2, w2T, FFH, CC,
                                                   (size_t)FFH * CC, (size_t)CC * FFH);
    cvtT_mat<<<dim3(VPAD2 / 32, 24, 1), blk, 0, stream>>>(Wlm, lmT, CC, VV, 0, 0);

    embed_kernel<<<dim3((MROWS * CC + 255) / 256), blk, 0, stream>>>(x, tok, pos, h, hb);

    for (int l = 0; l < LL; l++) {
        const __hip_bfloat16* kT_l = kT + (size_t)l * CC * CC;
        const __hip_bfloat16* qT_l = qT + (size_t)l * CC * CC;
        const __hip_bfloat16* vT_l = vT + (size_t)l * CC * CC;
        const __hip_bfloat16* pT_l = pT + (size_t)l * CC * CC;
        const __hip_bfloat16* w1T_l = w1T + (size_t)l * CC * FFH;
        const __hip_bfloat16* w2T_l = w2T + (size_t)l * FFH * CC;

        gemm_qkv_mfma<<<dim3(CC / 128, MROWS / 128, 3), blk, 0, stream>>>(
            hb, kT_l, qT_l, vT_l, kbb, qbb, vtb);
        attn_mfma<<<dim3(TT / QBLK, HH, BB), blk, 0, stream>>>(kbb, qbb, vtb, ocb);
        gemm_mfma<<<dim3(CC / 128, MROWS / 128), blk, 0, stream>>>(
            ocb, pT_l, bproj + (size_t)l * CC, tmpf, (__hip_bfloat16*)nullptr,
            MROWS, CC, CC, 0);
        resid_ln<<<dim3(MROWS), blk, 0, stream>>>(h, tmpf, ln1g + (size_t)l * CC,
                                                  ln1b + (size_t)l * CC, hb);
        gemm_mfma<<<dim3(FFH / 128, MROWS / 128), blk, 0, stream>>>(
            hb, w1T_l, b1 + (size_t)l * FFH, (float*)nullptr, ff1b,
            MROWS, FFH, CC, 1);
        gemm_mfma<<<dim3(CC / 128, MROWS / 128), blk, 0, stream>>>(
            ff1b, w2T_l, b2 + (size_t)l * CC, tmpf, (__hip_bfloat16*)nullptr,
            MROWS, CC, FFH, 0);
        resid_ln<<<dim3(MROWS), blk, 0, stream>>>(h, tmpf, ln2g + (size_t)l * CC,
                                                  ln2b + (size_t)l * CC, hb);
    }

    lm_head_mfma256<<<dim3(MROWS / 256, VPAD2 / 256), dim3(512), 0, stream>>>(
        hb, lmT, blm, logits, pm, ps);
    nll_combine<<<dim3(MROWS), blk, 0, stream>>>(pm, ps, logits, y, rl);
    loss_reduce<<<dim3(1), blk, 0, stream>>>(rl, lossp);
}

// Round 11
// 3178.952 us; speedup vs baseline: 16.8094x; 1.0342x over previous
//
#include <hip/hip_runtime.h>
#include <hip/hip_bf16.h>
#include <math.h>

#define BB 4
#define TT 1024
#define VV 50257
#define VPAD2 50432
#define CC 768
#define HH 12
#define DD 64
#define LL 12
#define FFH 3072
#define MROWS (BB*TT)   // 4096
#define QBLK 128
#define KVBLK 64
#define NPART (VPAD2 / 64)        // 788 partials per row

typedef __bf16 bf16x8 __attribute__((ext_vector_type(8)));
typedef float  f32x4  __attribute__((ext_vector_type(4)));
typedef unsigned int u32;
#define AS1 __attribute__((address_space(1)))
#define AS3 __attribute__((address_space(3)))

static __device__ __forceinline__ void gload_lds16(const void* g, void* l) {
    __builtin_amdgcn_global_load_lds((const AS1 u32*)g, (AS3 u32*)l, 16, 0, 0);
}

// stage one 128x64 bf16 tile pair into linear LDS, source pre-swizzled (4 waves)
static __device__ __forceinline__ void stage_tile(const __hip_bfloat16* __restrict__ A,
                                                  const __hip_bfloat16* __restrict__ Bt,
                                                  int Kld, int k0, int bm, int bn,
                                                  int w, int l, char* As, char* Bs) {
    #pragma unroll
    for (int it = 0; it < 4; it++) {
        int chunk = w * 4 + it;
        int o = chunk * 1024 + l * 16;
        int row = o >> 7;
        int cb = (o & 127) ^ ((row & 7) << 4);
        gload_lds16(A + (size_t)(bm + row) * Kld + k0 + (cb >> 1), As + chunk * 1024);
        gload_lds16(Bt + (size_t)(bn + row) * Kld + k0 + (cb >> 1), Bs + chunk * 1024);
    }
}

// stage A(128x64) + B(64x64) for the n64 tile (4 waves)
static __device__ __forceinline__ void stage_tile_n64(const __hip_bfloat16* __restrict__ A,
                                                      const __hip_bfloat16* __restrict__ Bt,
                                                      int Kld, int k0, int bm, int bn,
                                                      int w, int l, char* As, char* Bs) {
    #pragma unroll
    for (int it = 0; it < 4; it++) {
        int chunk = w * 4 + it;                 // 16 chunks -> 16KB A
        int o = chunk * 1024 + l * 16;
        int row = o >> 7;
        int cb = (o & 127) ^ ((row & 7) << 4);
        gload_lds16(A + (size_t)(bm + row) * Kld + k0 + (cb >> 1), As + chunk * 1024);
    }
    #pragma unroll
    for (int it = 0; it < 2; it++) {
        int chunk = w * 2 + it;                 // 8 chunks -> 8KB B
        int o = chunk * 1024 + l * 16;
        int row = o >> 7;
        int cb = (o & 127) ^ ((row & 7) << 4);
        gload_lds16(Bt + (size_t)(bn + row) * Kld + k0 + (cb >> 1), Bs + chunk * 1024);
    }
}

// stage one 256x64 bf16 tile pair into linear LDS (8 waves / 512 threads)
static __device__ __forceinline__ void stage_tile256(const __hip_bfloat16* __restrict__ A,
                                                     const __hip_bfloat16* __restrict__ Bt,
                                                     int Kld, int k0, int bm, int bn,
                                                     int w, int l, char* As, char* Bs) {
    #pragma unroll
    for (int it = 0; it < 4; it++) {
        int chunk = w * 4 + it;
        int o = chunk * 1024 + l * 16;
        int row = o >> 7;
        int cb = (o & 127) ^ ((row & 7) << 4);
        gload_lds16(A + (size_t)(bm + row) * Kld + k0 + (cb >> 1), As + chunk * 1024);
        gload_lds16(Bt + (size_t)(bn + row) * Kld + k0 + (cb >> 1), Bs + chunk * 1024);
    }
}

// ---------------- embedding
__global__ void embed_kernel(const int* __restrict__ x, const float* __restrict__ tok,
                             const float* __restrict__ pos, float* __restrict__ h,
                             __hip_bfloat16* __restrict__ hb) {
    int idx = blockIdx.x * 256 + threadIdx.x;
    if (idx >= MROWS * CC) return;
    int row = idx / CC, c = idx - row * CC;
    int id = x[row];
    float v = tok[(size_t)id * CC + c] + pos[(size_t)id * CC + c];
    h[idx] = v;
    hb[idx] = __float2bfloat16(v);
}

// ---------------- convert + transpose weights
__global__ __launch_bounds__(256) void cvtT_mat(const float* __restrict__ in,
                                                __hip_bfloat16* __restrict__ out,
                                                int K, int Nin,
                                                size_t ibs, size_t obs) {
    __shared__ float t[32][33];
    const float* ip = in + blockIdx.z * ibs;
    __hip_bfloat16* op = out + blockIdx.z * obs;
    int n0 = blockIdx.x * 32, k0 = blockIdx.y * 32;
    int tx = threadIdx.x & 31, ty = threadIdx.x >> 5;
    #pragma unroll
    for (int i = 0; i < 4; i++) {
        int k = k0 + ty + i * 8, n = n0 + tx;
        t[ty + i * 8][tx] = (n < Nin) ? ip[(size_t)k * Nin + n] : 0.f;
    }
    __syncthreads();
    #pragma unroll
    for (int i = 0; i < 4; i++) {
        int n = n0 + ty + i * 8, k = k0 + tx;
        op[(size_t)n * K + k] = __float2bfloat16(t[tx][ty + i * 8]);
    }
}

__global__ __launch_bounds__(256) void cvtT_qkv(const float* __restrict__ Wk,
                                                const float* __restrict__ Wq,
                                                const float* __restrict__ Wv,
                                                __hip_bfloat16* __restrict__ kT,
                                                __hip_bfloat16* __restrict__ qT,
                                                __hip_bfloat16* __restrict__ vT) {
    int z = blockIdx.z;
    int tensor = z / 144, lh = z % 144;
    int l = lh / HH, hh = lh % HH;
    const float* in = (tensor == 0 ? Wk : tensor == 1 ? Wq : Wv) + (size_t)lh * CC * DD;
    __hip_bfloat16* out = (tensor == 0 ? kT : tensor == 1 ? qT : vT)
                          + ((size_t)l * CC + hh * DD) * CC;
    __shared__ float t[32][33];
    int c0 = blockIdx.x * 32, d0 = blockIdx.y * 32;
    int tx = threadIdx.x & 31, ty = threadIdx.x >> 5;
    #pragma unroll
    for (int i = 0; i < 4; i++)
        t[ty + i * 8][tx] = in[(size_t)(c0 + ty + i * 8) * DD + d0 + tx];
    __syncthreads();
    #pragma unroll
    for (int i = 0; i < 4; i++)
        out[(size_t)(d0 + ty + i * 8) * CC + c0 + tx] = __float2bfloat16(t[tx][ty + i * 8]);
}

// ---------------- MFMA GEMM 128x128 dbuf + LDS-staged coalesced epilogue.
__global__ __launch_bounds__(256) void gemm_mfma(const __hip_bfloat16* __restrict__ A,
                                                 const __hip_bfloat16* __restrict__ Bt,
                                                 const float* __restrict__ bias,
                                                 float* __restrict__ Cf,
                                                 __hip_bfloat16* __restrict__ Cb,
                                                 int M, int N, int K, int relu) {
    __shared__ __align__(16) char smem[65536];
    int tid = threadIdx.x;
    int l = tid & 63, w = tid >> 6;
    int wr = w >> 1, wc = w & 1;
    int bm = blockIdx.y * 128, bn = blockIdx.x * 128;

    f32x4 acc[4][4] = {};

    stage_tile(A, Bt, K, 0, bm, bn, w, l, smem, smem + 32768);
    int p = 0;
    for (int k0 = 0; k0 < K; k0 += 64) {
        __syncthreads();
        if (k0 + 64 < K)
            stage_tile(A, Bt, K, k0 + 64, bm, bn, w, l,
                       smem + (p ^ 1) * 16384, smem + 32768 + (p ^ 1) * 16384);
        const char* Ab = smem + p * 16384;
        const char* Bb = smem + 32768 + p * 16384;
        #pragma unroll
        for (int ks = 0; ks < 2; ks++) {
            bf16x8 af[4], bfr[4];
            #pragma unroll
            for (int i = 0; i < 4; i++) {
                int row = wr * 64 + i * 16 + (l & 15);
                int cb = (ks * 64 + (l >> 4) * 16) ^ ((row & 7) << 4);
                af[i] = *(const bf16x8*)(Ab + row * 128 + cb);
            }
            #pragma unroll
            for (int j = 0; j < 4; j++) {
                int row = wc * 64 + j * 16 + (l & 15);
                int cb = (ks * 64 + (l >> 4) * 16) ^ ((row & 7) << 4);
                bfr[j] = *(const bf16x8*)(Bb + row * 128 + cb);
            }
            #pragma unroll
            for (int i = 0; i < 4; i++)
                #pragma unroll
                for (int j = 0; j < 4; j++)
                    acc[i][j] = __builtin_amdgcn_mfma_f32_16x16x32_bf16(af[i], bfr[j], acc[i][j], 0, 0, 0);
        }
        p ^= 1;
    }

    if (Cb) {
        __hip_bfloat16* ebh = (__hip_bfloat16*)smem;
        __syncthreads();
        #pragma unroll
        for (int i = 0; i < 4; i++) {
            #pragma unroll
            for (int j = 0; j < 4; j++) {
                int colt = wc * 64 + j * 16 + (l & 15);
                float bv = bias ? bias[bn + colt] : 0.f;
                #pragma unroll
                for (int r = 0; r < 4; r++) {
                    int rowc = wr * 64 + i * 16 + (l >> 4) * 4 + r;
                    float v = acc[i][j][r] + bv;
                    if (relu) v = fmaxf(v, 0.f);
                    ebh[rowc * 136 + colt] = __float2bfloat16(v);
                }
            }
        }
        __syncthreads();
        #pragma unroll
        for (int pass = 0; pass < 8; pass++) {
            int idx = pass * 256 + tid;
            int rowc = idx >> 4, colq = idx & 15;
            *(bf16x8*)&Cb[(size_t)(bm + rowc) * N + bn + colq * 8] =
                *(const bf16x8*)&ebh[rowc * 136 + colq * 8];
        }
    } else {
        float* eb = (float*)smem;
        #pragma unroll
        for (int c = 0; c < 2; c++) {
            __syncthreads();
            if (wr == c) {
                #pragma unroll
                for (int i = 0; i < 4; i++) {
                    #pragma unroll
                    for (int j = 0; j < 4; j++) {
                        int colt = wc * 64 + j * 16 + (l & 15);
                        float bv = bias ? bias[bn + colt] : 0.f;
                        #pragma unroll
                        for (int r = 0; r < 4; r++) {
                            int rowc = i * 16 + (l >> 4) * 4 + r;
                            float v = acc[i][j][r] + bv;
                            if (relu) v = fmaxf(v, 0.f);
                            eb[rowc * 132 + colt] = v;
                        }
                    }
                }
            }
            __syncthreads();
            #pragma unroll
            for (int pass = 0; pass < 8; pass++) {
                int idx = pass * 256 + tid;
                int rowc = idx >> 5, colq = idx & 31;
                *(f32x4*)&Cf[(size_t)(bm + c * 64 + rowc) * N + bn + colq * 4] =
                    *(const f32x4*)&eb[rowc * 132 + colq * 4];
            }
        }
    }
}

// ---------------- MFMA GEMM 128x64 tile (for N=768 GEMMs: 384 blocks, 48KB LDS -> 3 blocks/CU)
// 4 waves, each 32 rows x 64 cols (acc[2][4]). f32 output + bias (+relu).
__global__ __launch_bounds__(256) void gemm_mfma_n64(const __hip_bfloat16* __restrict__ A,
                                                     const __hip_bfloat16* __restrict__ Bt,
                                                     const float* __restrict__ bias,
                                                     float* __restrict__ Cf,
                                                     int M, int N, int K, int relu) {
    __shared__ __align__(16) char smem[49152];   // A dbuf 2x16K @0, B dbuf 2x8K @32768
    int tid = threadIdx.x;
    int l = tid & 63, w = tid >> 6;
    int bm = blockIdx.y * 128, bn = blockIdx.x * 64;

    f32x4 acc[2][4] = {};

    stage_tile_n64(A, Bt, K, 0, bm, bn, w, l, smem, smem + 32768);
    int p = 0;
    for (int k0 = 0; k0 < K; k0 += 64) {
        __syncthreads();
        if (k0 + 64 < K)
            stage_tile_n64(A, Bt, K, k0 + 64, bm, bn, w, l,
                           smem + (p ^ 1) * 16384, smem + 32768 + (p ^ 1) * 8192);
        const char* Ab = smem + p * 16384;
        const char* Bb = smem + 32768 + p * 8192;
        #pragma unroll
        for (int ks = 0; ks < 2; ks++) {
            bf16x8 af[2], bfr[4];
            #pragma unroll
            for (int i = 0; i < 2; i++) {
                int row = w * 32 + i * 16 + (l & 15);
                int cb = (ks * 64 + (l >> 4) * 16) ^ ((row & 7) << 4);
                af[i] = *(const bf16x8*)(Ab + row * 128 + cb);
            }
            #pragma unroll
            for (int j = 0; j < 4; j++) {
                int row = j * 16 + (l & 15);
                int cb = (ks * 64 + (l >> 4) * 16) ^ ((row & 7) << 4);
                bfr[j] = *(const bf16x8*)(Bb + row * 128 + cb);
            }
            #pragma unroll
            for (int i = 0; i < 2; i++)
                #pragma unroll
                for (int j = 0; j < 4; j++)
                    acc[i][j] = __builtin_amdgcn_mfma_f32_16x16x32_bf16(af[i], bfr[j], acc[i][j], 0, 0, 0);
        }
        p ^= 1;
    }

    // staged coalesced epilogue: 128x64 f32 (stride 68), then 16B stores
    float* eb = (float*)smem;
    __syncthreads();
    #pragma unroll
    for (int i = 0; i < 2; i++) {
        #pragma unroll
        for (int j = 0; j < 4; j++) {
            int colt = j * 16 + (l & 15);
            float bv = bias ? bias[bn + colt] : 0.f;
            #pragma unroll
            for (int r = 0; r < 4; r++) {
                int rowc = w * 32 + i * 16 + (l >> 4) * 4 + r;
                float v = acc[i][j][r] + bv;
                if (relu) v = fmaxf(v, 0.f);
                eb[rowc * 68 + colt] = v;
            }
        }
    }
    __syncthreads();
    #pragma unroll
    for (int pass = 0; pass < 8; pass++) {
        int idx = pass * 256 + tid;
        int rowc = idx >> 4, colq = idx & 15;
        *(f32x4*)&Cf[(size_t)(bm + rowc) * N + bn + colq * 4] =
            *(const f32x4*)&eb[rowc * 68 + colq * 4];
    }
}

// ---------------- LM head: 256x256, 8 waves, BK=64 dbuf, fused LSE,
// barrier-free per-wave staged epilogue.
__global__ __launch_bounds__(512) void lm_head_mfma256(const __hip_bfloat16* __restrict__ A,
                                                       const __hip_bfloat16* __restrict__ Bt,
                                                       const float* __restrict__ bias,
                                                       float* __restrict__ Cf,
                                                       float* __restrict__ pm,
                                                       float* __restrict__ ps) {
    __shared__ __align__(16) char smem[131072];
    int tid = threadIdx.x;
    int l = tid & 63, w = tid >> 6;
    int wr = w >> 2, wc = w & 3;
    int bm = blockIdx.x * 256, bn = blockIdx.y * 256;   // row-fastest

    f32x4 acc[8][4] = {};

    stage_tile256(A, Bt, CC, 0, bm, bn, w, l, smem, smem + 65536);
    int p = 0;
    for (int k0 = 0; k0 < CC; k0 += 64) {
        __syncthreads();
        if (k0 + 64 < CC)
            stage_tile256(A, Bt, CC, k0 + 64, bm, bn, w, l,
                          smem + (p ^ 1) * 32768, smem + 65536 + (p ^ 1) * 32768);
        const char* Ab = smem + p * 32768;
        const char* Bb = smem + 65536 + p * 32768;
        #pragma unroll
        for (int ks = 0; ks < 2; ks++) {
            bf16x8 af[8], bfr[4];
            #pragma unroll
            for (int i = 0; i < 8; i++) {
                int row = wr * 128 + i * 16 + (l & 15);
                int cb = (ks * 64 + (l >> 4) * 16) ^ ((row & 7) << 4);
                af[i] = *(const bf16x8*)(Ab + row * 128 + cb);
            }
            #pragma unroll
            for (int j = 0; j < 4; j++) {
                int row = wc * 64 + j * 16 + (l & 15);
                int cb = (ks * 64 + (l >> 4) * 16) ^ ((row & 7) << 4);
                bfr[j] = *(const bf16x8*)(Bb + row * 128 + cb);
            }
            #pragma unroll
            for (int i = 0; i < 8; i++)
                #pragma unroll
                for (int j = 0; j < 4; j++)
                    acc[i][j] = __builtin_amdgcn_mfma_f32_16x16x32_bf16(af[i], bfr[j], acc[i][j], 0, 0, 0);
        }
        p ^= 1;
    }

    #pragma unroll
    for (int j = 0; j < 4; j++) {
        int col = bn + wc * 64 + j * 16 + (l & 15);
        float bv = (col < VV) ? bias[col] : 0.f;
        #pragma unroll
        for (int i = 0; i < 8; i++)
            #pragma unroll
            for (int r = 0; r < 4; r++)
                acc[i][j][r] += bv;
    }

    int pidx = blockIdx.y * 4 + wc;
    #pragma unroll
    for (int i = 0; i < 8; i++) {
        int row = bm + wr * 128 + i * 16 + (l >> 4) * 4;
        #pragma unroll
        for (int r = 0; r < 4; r++) {
            float pv[4];
            float rmax = -1e30f;
            #pragma unroll
            for (int j = 0; j < 4; j++) {
                int col = bn + wc * 64 + j * 16 + (l & 15);
                float v = (col < VV) ? acc[i][j][r] : -1e30f;
                pv[j] = v;
                rmax = fmaxf(rmax, v);
            }
            #pragma unroll
            for (int msk = 1; msk < 16; msk <<= 1)
                rmax = fmaxf(rmax, __shfl_xor(rmax, msk));
            float s = 0.f;
            #pragma unroll
            for (int j = 0; j < 4; j++) s += __expf(pv[j] - rmax);
            #pragma unroll
            for (int msk = 1; msk < 16; msk <<= 1)
                s += __shfl_xor(s, msk);
            if ((l & 15) == 0) {
                pm[(size_t)(row + r) * NPART + pidx] = rmax;
                ps[(size_t)(row + r) * NPART + pidx] = s;
            }
        }
    }

    __syncthreads();
    float* eb0 = (float*)smem + (size_t)(w * 2 + 0) * (16 * 68);
    float* eb1 = (float*)smem + (size_t)(w * 2 + 1) * (16 * 68);
    int colg = bn + wc * 64 + l;
    bool valid = colg < VV;
    #pragma unroll
    for (int i = 0; i < 8; i++) {
        float* eb = (i & 1) ? eb1 : eb0;
        #pragma unroll
        for (int j = 0; j < 4; j++) {
            int colt = j * 16 + (l & 15);
            #pragma unroll
            for (int r = 0; r < 4; r++) {
                int rowc = (l >> 4) * 4 + r;
                eb[rowc * 68 + colt] = acc[i][j][r];
            }
        }
        int rowbase = bm + wr * 128 + i * 16;
        #pragma unroll
        for (int pp = 0; pp < 16; pp++) {
            float v = eb[pp * 68 + l];
            if (valid) Cf[(size_t)(rowbase + pp) * VV + colg] = v;
        }
    }
}

// ---------------- combine LSE partials -> per-row NLL
__global__ __launch_bounds__(256) void nll_combine(const float* __restrict__ pm,
                                                   const float* __restrict__ ps,
                                                   const float* __restrict__ logits,
                                                   const int* __restrict__ y,
                                                   float* __restrict__ rl) {
    int m = blockIdx.x, tid = threadIdx.x;
    __shared__ float rm[256], rs[256];
    float mt = -1e30f, st = 0.f;
    for (int i = tid; i < NPART; i += 256) {
        float mi = pm[(size_t)m * NPART + i];
        float si = ps[(size_t)m * NPART + i];
        float mn = fmaxf(mt, mi);
        st = st * __expf(mt - mn) + si * __expf(mi - mn);
        mt = mn;
    }
    rm[tid] = mt; rs[tid] = st; __syncthreads();
    for (int off = 128; off > 0; off >>= 1) {
        if (tid < off) {
            float ma = rm[tid], mb = rm[tid + off];
            float mn = fmaxf(ma, mb);
            rs[tid] = rs[tid] * __expf(ma - mn) + rs[tid + off] * __expf(mb - mn);
            rm[tid] = mn;
        }
        __syncthreads();
    }
    if (tid == 0)
        rl[m] = logf(rs[0]) + rm[0] - logits[(size_t)m * VV + y[m]];
}

// ---------------- QKV MFMA GEMM (dbuf): LDS-staged coalesced epilogue.
__global__ __launch_bounds__(256) void gemm_qkv_mfma(const __hip_bfloat16* __restrict__ A,
                                                     const __hip_bfloat16* __restrict__ kT,
                                                     const __hip_bfloat16* __restrict__ qT,
                                                     const __hip_bfloat16* __restrict__ vT,
                                                     __hip_bfloat16* __restrict__ ko,
                                                     __hip_bfloat16* __restrict__ qo,
                                                     __hip_bfloat16* __restrict__ vto) {
    const __hip_bfloat16* Bt = (blockIdx.z == 0) ? kT : (blockIdx.z == 1) ? qT : vT;
    __shared__ __align__(16) char smem[65536];
    int tid = threadIdx.x;
    int l = tid & 63, w = tid >> 6;
    int wr = w >> 1, wc = w & 1;
    int bm = blockIdx.y * 128, bn = blockIdx.x * 128;

    f32x4 acc[4][4] = {};

    stage_tile(A, Bt, CC, 0, bm, bn, w, l, smem, smem + 32768);
    int p = 0;
    for (int k0 = 0; k0 < CC; k0 += 64) {
        __syncthreads();
        if (k0 + 64 < CC)
            stage_tile(A, Bt, CC, k0 + 64, bm, bn, w, l,
                       smem + (p ^ 1) * 16384, smem + 32768 + (p ^ 1) * 16384);
        const char* Ab = smem + p * 16384;
        const char* Bb = smem + 32768 + p * 16384;
        #pragma unroll
        for (int ks = 0; ks < 2; ks++) {
            bf16x8 af[4], bfr[4];
            #pragma unroll
            for (int i = 0; i < 4; i++) {
                int row = wr * 64 + i * 16 + (l & 15);
                int cb = (ks * 64 + (l >> 4) * 16) ^ ((row & 7) << 4);
                af[i] = *(const bf16x8*)(Ab + row * 128 + cb);
            }
            #pragma unroll
            for (int j = 0; j < 4; j++) {
                int row = wc * 64 + j * 16 + (l & 15);
                int cb = (ks * 64 + (l >> 4) * 16) ^ ((row & 7) << 4);
                bfr[j] = *(const bf16x8*)(Bb + row * 128 + cb);
            }
            #pragma unroll
            for (int i = 0; i < 4; i++)
                #pragma unroll
                for (int j = 0; j < 4; j++)
                    acc[i][j] = __builtin_amdgcn_mfma_f32_16x16x32_bf16(af[i], bfr[j], acc[i][j], 0, 0, 0);
        }
        p ^= 1;
    }

    int zz = blockIdx.z;
    int b = bm >> 10, tbase = bm & 1023;
    __hip_bfloat16* eb = (__hip_bfloat16*)smem;
    __syncthreads();
    if (zz != 2) {
        #pragma unroll
        for (int i = 0; i < 4; i++)
            #pragma unroll
            for (int j = 0; j < 4; j++) {
                int colt = wc * 64 + j * 16 + (l & 15);
                #pragma unroll
                for (int r = 0; r < 4; r++) {
                    int rowc = wr * 64 + i * 16 + (l >> 4) * 4 + r;
                    eb[rowc * 136 + colt] = __float2bfloat16(acc[i][j][r]);
                }
            }
        __syncthreads();
        __hip_bfloat16* O = (zz == 0) ? ko : qo;
        #pragma unroll
        for (int pass = 0; pass < 8; pass++) {
            int idx = pass * 256 + tid;
            int rowc = idx >> 4, colq = idx & 15;
            int head = (bn >> 6) + (colq >> 3);
            int d = (colq & 7) * 8;
            int t = tbase + rowc;
            *(bf16x8*)&O[(((size_t)(b * HH + head)) * TT + t) * DD + d] =
                *(const bf16x8*)&eb[rowc * 136 + colq * 8];
        }
    } else {
        #pragma unroll
        for (int i = 0; i < 4; i++)
            #pragma unroll
            for (int j = 0; j < 4; j++) {
                int colt = wc * 64 + j * 16 + (l & 15);
                #pragma unroll
                for (int r = 0; r < 4; r++) {
                    int rowc = wr * 64 + i * 16 + (l >> 4) * 4 + r;
                    eb[colt * 136 + rowc] = __float2bfloat16(acc[i][j][r]);
                }
            }
        __syncthreads();
        #pragma unroll
        for (int pass = 0; pass < 8; pass++) {
            int idx = pass * 256 + tid;
            int line = idx >> 4, tq = idx & 15;
            int head = (bn >> 6) + (line >> 6);
            int d = line & 63;
            *(bf16x8*)&vto[(((size_t)(b * HH + head)) * DD + d) * TT + tbase + tq * 8] =
                *(const bf16x8*)&eb[line * 136 + tq * 8];
        }
    }
}

// ---------------- MFMA flash attention (quirk: k plays query role)
__global__ __launch_bounds__(256) void attn_mfma(const __hip_bfloat16* __restrict__ kq,
                                                 const __hip_bfloat16* __restrict__ qk,
                                                 const __hip_bfloat16* __restrict__ vt,
                                                 __hip_bfloat16* __restrict__ oc) {
    __shared__ __hip_bfloat16 Qs[2][KVBLK * 64];
    __shared__ __hip_bfloat16 Vs[2][64 * KVBLK];
    __shared__ __hip_bfloat16 Ps[QBLK * KVBLK];
    int tid = threadIdx.x;
    int l = tid & 63, w = tid >> 6;
    int t0 = blockIdx.x * QBLK;
    size_t bh = (size_t)(blockIdx.z * HH + blockIdx.y);
    const __hip_bfloat16* kqp = kq + bh * TT * DD;
    const __hip_bfloat16* qkp = qk + bh * TT * DD;
    const __hip_bfloat16* vtp = vt + bh * DD * TT;

    bf16x8 af[2][2];
    #pragma unroll
    for (int i = 0; i < 2; i++)
        #pragma unroll
        for (int ks = 0; ks < 2; ks++)
            af[i][ks] = *(const bf16x8*)&kqp[(size_t)(t0 + w * 32 + i * 16 + (l & 15)) * DD
                                             + ks * 32 + (l >> 4) * 8];

    f32x4 acc_o[2][4] = {};
    float mrow[2][4], lrow[2][4];
    #pragma unroll
    for (int i = 0; i < 2; i++)
        #pragma unroll
        for (int r = 0; r < 4; r++) { mrow[i][r] = -1e30f; lrow[i][r] = 0.f; }

    auto stageKV = [&](int pp, int s0) {
        #pragma unroll
        for (int it = 0; it < 2; it++) {
            int chunk = w * 2 + it;
            int o = chunk * 1024 + l * 16;
            int row = o >> 7;
            int cb = (o & 127) ^ ((row & 7) << 4);
            gload_lds16(qkp + (size_t)(s0 + row) * DD + (cb >> 1),
                        (char*)Qs[pp] + chunk * 1024);
            gload_lds16(vtp + (size_t)row * TT + s0 + (cb >> 1),
                        (char*)Vs[pp] + chunk * 1024);
        }
    };

    int nt = (t0 + QBLK) / KVBLK;
    stageKV(0, 0);
    int p = 0;
    for (int ti = 0; ti < nt; ti++) {
        int s0 = ti * KVBLK;
        __syncthreads();
        if (ti + 1 < nt) stageKV(p ^ 1, s0 + KVBLK);

        f32x4 sa[2][4] = {};
        #pragma unroll
        for (int ks = 0; ks < 2; ks++) {
            bf16x8 bfr[4];
            #pragma unroll
            for (int j = 0; j < 4; j++) {
                int row = j * 16 + (l & 15);
                int cb = (ks * 64 + (l >> 4) * 16) ^ ((row & 7) << 4);
                bfr[j] = *(const bf16x8*)((const char*)Qs[p] + row * 128 + cb);
            }
            #pragma unroll
            for (int i = 0; i < 2; i++)
                #pragma unroll
                for (int j = 0; j < 4; j++)
                    sa[i][j] = __builtin_amdgcn_mfma_f32_16x16x32_bf16(af[i][ks], bfr[j], sa[i][j], 0, 0, 0);
        }

        #pragma unroll
        for (int i = 0; i < 2; i++) {
            #pragma unroll
            for (int r = 0; r < 4; r++) {
                int t = t0 + w * 32 + i * 16 + (l >> 4) * 4 + r;
                float pv[4];
                float rmax = -1e30f;
                #pragma unroll
                for (int j = 0; j < 4; j++) {
                    int s = s0 + j * 16 + (l & 15);
                    float v = sa[i][j][r] * 0.125f;
                    v = (s <= t) ? v : -1e30f;
                    pv[j] = v;
                    rmax = fmaxf(rmax, v);
                }
                #pragma unroll
                for (int msk = 1; msk < 16; msk <<= 1)
                    rmax = fmaxf(rmax, __shfl_xor(rmax, msk));
                float mo = mrow[i][r];
                float mn = fmaxf(mo, rmax);
                float fac = __expf(mo - mn);
                float ls = 0.f;
                int prow = w * 32 + i * 16 + (l >> 4) * 4 + r;
                #pragma unroll
                for (int j = 0; j < 4; j++) {
                    float e = __expf(pv[j] - mn);
                    ls += e;
                    int cb = (j * 32 + (l & 15) * 2) ^ ((prow & 7) << 4);
                    *(__hip_bfloat16*)((char*)Ps + prow * 128 + cb) = __float2bfloat16(e);
                }
                #pragma unroll
                for (int msk = 1; msk < 16; msk <<= 1)
                    ls += __shfl_xor(ls, msk);
                mrow[i][r] = mn;
                lrow[i][r] = lrow[i][r] * fac + ls;
                #pragma unroll
                for (int jd = 0; jd < 4; jd++)
                    acc_o[i][jd][r] *= fac;
            }
        }

        #pragma unroll
        for (int ks = 0; ks < 2; ks++) {
            bf16x8 pa[2], vf[4];
            #pragma unroll
            for (int i = 0; i < 2; i++) {
                int row = w * 32 + i * 16 + (l & 15);
                int cb = (ks * 64 + (l >> 4) * 16) ^ ((row & 7) << 4);
                pa[i] = *(const bf16x8*)((const char*)Ps + row * 128 + cb);
            }
            #pragma unroll
            for (int jd = 0; jd < 4; jd++) {
                int row = jd * 16 + (l & 15);
                int cb = (ks * 64 + (l >> 4) * 16) ^ ((row & 7) << 4);
                vf[jd] = *(const bf16x8*)((const char*)Vs[p] + row * 128 + cb);
            }
            #pragma unroll
            for (int i = 0; i < 2; i++)
                #pragma unroll
                for (int jd = 0; jd < 4; jd++)
                    acc_o[i][jd] = __builtin_amdgcn_mfma_f32_16x16x32_bf16(pa[i], vf[jd], acc_o[i][jd], 0, 0, 0);
        }
        p ^= 1;
    }

    int b = blockIdx.z, hh = blockIdx.y;
    #pragma unroll
    for (int i = 0; i < 2; i++) {
        #pragma unroll
        for (int r = 0; r < 4; r++) {
            float inv = 1.f / lrow[i][r];
            int t = t0 + w * 32 + i * 16 + (l >> 4) * 4 + r;
            #pragma unroll
            for (int jd = 0; jd < 4; jd++) {
                int d = jd * 16 + (l & 15);
                oc[((size_t)(b * TT + t)) * CC + hh * DD + d] =
                    __float2bfloat16(acc_o[i][jd][r] * inv);
            }
        }
    }
}

// ---------------- h = LN(h + t); writes f32 h and bf16 hb
__global__ __launch_bounds__(256) void resid_ln(float* __restrict__ h,
                                                const float* __restrict__ t,
                                                const float* __restrict__ g,
                                                const float* __restrict__ bta,
                                                __hip_bfloat16* __restrict__ hb) {
    int row = blockIdx.x;
    int tid = threadIdx.x;
    __shared__ float red[256];
    float x[3];
    float s = 0.f;
    #pragma unroll
    for (int i = 0; i < 3; i++) {
        int c = tid + i * 256;
        x[i] = h[(size_t)row * CC + c] + t[(size_t)row * CC + c];
        s += x[i];
    }
    red[tid] = s; __syncthreads();
    for (int off = 128; off > 0; off >>= 1) {
        if (tid < off) red[tid] += red[tid + off];
        __syncthreads();
    }
    float mean = red[0] * (1.f / CC); __syncthreads();
    float s2 = 0.f;
    #pragma unroll
    for (int i = 0; i < 3; i++) { float dd = x[i] - mean; s2 += dd * dd; }
    red[tid] = s2; __syncthreads();
    for (int off = 128; off > 0; off >>= 1) {
        if (tid < off) red[tid] += red[tid + off];
        __syncthreads();
    }
    float inv = rsqrtf(red[0] * (1.f / CC) + 1e-5f);
    #pragma unroll
    for (int i = 0; i < 3; i++) {
        int c = tid + i * 256;
        float o = (x[i] - mean) * inv * g[c] + bta[c];
        h[(size_t)row * CC + c] = o;
        hb[(size_t)row * CC + c] = __float2bfloat16(o);
    }
}

__global__ __launch_bounds__(256) void loss_reduce(const float* __restrict__ rl,
                                                   float* __restrict__ out) {
    int tid = threadIdx.x;
    __shared__ float red[256];
    float s = 0.f;
    for (int i = tid; i < MROWS; i += 256) s += rl[i];
    red[tid] = s; __syncthreads();
    for (int off = 128; off > 0; off >>= 1) {
        if (tid < off) red[tid] += red[tid + off];
        __syncthreads();
    }
    if (tid == 0) out[0] = red[0] * (1.f / MROWS);
}

extern "C" void kernel_launch(void* const* d_in, const int* in_sizes, int n_in,
                              void* d_out, int out_size, void* d_ws, size_t ws_size,
                              hipStream_t stream) {
    const int*   x     = (const int*)d_in[0];
    const int*   y     = (const int*)d_in[1];
    const float* tok   = (const float*)d_in[2];
    const float* pos   = (const float*)d_in[3];
    const float* Wk    = (const float*)d_in[4];
    const float* Wq    = (const float*)d_in[5];
    const float* Wv    = (const float*)d_in[6];
    const float* Wproj = (const float*)d_in[7];
    const float* bproj = (const float*)d_in[8];
    const float* ln1g  = (const float*)d_in[9];
    const float* ln1b  = (const float*)d_in[10];
    const float* W1    = (const float*)d_in[11];
    const float* b1    = (const float*)d_in[12];
    const float* W2    = (const float*)d_in[13];
    const float* b2    = (const float*)d_in[14];
    const float* ln2g  = (const float*)d_in[15];
    const float* ln2b  = (const float*)d_in[16];
    const float* Wlm   = (const float*)d_in[17];
    const float* blm   = (const float*)d_in[18];

    float* logits = (float*)d_out;
    float* lossp  = (float*)d_out + ((size_t)out_size - 1);

    char* p = (char*)d_ws;
    auto alloc = [&](size_t bytes) { char* r = p; p += (bytes + 255) & ~255ULL; return r; };
    const size_t S_HC = (size_t)MROWS * CC;

    float* h    = (float*)alloc(S_HC * 4);
    float* tmpf = (float*)alloc(S_HC * 4);
    float* rl   = (float*)alloc(MROWS * 4);
    float* pm   = (float*)alloc((size_t)MROWS * NPART * 4);
    float* ps   = (float*)alloc((size_t)MROWS * NPART * 4);
    __hip_bfloat16* kbb  = (__hip_bfloat16*)alloc(S_HC * 2);
    __hip_bfloat16* qbb  = (__hip_bfloat16*)alloc(S_HC * 2);
    __hip_bfloat16* vtb  = (__hip_bfloat16*)alloc(S_HC * 2);
    __hip_bfloat16* hb   = (__hip_bfloat16*)alloc(S_HC * 2);
    __hip_bfloat16* ocb  = (__hip_bfloat16*)alloc(S_HC * 2);
    __hip_bfloat16* ff1b = (__hip_bfloat16*)alloc((size_t)MROWS * FFH * 2);
    __hip_bfloat16* kT   = (__hip_bfloat16*)alloc((size_t)LL * CC * CC * 2);
    __hip_bfloat16* qT   = (__hip_bfloat16*)alloc((size_t)LL * CC * CC * 2);
    __hip_bfloat16* vT   = (__hip_bfloat16*)alloc((size_t)LL * CC * CC * 2);
    __hip_bfloat16* pT   = (__hip_bfloat16*)alloc((size_t)LL * CC * CC * 2);
    __hip_bfloat16* w1T  = (__hip_bfloat16*)alloc((size_t)LL * CC * FFH * 2);
    __hip_bfloat16* w2T  = (__hip_bfloat16*)alloc((size_t)LL * FFH * CC * 2);
    __hip_bfloat16* lmT  = (__hip_bfloat16*)alloc((size_t)VPAD2 * CC * 2);

    dim3 blk(256);

    cvtT_qkv<<<dim3(24, 2, 3 * 144), blk, 0, stream>>>(Wk, Wq, Wv, kT, qT, vT);
    cvtT_mat<<<dim3(24, 24, LL), blk, 0, stream>>>(Wproj, pT, CC, CC,
                                                   (size_t)CC * CC, (size_t)CC * CC);
    cvtT_mat<<<dim3(96, 24, LL), blk, 0, stream>>>(W1, w1T, CC, FFH,
                                                   (size_t)CC * FFH, (size_t)FFH * CC);
    cvtT_mat<<<dim3(24, 96, LL), blk, 0, stream>>>(W2, w2T, FFH, CC,
                                                   (size_t)FFH * CC, (size_t)CC * FFH);
    cvtT_mat<<<dim3(VPAD2 / 32, 24, 1), blk, 0, stream>>>(Wlm, lmT, CC, VV, 0, 0);

    embed_kernel<<<dim3((MROWS * CC + 255) / 256), blk, 0, stream>>>(x, tok, pos, h, hb);

    for (int l = 0; l < LL; l++) {
        const __hip_bfloat16* kT_l = kT + (size_t)l * CC * CC;
        const __hip_bfloat16* qT_l = qT + (size_t)l * CC * CC;
        const __hip_bfloat16* vT_l = vT + (size_t)l * CC * CC;
        const __hip_bfloat16* pT_l = pT + (size_t)l * CC * CC;
        const __hip_bfloat16* w1T_l = w1T + (size_t)l * CC * FFH;
        const __hip_bfloat16* w2T_l = w2T + (size_t)l * FFH * CC;

        gemm_qkv_mfma<<<dim3(CC / 128, MROWS / 128, 3), blk, 0, stream>>>(
            hb, kT_l, qT_l, vT_l, kbb, qbb, vtb);
        attn_mfma<<<dim3(TT / QBLK, HH, BB), blk, 0, stream>>>(kbb, qbb, vtb, ocb);
        // proj: 128x64 tile -> 384 blocks
        gemm_mfma_n64<<<dim3(CC / 64, MROWS / 128), blk, 0, stream>>>(
            ocb, pT_l, bproj + (size_t)l * CC, tmpf, MROWS, CC, CC, 0);
        resid_ln<<<dim3(MROWS), blk, 0, stream>>>(h, tmpf, ln1g + (size_t)l * CC,
                                                  ln1b + (size_t)l * CC, hb);
        gemm_mfma<<<dim3(FFH / 128, MROWS / 128), blk, 0, stream>>>(
            hb, w1T_l, b1 + (size_t)l * FFH, (float*)nullptr, ff1b,
            MROWS, FFH, CC, 1);
        // ffn2: 128x64 tile -> 384 blocks
        gemm_mfma_n64<<<dim3(CC / 64, MROWS / 128), blk, 0, stream>>>(
            ff1b, w2T_l, b2 + (size_t)l * CC, tmpf, MROWS, CC, FFH, 0);
        resid_ln<<<dim3(MROWS), blk, 0, stream>>>(h, tmpf, ln2g + (size_t)l * CC,
                                                  ln2b + (size_t)l * CC, hb);
    }

    lm_head_mfma256<<<dim3(MROWS / 256, VPAD2 / 256), dim3(512), 0, stream>>>(
        hb, lmT, blm, logits, pm, ps);
    nll_combine<<<dim3(MROWS), blk, 0, stream>>>(pm, ps, logits, y, rl);
    loss_reduce<<<dim3(1), blk, 0, stream>>>(rl, lossp);
}